// Round 10
// baseline (1408.474 us; speedup 1.0000x reference)
//
#include <hip/hip_runtime.h>

#define NN 50000
#define NE 800000
#define FIN 128
#define EDIM 16
#define EMB 64
#define NH 2
#define NLAYERS 3
#define NG 64
#define HCC 128
#define INV_SQRT_D 0.125f
#define EPS_BN 1e-5f
#define SCAN_B 196   // ceil(NN/256)
#define SCALE_L2E 0.18033688f   // 0.125 * log2(e)

typedef __attribute__((ext_vector_type(8))) short bf16x8;
typedef __attribute__((ext_vector_type(4))) float f32x4;

__device__ __forceinline__ unsigned encf(float f){
  unsigned u = __float_as_uint(f);
  return (u & 0x80000000u) ? ~u : (u | 0x80000000u);
}
__device__ __forceinline__ float decf(unsigned e){
  unsigned u = (e & 0x80000000u) ? (e ^ 0x80000000u) : ~e;
  return __uint_as_float(u);
}
__device__ __forceinline__ unsigned f2bf(float x){   // RNE bf16, returned in low 16
  unsigned u = __float_as_uint(x);
  return (u + 0x7fffu + ((u >> 16) & 1u)) >> 16;
}
// split fp32 -> hi + lo bf16 (a ~= hi + lo, |lo| <= 2^-9 |a|)
__device__ __forceinline__ void f2bf_split(float x, unsigned short* hi, unsigned short* lo){
  unsigned h = f2bf(x);
  float hf = __uint_as_float(h << 16);
  *hi = (unsigned short)h;
  *lo = (unsigned short)f2bf(x - hf);
}

__global__ void hist_k(const int* __restrict__ dst, int* __restrict__ deg){
  int i = blockIdx.x * 256 + threadIdx.x;
  if (i < NE) atomicAdd(&deg[dst[i]], 1);
}

// batch_index is sorted: group starts via boundary detection, no atomics.
__global__ void bounds_k(const int* __restrict__ batch, int* __restrict__ starts){
  int i = blockIdx.x * 256 + threadIdx.x;
  if (i >= NN) return;
  int g = batch[i];
  int gp = (i == 0) ? -1 : batch[i - 1];
  for (int gg = gp + 1; gg <= g; gg++) starts[gg] = i;
  if (i == NN - 1){
    for (int gg = g + 1; gg <= NG; gg++) starts[gg] = NN;
  }
}

__global__ void counts_from_starts_k(const int* __restrict__ starts, int* __restrict__ counts){
  int g = threadIdx.x;
  if (g < NG) counts[g] = starts[g + 1] - starts[g];
}

__global__ void scan1_k(const int* __restrict__ deg, int* __restrict__ bsums){
  __shared__ int lds[256];
  int b = blockIdx.x, t = threadIdx.x;
  int idx = b * 256 + t;
  lds[t] = (idx < NN) ? deg[idx] : 0;
  __syncthreads();
  for (int off = 128; off >= 1; off >>= 1){
    if (t < off) lds[t] += lds[t + off];
    __syncthreads();
  }
  if (t == 0) bsums[b] = lds[0];
}

__global__ void scan2_k(int* __restrict__ bsums){
  __shared__ int lds[256];
  int t = threadIdx.x;
  int v = (t < SCAN_B) ? bsums[t] : 0;
  int x = v;
  lds[t] = x;
  __syncthreads();
  for (int off = 1; off < 256; off <<= 1){
    int y = (t >= off) ? lds[t - off] : 0;
    __syncthreads();
    x += y;
    lds[t] = x;
    __syncthreads();
  }
  if (t < SCAN_B) bsums[t] = x - v;   // exclusive
}

__global__ void scan3_k(const int* __restrict__ deg, const int* __restrict__ bsums,
                        int* __restrict__ row_ptr){
  __shared__ int lds[256];
  int b = blockIdx.x, t = threadIdx.x;
  int idx = b * 256 + t;
  int v = (idx < NN) ? deg[idx] : 0;
  int x = v;
  lds[t] = x;
  __syncthreads();
  for (int off = 1; off < 256; off <<= 1){
    int y = (t >= off) ? lds[t - off] : 0;
    __syncthreads();
    x += y;
    lds[t] = x;
    __syncthreads();
  }
  if (idx <= NN) row_ptr[idx] = bsums[b] + x - v;
}

__global__ void cursor_k(const int* __restrict__ row_ptr, int* __restrict__ cur){
  int i = blockIdx.x * 256 + threadIdx.x;
  if (i < NN) cur[i] = row_ptr[i];
}

__global__ void scatter_k(const int* __restrict__ dst, const int* __restrict__ src,
                          int* __restrict__ cur, int* __restrict__ eid,
                          int* __restrict__ src_s){
  int i = blockIdx.x * 256 + threadIdx.x;
  if (i < NE){
    int p = atomicAdd(&cur[dst[i]], 1);
    eid[p] = i;
    src_s[p] = src[i];
  }
}

// edge_attr -> bf16, reordered into CSR position order. thread = (p, half-row)
__global__ void pack_ea_k(const float* __restrict__ ea, const int* __restrict__ eid,
                          unsigned* __restrict__ eab){
  int i = blockIdx.x * 256 + threadIdx.x;
  if (i >= NE * 2) return;
  int p = i >> 1, half = i & 1;
  int e = eid[p];
  const float* s = ea + (size_t)e * 16 + half * 8;
  float4 a = *(const float4*)(s);
  float4 b = *(const float4*)(s + 4);
  uint4 o;
  o.x = f2bf(a.x) | (f2bf(a.y) << 16);
  o.y = f2bf(a.z) | (f2bf(a.w) << 16);
  o.z = f2bf(b.x) | (f2bf(b.y) << 16);
  o.w = f2bf(b.z) | (f2bf(b.w) << 16);
  ((uint4*)eab)[(size_t)p * 2 + half] = o;
}

// fp32 -> split bf16 (x once per call)
__global__ void tobf_k(const float* __restrict__ in, unsigned short* __restrict__ hi,
                       unsigned short* __restrict__ lo, int n){
  int i = blockIdx.x * 256 + threadIdx.x;
  if (i < n) f2bf_split(in[i], &hi[i], &lo[i]);
}

// pack q/k/v/skip weights into split bf16 Wp_hi/Wp_lo[512][D] + fp32 bias bp[512]
__global__ void pack_k(const float* __restrict__ qw, const float* __restrict__ kw,
                       const float* __restrict__ vw, const float* __restrict__ skw,
                       const float* __restrict__ qb, const float* __restrict__ kb,
                       const float* __restrict__ vb, const float* __restrict__ skb,
                       unsigned short* __restrict__ Wh, unsigned short* __restrict__ Wl,
                       float* __restrict__ bp, int D){
  int i = blockIdx.x * 256 + threadIdx.x;
  if (i < 512 * D){
    int c = i / D, d = i - c * D;
    const float* w = (c < 128) ? qw : (c < 256) ? kw : (c < 384) ? vw : skw;
    f2bf_split(w[(c & 127) * D + d], &Wh[i], &Wl[i]);
  }
  if (i < 512){
    const float* b = (i < 128) ? qb : (i < 256) ? kb : (i < 384) ? vb : skb;
    bp[i] = b[i & 127];
  }
}

// qe[n, h, d] = (sum_c q[n,h,c] * ew[h*64+c, d]) * SCALE_L2E
__global__ __launch_bounds__(256) void qe_k(const float* __restrict__ qf,
    const float* __restrict__ ew, float* __restrict__ qe){
  __shared__ float ews[2048];
  int t = threadIdx.x;
  for (int i = t; i < 2048; i += 256) ews[i] = ew[i];
  __syncthreads();
  int g = t >> 5;            // node within block (8 nodes/block)
  int hd = t & 31;           // h*16 + d
  int h = hd >> 4, d = hd & 15;
  int n = blockIdx.x * 8 + g;
  if (n >= NN) return;
  const float* qp = qf + (size_t)n * 128 + h * 64;
  float s = 0.f;
  #pragma unroll 8
  for (int c = 0; c < 64; c++)
    s += qp[c] * ews[(h * 64 + c) * 16 + d];
  qe[(size_t)n * 32 + hd] = s * SCALE_L2E;
}

// ewT[h][d][c] = ew[h*64+c][d]  (transposed, for edge_k epilogue float4 loads)
__global__ void ewt_k(const float* __restrict__ ew, float* __restrict__ ewT){
  int i = blockIdx.x * 256 + threadIdx.x;
  if (i < 2048){
    int c = i >> 4, d = i & 15;          // c = h*64 + ch
    ewT[((c >> 6) * 16 + d) * 64 + (c & 63)] = ew[i];
  }
}

// Fused qkvs GEMM, 4-way column-split, BATCHED per-kk loads (anti-serialization):
// per kk: issue 18 independent 16B loads into named register arrays, then 24 MFMAs.
// grid = (ceil(NN/64), 4):
//   part0: q cols 0..127 -> qf ; part1: k0+v0 -> kvb ch 0..63
//   part2: k1+v1 -> kvb ch 64..127 ; part3: skip -> sk
// Split-bf16: C ~= Ah*Wh + Al*Wh + Ah*Wl.
template<int D>
__global__ __launch_bounds__(256) void gemm4_k(const unsigned short* __restrict__ Ah,
                                               const unsigned short* __restrict__ Al,
                                               const unsigned short* __restrict__ Wh,
                                               const unsigned short* __restrict__ Wl,
                                               const float* __restrict__ bp,
                                               float* __restrict__ qf,
                                               unsigned* __restrict__ kvb,
                                               float* __restrict__ sk){
  int t = threadIdx.x;
  int w = t >> 6, lane = t & 63;
  int brow = blockIdx.x * 64 + w * 16;
  int part = blockIdx.y;
  int r = lane & 15, kg = lane >> 4;
  int arow = brow + r; if (arow >= NN) arow = NN - 1;
  const int NK = D / 32;
  int cb0 = (part == 0) ? 0 : (part == 1) ? 2 : (part == 2) ? 3 : 6;
  int cb1 = (part == 0) ? 1 : (part == 1) ? 4 : (part == 2) ? 5 : 7;
  f32x4 acc0[4], acc1[4];
  #pragma unroll
  for (int nf = 0; nf < 4; nf++){
    acc0[nf] = (f32x4){0.f,0.f,0.f,0.f};
    acc1[nf] = (f32x4){0.f,0.f,0.f,0.f};
  }
  size_t aoff  = (size_t)arow * D + kg * 8;
  size_t w0off = (size_t)(cb0 * 64 + r) * D + kg * 8;
  size_t w1off = (size_t)(cb1 * 64 + r) * D + kg * 8;
  #pragma unroll
  for (int kk = 0; kk < NK; kk++){
    int kb = kk * 32;
    // ---- batched load phase: 18 independent loads, no consumer in between ----
    bf16x8 ah = *(const bf16x8*)(Ah + aoff + kb);
    bf16x8 al = *(const bf16x8*)(Al + aoff + kb);
    bf16x8 b0h[4], b0l[4], b1h[4], b1l[4];
    #pragma unroll
    for (int nf = 0; nf < 4; nf++){
      b0h[nf] = *(const bf16x8*)(Wh + w0off + kb + (size_t)nf * 16 * D);
      b0l[nf] = *(const bf16x8*)(Wl + w0off + kb + (size_t)nf * 16 * D);
      b1h[nf] = *(const bf16x8*)(Wh + w1off + kb + (size_t)nf * 16 * D);
      b1l[nf] = *(const bf16x8*)(Wl + w1off + kb + (size_t)nf * 16 * D);
    }
    // ---- compute phase: 24 MFMAs on 8 independent accumulator chains ----
    #pragma unroll
    for (int nf = 0; nf < 4; nf++){
      acc0[nf] = __builtin_amdgcn_mfma_f32_16x16x32_bf16(ah, b0h[nf], acc0[nf], 0, 0, 0);
      acc1[nf] = __builtin_amdgcn_mfma_f32_16x16x32_bf16(ah, b1h[nf], acc1[nf], 0, 0, 0);
      acc0[nf] = __builtin_amdgcn_mfma_f32_16x16x32_bf16(al, b0h[nf], acc0[nf], 0, 0, 0);
      acc1[nf] = __builtin_amdgcn_mfma_f32_16x16x32_bf16(al, b1h[nf], acc1[nf], 0, 0, 0);
      acc0[nf] = __builtin_amdgcn_mfma_f32_16x16x32_bf16(ah, b0l[nf], acc0[nf], 0, 0, 0);
      acc1[nf] = __builtin_amdgcn_mfma_f32_16x16x32_bf16(ah, b1l[nf], acc1[nf], 0, 0, 0);
    }
  }
  int rowbase = brow + kg * 4;
  if (part == 0){
    #pragma unroll
    for (int nf = 0; nf < 4; nf++){
      int ch0 = nf * 16 + r, ch1 = 64 + nf * 16 + r;
      float b0 = bp[ch0], b1 = bp[ch1];
      #pragma unroll
      for (int j = 0; j < 4; j++){
        int row = rowbase + j;
        if (row < NN){
          qf[(size_t)row * 128 + ch0] = acc0[nf][j] + b0;
          qf[(size_t)row * 128 + ch1] = acc1[nf][j] + b1;
        }
      }
    }
  } else if (part == 3){
    #pragma unroll
    for (int nf = 0; nf < 4; nf++){
      int ch0 = nf * 16 + r, ch1 = 64 + nf * 16 + r;
      float b0 = bp[384 + ch0], b1 = bp[384 + ch1];
      #pragma unroll
      for (int j = 0; j < 4; j++){
        int row = rowbase + j;
        if (row < NN){
          sk[(size_t)row * 128 + ch0] = acc0[nf][j] + b0;
          sk[(size_t)row * 128 + ch1] = acc1[nf][j] + b1;
        }
      }
    }
  } else {
    int chbase = (part - 1) * 64;
    #pragma unroll
    for (int nf = 0; nf < 4; nf++){
      int ch = chbase + nf * 16 + r;
      float bk = bp[cb0 * 64 + nf * 16 + r];
      float bv = bp[cb1 * 64 + nf * 16 + r];
      #pragma unroll
      for (int j = 0; j < 4; j++){
        int row = rowbase + j;
        if (row < NN){
          float kk4 = acc0[nf][j] + bk;
          float vv = acc1[nf][j] + bv;
          kvb[(size_t)row * 128 + ch] = f2bf(kk4) | (f2bf(vv) << 16);
        }
      }
    }
  }
}

// One wave per (node, head). 4 edges per wave iteration: 16 lanes per edge
// (grp = lane>>4 picks the edge, l = lane&15 picks 4 channels 4l..4l+3).
__global__ __launch_bounds__(256) void edge_k(const float* __restrict__ qf,
    const unsigned* __restrict__ kvb, const unsigned short* __restrict__ eab_us,
    const float* __restrict__ qe, const float* __restrict__ ewT,
    const int* __restrict__ row_ptr, const int* __restrict__ src_s,
    float* __restrict__ attn){
  int wv = (blockIdx.x * 256 + threadIdx.x) >> 6;
  if (wv >= NN * 2) return;
  int lane = threadIdx.x & 63;
  int n = wv >> 1, h = wv & 1;
  int grp = lane >> 4, l = lane & 15;
  float4 qv = *(const float4*)(qf + (size_t)n * 128 + h * 64 + 4 * l);
  float q0 = qv.x * SCALE_L2E, q1 = qv.y * SCALE_L2E;
  float q2 = qv.z * SCALE_L2E, q3 = qv.w * SCALE_L2E;
  float qel = qe[(size_t)n * 32 + h * 16 + l];
  int beg = row_ptr[n], end = row_ptr[n + 1];
  int nb = end - beg;
  float a0 = 0.f, a1 = 0.f, a2 = 0.f, a3 = 0.f, den = 0.f, tl = 0.f;
  int hoff = h * 64 + 4 * l;
  for (int cb = 0; cb < nb; cb += 64){
    int sv = (cb + lane < nb) ? src_s[beg + cb + lane] : 0;
    int m = min(64, nb - cb);
    for (int u = 0; u < m; u += 8){
      int eA = u + grp, eB = u + 4 + grp;        // both < 64 (u <= 56)
      int sA = __shfl(sv, eA);
      int sB = __shfl(sv, eB);
      uint4 kvA = *(const uint4*)(kvb + (size_t)sA * 128 + hoff);
      uint4 kvB = *(const uint4*)(kvb + (size_t)sB * 128 + hoff);
      size_t gA = (size_t)(beg + cb + eA); if (gA >= NE) gA = NE - 1;
      size_t gB = (size_t)(beg + cb + eB); if (gB >= NE) gB = NE - 1;
      unsigned short eaAu = eab_us[gA * 16 + l];
      unsigned short eaBu = eab_us[gB * 16 + l];
      {
        float eaf = __uint_as_float((unsigned)eaAu << 16);
        float k0 = __uint_as_float(kvA.x << 16), v0 = __uint_as_float(kvA.x & 0xffff0000u);
        float k1 = __uint_as_float(kvA.y << 16), v1 = __uint_as_float(kvA.y & 0xffff0000u);
        float k2 = __uint_as_float(kvA.z << 16), v2 = __uint_as_float(kvA.z & 0xffff0000u);
        float k3 = __uint_as_float(kvA.w << 16), v3 = __uint_as_float(kvA.w & 0xffff0000u);
        float p = fmaf(q0, k0, fmaf(q1, k1, fmaf(q2, k2, fmaf(q3, k3, qel * eaf))));
        p += __shfl_xor(p, 1); p += __shfl_xor(p, 2);
        p += __shfl_xor(p, 4); p += __shfl_xor(p, 8);
        float w = exp2f(p);
        if (eA >= m) w = 0.f;
        a0 = fmaf(v0, w, a0); a1 = fmaf(v1, w, a1);
        a2 = fmaf(v2, w, a2); a3 = fmaf(v3, w, a3);
        den += w; tl = fmaf(eaf, w, tl);
      }
      {
        float eaf = __uint_as_float((unsigned)eaBu << 16);
        float k0 = __uint_as_float(kvB.x << 16), v0 = __uint_as_float(kvB.x & 0xffff0000u);
        float k1 = __uint_as_float(kvB.y << 16), v1 = __uint_as_float(kvB.y & 0xffff0000u);
        float k2 = __uint_as_float(kvB.z << 16), v2 = __uint_as_float(kvB.z & 0xffff0000u);
        float k3 = __uint_as_float(kvB.w << 16), v3 = __uint_as_float(kvB.w & 0xffff0000u);
        float p = fmaf(q0, k0, fmaf(q1, k1, fmaf(q2, k2, fmaf(q3, k3, qel * eaf))));
        p += __shfl_xor(p, 1); p += __shfl_xor(p, 2);
        p += __shfl_xor(p, 4); p += __shfl_xor(p, 8);
        float w = exp2f(p);
        if (eB >= m) w = 0.f;
        a0 = fmaf(v0, w, a0); a1 = fmaf(v1, w, a1);
        a2 = fmaf(v2, w, a2); a3 = fmaf(v3, w, a3);
        den += w; tl = fmaf(eaf, w, tl);
      }
    }
  }
  a0 += __shfl_xor(a0, 16); a0 += __shfl_xor(a0, 32);
  a1 += __shfl_xor(a1, 16); a1 += __shfl_xor(a1, 32);
  a2 += __shfl_xor(a2, 16); a2 += __shfl_xor(a2, 32);
  a3 += __shfl_xor(a3, 16); a3 += __shfl_xor(a3, 32);
  den += __shfl_xor(den, 16); den += __shfl_xor(den, 32);
  tl  += __shfl_xor(tl, 16);  tl  += __shfl_xor(tl, 32);
  float e0 = 0.f, e1 = 0.f, e2 = 0.f, e3 = 0.f;
  const float* ewp = ewT + (size_t)h * 16 * 64 + 4 * l;
  #pragma unroll
  for (int d = 0; d < 16; d++){
    float td = __shfl(tl, d);
    float4 w4 = *(const float4*)(ewp + d * 64);
    e0 = fmaf(w4.x, td, e0); e1 = fmaf(w4.y, td, e1);
    e2 = fmaf(w4.z, td, e2); e3 = fmaf(w4.w, td, e3);
  }
  float inv = den > 0.f ? 1.f / den : 0.f;
  float4 o;
  o.x = (a0 + e0) * inv; o.y = (a1 + e1) * inv;
  o.z = (a2 + e2) * inv; o.w = (a3 + e3) * inv;
  *(float4*)(attn + (size_t)n * 128 + h * 64 + 4 * l) = o;
}

// beta-gate combine + [128->64] proj + leaky relu + BN partial sums.
__global__ __launch_bounds__(256) void combine_k(const float* __restrict__ attn,
    const float* __restrict__ sk, const float* __restrict__ bw,
    const float* __restrict__ tw, const float* __restrict__ tb,
    float* __restrict__ h2, float* __restrict__ bn_acc){
  __shared__ float twT[128][65];
  __shared__ float hcs[4][128];
  __shared__ float bsum[64], bsq[64];
  int t = threadIdx.x;
  int lane = t & 63, wv = t >> 6;
  for (int i = t; i < 64 * 128; i += 256){
    int j = i >> 7, k = i & 127;
    twT[k][j] = tw[i];
  }
  if (t < 64){ bsum[t] = 0.f; bsq[t] = 0.f; }
  __syncthreads();
  float bw0 = bw[lane],       bw1 = bw[64 + lane];
  float bwr0 = bw[128 + lane], bwr1 = bw[192 + lane];
  float bwd0 = bw[256 + lane], bwd1 = bw[320 + lane];
  float tbv = tb[lane];
  float rs = 0.f, rq = 0.f;
  int base_node = blockIdx.x * 16 + wv * 4;
  for (int it = 0; it < 4; it++){
    int n = base_node + it;
    bool valid = n < NN;
    float o0 = 0.f, o1 = 0.f, r0 = 0.f, r1 = 0.f;
    if (valid){
      o0 = attn[(size_t)n * 128 + lane];
      o1 = attn[(size_t)n * 128 + 64 + lane];
      r0 = sk[(size_t)n * 128 + lane];
      r1 = sk[(size_t)n * 128 + 64 + lane];
    }
    float p = o0 * bw0 + o1 * bw1 + r0 * bwr0 + r1 * bwr1 + (o0 - r0) * bwd0 + (o1 - r1) * bwd1;
    #pragma unroll
    for (int off = 32; off >= 1; off >>= 1) p += __shfl_xor(p, off);
    float beta = 1.f / (1.f + __expf(-p));
    float hc0 = beta * r0 + (1.f - beta) * o0;
    float hc1 = beta * r1 + (1.f - beta) * o1;
    hcs[wv][lane] = hc0;
    hcs[wv][64 + lane] = hc1;
    __syncthreads();
    float s = tbv;
    #pragma unroll 8
    for (int k = 0; k < 128; k++) s += hcs[wv][k] * twT[k][lane];
    __syncthreads();
    if (valid){
      float hv = s > 0.f ? s : 0.01f * s;
      h2[(size_t)n * 64 + lane] = hv;
      rs += hv; rq += hv * hv;
    }
  }
  atomicAdd(&bsum[lane], rs);
  atomicAdd(&bsq[lane], rq);
  __syncthreads();
  if (t < 64){
    atomicAdd(&bn_acc[t], bsum[t]);
    atomicAdd(&bn_acc[64 + t], bsq[t]);
  }
}

__global__ void bn_final_k(const float* __restrict__ bn_acc, const float* __restrict__ bnw,
                           const float* __restrict__ bnb, float* __restrict__ ss){
  int j = threadIdx.x;
  if (j < 64){
    float m = bn_acc[j] / (float)NN;
    float v = bn_acc[64 + j] / (float)NN - m * m;
    float sc = bnw[j] * rsqrtf(v + EPS_BN);
    ss[j] = sc;
    ss[64 + j] = bnb[j] - m * sc;
  }
}

// BN apply -> split bf16 h (next-layer GEMM input) + pooled max/sum (sorted batch)
__global__ __launch_bounds__(256) void bn_apply_k(const float* __restrict__ h2,
    const float* __restrict__ ss, const int* __restrict__ batch,
    unsigned short* __restrict__ hbh, unsigned short* __restrict__ hbl,
    float* __restrict__ gsum, unsigned* __restrict__ gmax,
    int do_pool){
  int wid = (blockIdx.x * 256 + threadIdx.x) >> 6;
  int lane = threadIdx.x & 63;
  const int CH = (NN + 1023) / 1024;
  int start = wid * CH;
  int end = start + CH; if (end > NN) end = NN;
  float sc = ss[lane], sh = ss[64 + lane];
  int curg = -1; float lmax = 0.f, lsum = 0.f;
  for (int n = start; n < end; n++){
    float v = h2[(size_t)n * 64 + lane] * sc + sh;
    f2bf_split(v, &hbh[(size_t)n * 64 + lane], &hbl[(size_t)n * 64 + lane]);
    if (do_pool){
      int g = batch[n];
      if (g != curg){
        if (curg >= 0){
          atomicAdd(&gsum[curg * 64 + lane], lsum);
          atomicMax(&gmax[curg * 64 + lane], encf(lmax));
        }
        curg = g; lmax = v; lsum = v;
      } else {
        lmax = fmaxf(lmax, v); lsum += v;
      }
    }
  }
  if (do_pool && curg >= 0){
    atomicAdd(&gsum[curg * 64 + lane], lsum);
    atomicMax(&gmax[curg * 64 + lane], encf(lmax));
  }
}

__global__ void pool_final_k(const float* __restrict__ gsum, const unsigned* __restrict__ gmax,
                             const int* __restrict__ counts, float* __restrict__ gr){
  int i = blockIdx.x * 256 + threadIdx.x;
  if (i < NG * 64){
    int g = i >> 6, j = i & 63;
    unsigned e = gmax[i];
    float mx = e ? decf(e) : 0.f;
    int c = counts[g]; if (c < 1) c = 1;
    gr[g * 128 + j]       += mx;
    gr[g * 128 + 64 + j]  += gsum[i] / (float)c;
  }
}

extern "C" void kernel_launch(void* const* d_in, const int* in_sizes, int n_in,
                              void* d_out, int out_size, void* d_ws, size_t ws_size,
                              hipStream_t stream){
  const float* x     = (const float*)d_in[0];
  const float* ea    = (const float*)d_in[1];
  const int*   eidx  = (const int*)d_in[2];
  const int*   batch = (const int*)d_in[3];
  const float* c1_qw = (const float*)d_in[4];
  const float* c1_qb = (const float*)d_in[5];
  const float* c1_kw = (const float*)d_in[6];
  const float* c1_kb = (const float*)d_in[7];
  const float* c1_vw = (const float*)d_in[8];
  const float* c1_vb = (const float*)d_in[9];
  const float* c1_ew = (const float*)d_in[10];
  const float* c1_skw= (const float*)d_in[11];
  const float* c1_skb= (const float*)d_in[12];
  const float* c1_bw = (const float*)d_in[13];
  const float* c1_tw = (const float*)d_in[14];
  const float* c1_tb = (const float*)d_in[15];
  const float* c1_bnw= (const float*)d_in[16];
  const float* c1_bnb= (const float*)d_in[17];
  const float* L_qw  = (const float*)d_in[18];
  const float* L_qb  = (const float*)d_in[19];
  const float* L_kw  = (const float*)d_in[20];
  const float* L_kb  = (const float*)d_in[21];
  const float* L_vw  = (const float*)d_in[22];
  const float* L_vb  = (const float*)d_in[23];
  const float* L_ew  = (const float*)d_in[24];
  const float* L_skw = (const float*)d_in[25];
  const float* L_skb = (const float*)d_in[26];
  const float* L_bw  = (const float*)d_in[27];
  const float* L_tw  = (const float*)d_in[28];
  const float* L_tb  = (const float*)d_in[29];
  const float* L_bnw = (const float*)d_in[30];
  const float* L_bnb = (const float*)d_in[31];
  const int* srcs = eidx;
  const int* dsts = eidx + NE;

  char* p = (char*)d_ws;
  auto carve = [&](size_t bytes) -> void* {
    void* r = (void*)p;
    p += (bytes + 255) & ~(size_t)255;
    return r;
  };
  unsigned short* Wh = (unsigned short*)carve(512 * 128 * sizeof(unsigned short));
  unsigned short* Wl = (unsigned short*)carve(512 * 128 * sizeof(unsigned short));
  float*    bp     = (float*)carve(512 * sizeof(float));
  float*    qf     = (float*)carve((size_t)NN * 128 * sizeof(float));
  float*    skb_   = (float*)carve((size_t)NN * 128 * sizeof(float));
  unsigned* kvb    = (unsigned*)carve((size_t)NN * 128 * sizeof(unsigned));
  unsigned* eab    = (unsigned*)carve((size_t)NE * 8 * sizeof(unsigned));
  float*    qe     = (float*)carve((size_t)NN * 32 * sizeof(float));
  float*    ewT    = (float*)carve(2048 * sizeof(float));
  float*    attn   = (float*)carve((size_t)NN * 128 * sizeof(float));
  unsigned short* xbh = (unsigned short*)carve((size_t)NN * FIN * sizeof(unsigned short));
  unsigned short* xbl = (unsigned short*)carve((size_t)NN * FIN * sizeof(unsigned short));
  unsigned short* hbh = (unsigned short*)carve((size_t)NN * 64 * sizeof(unsigned short));
  unsigned short* hbl = (unsigned short*)carve((size_t)NN * 64 * sizeof(unsigned short));
  float*    h2     = (float*)carve((size_t)NN * 64 * sizeof(float));
  float*    bn_acc = (float*)carve(128 * sizeof(float));
  float*    ss     = (float*)carve(128 * sizeof(float));
  float*    gsum   = (float*)carve((size_t)NG * 64 * sizeof(float));
  unsigned* gmax   = (unsigned*)carve((size_t)NG * 64 * sizeof(unsigned));
  int*      deg    = (int*)carve(NN * sizeof(int));
  int*      row_ptr= (int*)carve((NN + 1) * sizeof(int));
  int*      eid    = (int*)carve((size_t)NE * sizeof(int));
  int*      src_s  = (int*)carve((size_t)NE * sizeof(int));
  int*      counts = (int*)carve(NG * sizeof(int));
  int*      starts = (int*)carve((NG + 1) * sizeof(int));
  int*      bsums  = (int*)carve(256 * sizeof(int));

  hipMemsetAsync(d_out, 0, (size_t)out_size * sizeof(float), stream);
  hipMemsetAsync(deg, 0, NN * sizeof(int), stream);
  hist_k<<<(NE + 255) / 256, 256, 0, stream>>>(dsts, deg);
  bounds_k<<<(NN + 255) / 256, 256, 0, stream>>>(batch, starts);
  counts_from_starts_k<<<1, 64, 0, stream>>>(starts, counts);
  scan1_k<<<SCAN_B, 256, 0, stream>>>(deg, bsums);
  scan2_k<<<1, 256, 0, stream>>>(bsums);
  scan3_k<<<SCAN_B, 256, 0, stream>>>(deg, bsums, row_ptr);
  cursor_k<<<(NN + 255) / 256, 256, 0, stream>>>(row_ptr, deg);   // reuse deg as cursor
  scatter_k<<<(NE + 255) / 256, 256, 0, stream>>>(dsts, srcs, deg, eid, src_s);
  pack_ea_k<<<(NE * 2 + 255) / 256, 256, 0, stream>>>(ea, eid, eab);
  tobf_k<<<(NN * FIN + 255) / 256, 256, 0, stream>>>(x, xbh, xbl, NN * FIN);

  const unsigned short* hin_h = xbh;
  const unsigned short* hin_l = xbl;
  for (int L = 0; L < 4; L++){
    int D = (L == 0) ? FIN : EMB;
    const float *qw,*qb,*kw,*kb,*vw,*vb,*eww,*skw,*skb,*bww,*tw,*tb,*bnw,*bnb;
    if (L == 0){
      qw=c1_qw; qb=c1_qb; kw=c1_kw; kb=c1_kb; vw=c1_vw; vb=c1_vb;
      eww=c1_ew; skw=c1_skw; skb=c1_skb; bww=c1_bw; tw=c1_tw; tb=c1_tb;
      bnw=c1_bnw; bnb=c1_bnb;
    } else {
      int i = L - 1;
      qw = L_qw + (size_t)i * HCC * EMB;  qb = L_qb + (size_t)i * HCC;
      kw = L_kw + (size_t)i * HCC * EMB;  kb = L_kb + (size_t)i * HCC;
      vw = L_vw + (size_t)i * HCC * EMB;  vb = L_vb + (size_t)i * HCC;
      eww= L_ew + (size_t)i * HCC * EDIM;
      skw= L_skw+ (size_t)i * HCC * EMB;  skb= L_skb+ (size_t)i * HCC;
      bww= L_bw + (size_t)i * 3 * HCC;
      tw = L_tw + (size_t)i * EMB * HCC;  tb = L_tb + (size_t)i * EMB;
      bnw= L_bnw+ (size_t)i * EMB;        bnb= L_bnb+ (size_t)i * EMB;
    }
    pack_k<<<(512 * D + 255) / 256, 256, 0, stream>>>(qw, kw, vw, skw, qb, kb, vb, skb, Wh, Wl, bp, D);
    dim3 gg((NN + 63) / 64, 4);
    if (D == 128) gemm4_k<128><<<gg, 256, 0, stream>>>(hin_h, hin_l, Wh, Wl, bp, qf, kvb, skb_);
    else          gemm4_k<64><<<gg, 256, 0, stream>>>(hin_h, hin_l, Wh, Wl, bp, qf, kvb, skb_);
    qe_k<<<(NN + 7) / 8, 256, 0, stream>>>(qf, eww, qe);
    ewt_k<<<8, 256, 0, stream>>>(eww, ewT);
    edge_k<<<(NN * 2 * 64 + 255) / 256, 256, 0, stream>>>(qf, kvb, (const unsigned short*)eab, qe, ewT, row_ptr, src_s, attn);
    hipMemsetAsync(bn_acc, 0, 128 * sizeof(float), stream);
    combine_k<<<(NN + 15) / 16, 256, 0, stream>>>(attn, skb_, bww, tw, tb, h2, bn_acc);
    bn_final_k<<<1, 64, 0, stream>>>(bn_acc, bnw, bnb, ss);
    if (L > 0) hipMemsetAsync(gsum, 0, 2 * NG * 64 * sizeof(float), stream);
    bn_apply_k<<<256, 256, 0, stream>>>(h2, ss, batch, hbh, hbl, gsum, gmax, (L > 0) ? 1 : 0);
    if (L > 0) pool_final_k<<<(NG * 64 + 255) / 256, 256, 0, stream>>>(gsum, gmax, counts, (float*)d_out);
    hin_h = hbh; hin_l = hbl;
  }
}

// Round 11
// 1224.990 us; speedup vs baseline: 1.1498x; 1.1498x over previous
//
#include <hip/hip_runtime.h>

#define NN 50000
#define NE 800000
#define FIN 128
#define EDIM 16
#define EMB 64
#define NH 2
#define NLAYERS 3
#define NG 64
#define HCC 128
#define INV_SQRT_D 0.125f
#define EPS_BN 1e-5f
#define SCAN_B 196   // ceil(NN/256)
#define SCALE_L2E 0.18033688f   // 0.125 * log2(e)
#define NRT (NN / 16)            // 3125 row tiles (NN divisible by 16)

typedef __attribute__((ext_vector_type(8))) short bf16x8;
typedef __attribute__((ext_vector_type(4))) float f32x4;

__device__ __forceinline__ unsigned encf(float f){
  unsigned u = __float_as_uint(f);
  return (u & 0x80000000u) ? ~u : (u | 0x80000000u);
}
__device__ __forceinline__ float decf(unsigned e){
  unsigned u = (e & 0x80000000u) ? (e ^ 0x80000000u) : ~e;
  return __uint_as_float(u);
}
__device__ __forceinline__ unsigned f2bf(float x){   // RNE bf16, returned in low 16
  unsigned u = __float_as_uint(x);
  return (u + 0x7fffu + ((u >> 16) & 1u)) >> 16;
}
// split fp32 -> hi + lo bf16 (a ~= hi + lo, |lo| <= 2^-9 |a|)
__device__ __forceinline__ void f2bf_split(float x, unsigned short* hi, unsigned short* lo){
  unsigned h = f2bf(x);
  float hf = __uint_as_float(h << 16);
  *hi = (unsigned short)h;
  *lo = (unsigned short)f2bf(x - hf);
}
// fragment-major index: element (tile16, kk, lane, j) -> flat offset (in halves)
__device__ __forceinline__ size_t fragidx(int tile, int NK, int kk, int lane, int j){
  return (((size_t)tile * NK + kk) * 64 + lane) * 8 + j;
}

__global__ void hist_k(const int* __restrict__ dst, int* __restrict__ deg){
  int i = blockIdx.x * 256 + threadIdx.x;
  if (i < NE) atomicAdd(&deg[dst[i]], 1);
}

// batch_index is sorted: group starts via boundary detection, no atomics.
__global__ void bounds_k(const int* __restrict__ batch, int* __restrict__ starts){
  int i = blockIdx.x * 256 + threadIdx.x;
  if (i >= NN) return;
  int g = batch[i];
  int gp = (i == 0) ? -1 : batch[i - 1];
  for (int gg = gp + 1; gg <= g; gg++) starts[gg] = i;
  if (i == NN - 1){
    for (int gg = g + 1; gg <= NG; gg++) starts[gg] = NN;
  }
}

__global__ void counts_from_starts_k(const int* __restrict__ starts, int* __restrict__ counts){
  int g = threadIdx.x;
  if (g < NG) counts[g] = starts[g + 1] - starts[g];
}

__global__ void scan1_k(const int* __restrict__ deg, int* __restrict__ bsums){
  __shared__ int lds[256];
  int b = blockIdx.x, t = threadIdx.x;
  int idx = b * 256 + t;
  lds[t] = (idx < NN) ? deg[idx] : 0;
  __syncthreads();
  for (int off = 128; off >= 1; off >>= 1){
    if (t < off) lds[t] += lds[t + off];
    __syncthreads();
  }
  if (t == 0) bsums[b] = lds[0];
}

__global__ void scan2_k(int* __restrict__ bsums){
  __shared__ int lds[256];
  int t = threadIdx.x;
  int v = (t < SCAN_B) ? bsums[t] : 0;
  int x = v;
  lds[t] = x;
  __syncthreads();
  for (int off = 1; off < 256; off <<= 1){
    int y = (t >= off) ? lds[t - off] : 0;
    __syncthreads();
    x += y;
    lds[t] = x;
    __syncthreads();
  }
  if (t < SCAN_B) bsums[t] = x - v;   // exclusive
}

__global__ void scan3_k(const int* __restrict__ deg, const int* __restrict__ bsums,
                        int* __restrict__ row_ptr){
  __shared__ int lds[256];
  int b = blockIdx.x, t = threadIdx.x;
  int idx = b * 256 + t;
  int v = (idx < NN) ? deg[idx] : 0;
  int x = v;
  lds[t] = x;
  __syncthreads();
  for (int off = 1; off < 256; off <<= 1){
    int y = (t >= off) ? lds[t - off] : 0;
    __syncthreads();
    x += y;
    lds[t] = x;
    __syncthreads();
  }
  if (idx <= NN) row_ptr[idx] = bsums[b] + x - v;
}

__global__ void cursor_k(const int* __restrict__ row_ptr, int* __restrict__ cur){
  int i = blockIdx.x * 256 + threadIdx.x;
  if (i < NN) cur[i] = row_ptr[i];
}

__global__ void scatter_k(const int* __restrict__ dst, const int* __restrict__ src,
                          int* __restrict__ cur, int* __restrict__ eid,
                          int* __restrict__ src_s){
  int i = blockIdx.x * 256 + threadIdx.x;
  if (i < NE){
    int p = atomicAdd(&cur[dst[i]], 1);
    eid[p] = i;
    src_s[p] = src[i];
  }
}

// edge_attr -> bf16, reordered into CSR position order. thread = (p, half-row)
__global__ void pack_ea_k(const float* __restrict__ ea, const int* __restrict__ eid,
                          unsigned* __restrict__ eab){
  int i = blockIdx.x * 256 + threadIdx.x;
  if (i >= NE * 2) return;
  int p = i >> 1, half = i & 1;
  int e = eid[p];
  const float* s = ea + (size_t)e * 16 + half * 8;
  float4 a = *(const float4*)(s);
  float4 b = *(const float4*)(s + 4);
  uint4 o;
  o.x = f2bf(a.x) | (f2bf(a.y) << 16);
  o.y = f2bf(a.z) | (f2bf(a.w) << 16);
  o.z = f2bf(b.x) | (f2bf(b.y) << 16);
  o.w = f2bf(b.z) | (f2bf(b.w) << 16);
  ((uint4*)eab)[(size_t)p * 2 + half] = o;
}

// x (fp32, NN x 128) -> split bf16 in MFMA-fragment-major layout (NK=4)
__global__ void tobf2_k(const float* __restrict__ in, unsigned short* __restrict__ hi,
                        unsigned short* __restrict__ lo){
  int i = blockIdx.x * 256 + threadIdx.x;
  if (i >= NN * 128) return;
  int n = i >> 7, c = i & 127;
  int rt = n >> 4, rr = n & 15;
  int kk = c >> 5, kg = (c & 31) >> 3, j = c & 7;
  size_t idx = fragidx(rt, 4, kk, kg * 16 + rr, j);
  f2bf_split(in[i], &hi[idx], &lo[idx]);
}

// pack q/k/v/skip weights into split-bf16 FRAGMENT-MAJOR W2[tile16][kk][lane][8]
// (tile16 = global col/16, lane = kg*16 + (col&15)) + fp32 bias bp[512]
__global__ void pack2_k(const float* __restrict__ qw, const float* __restrict__ kw,
                        const float* __restrict__ vw, const float* __restrict__ skw,
                        const float* __restrict__ qb, const float* __restrict__ kb,
                        const float* __restrict__ vb, const float* __restrict__ skb,
                        unsigned short* __restrict__ W2h, unsigned short* __restrict__ W2l,
                        float* __restrict__ bp, int D){
  int i = blockIdx.x * 256 + threadIdx.x;
  int NK = D / 32;
  if (i < 512 * D){
    int c = i / D, d = i - c * D;
    const float* w = (c < 128) ? qw : (c < 256) ? kw : (c < 384) ? vw : skw;
    int tile = c >> 4, rr = c & 15;
    int kk = d >> 5, kg = (d & 31) >> 3, j = d & 7;
    size_t idx = fragidx(tile, NK, kk, kg * 16 + rr, j);
    f2bf_split(w[(c & 127) * D + d], &W2h[idx], &W2l[idx]);
  }
  if (i < 512){
    const float* b = (i < 128) ? qb : (i < 256) ? kb : (i < 384) ? vb : skb;
    bp[i] = b[i & 127];
  }
}

// qe[n, h, d] = (sum_c q[n,h,c] * ew[h*64+c, d]) * SCALE_L2E
__global__ __launch_bounds__(256) void qe_k(const float* __restrict__ qf,
    const float* __restrict__ ew, float* __restrict__ qe){
  __shared__ float ews[2048];
  int t = threadIdx.x;
  for (int i = t; i < 2048; i += 256) ews[i] = ew[i];
  __syncthreads();
  int g = t >> 5;            // node within block (8 nodes/block)
  int hd = t & 31;           // h*16 + d
  int h = hd >> 4, d = hd & 15;
  int n = blockIdx.x * 8 + g;
  if (n >= NN) return;
  const float* qp = qf + (size_t)n * 128 + h * 64;
  float s = 0.f;
  #pragma unroll 8
  for (int c = 0; c < 64; c++)
    s += qp[c] * ews[(h * 64 + c) * 16 + d];
  qe[(size_t)n * 32 + hd] = s * SCALE_L2E;
}

// ewT[h][d][c] = ew[h*64+c][d]  (transposed, for edge_k epilogue float4 loads)
__global__ void ewt_k(const float* __restrict__ ew, float* __restrict__ ewT){
  int i = blockIdx.x * 256 + threadIdx.x;
  if (i < 2048){
    int c = i >> 4, d = i & 15;          // c = h*64 + ch
    ewT[((c >> 6) * 16 + d) * 64 + (c & 63)] = ew[i];
  }
}

// Fused qkvs GEMM with FRAGMENT-MAJOR operands: every A/W fragment load is one
// coalesced 1KB transaction (lane-consecutive 16B), vs 16 strided cache lines
// before. grid = (ceil(NN/64), 4 parts):
//   part0: q -> qf ; part1: k0+v0 -> kvb ch 0..63
//   part2: k1+v1 -> kvb ch 64..127 ; part3: skip -> sk
// Split-bf16: C ~= Ah*Wh + Al*Wh + Ah*Wl.
template<int D>
__global__ __launch_bounds__(256, 4) void gemm5_k(const unsigned short* __restrict__ A2h,
                                                  const unsigned short* __restrict__ A2l,
                                                  const unsigned short* __restrict__ W2h,
                                                  const unsigned short* __restrict__ W2l,
                                                  const float* __restrict__ bp,
                                                  float* __restrict__ qf,
                                                  unsigned* __restrict__ kvb,
                                                  float* __restrict__ sk){
  const int NK = D / 32;
  int t = threadIdx.x;
  int w = t >> 6, lane = t & 63;
  int brow = blockIdx.x * 64 + w * 16;
  int part = blockIdx.y;
  int r = lane & 15, kg = lane >> 4;
  int rt = brow >> 4; if (rt > NRT - 1) rt = NRT - 1;
  int cb0 = (part == 0) ? 0 : (part == 1) ? 2 : (part == 2) ? 3 : 6;
  int cb1 = (part == 0) ? 1 : (part == 1) ? 4 : (part == 2) ? 5 : 7;
  f32x4 acc0[4], acc1[4];
  #pragma unroll
  for (int tt = 0; tt < 4; tt++){
    acc0[tt] = (f32x4){0.f,0.f,0.f,0.f};
    acc1[tt] = (f32x4){0.f,0.f,0.f,0.f};
  }
  const unsigned short* a2hp = A2h + ((size_t)rt * NK) * 512 + lane * 8;
  const unsigned short* a2lp = A2l + ((size_t)rt * NK) * 512 + lane * 8;
  #pragma unroll
  for (int kk = 0; kk < NK; kk++){
    // ---- load phase: 18 independent coalesced 16B/lane loads ----
    bf16x8 ah = *(const bf16x8*)(a2hp + kk * 512);
    bf16x8 al = *(const bf16x8*)(a2lp + kk * 512);
    bf16x8 b0h[4], b0l[4], b1h[4], b1l[4];
    #pragma unroll
    for (int tt = 0; tt < 4; tt++){
      size_t i0 = fragidx(cb0 * 4 + tt, NK, kk, lane, 0);
      size_t i1 = fragidx(cb1 * 4 + tt, NK, kk, lane, 0);
      b0h[tt] = *(const bf16x8*)(W2h + i0);
      b0l[tt] = *(const bf16x8*)(W2l + i0);
      b1h[tt] = *(const bf16x8*)(W2h + i1);
      b1l[tt] = *(const bf16x8*)(W2l + i1);
    }
    // ---- compute phase: 24 MFMAs on 8 independent accumulator chains ----
    #pragma unroll
    for (int tt = 0; tt < 4; tt++){
      acc0[tt] = __builtin_amdgcn_mfma_f32_16x16x32_bf16(ah, b0h[tt], acc0[tt], 0, 0, 0);
      acc1[tt] = __builtin_amdgcn_mfma_f32_16x16x32_bf16(ah, b1h[tt], acc1[tt], 0, 0, 0);
      acc0[tt] = __builtin_amdgcn_mfma_f32_16x16x32_bf16(al, b0h[tt], acc0[tt], 0, 0, 0);
      acc1[tt] = __builtin_amdgcn_mfma_f32_16x16x32_bf16(al, b1h[tt], acc1[tt], 0, 0, 0);
      acc0[tt] = __builtin_amdgcn_mfma_f32_16x16x32_bf16(ah, b0l[tt], acc0[tt], 0, 0, 0);
      acc1[tt] = __builtin_amdgcn_mfma_f32_16x16x32_bf16(ah, b1l[tt], acc1[tt], 0, 0, 0);
    }
  }
  int rowbase = brow + kg * 4;
  if (part == 0){
    #pragma unroll
    for (int tt = 0; tt < 4; tt++){
      int ch0 = tt * 16 + r, ch1 = 64 + tt * 16 + r;
      float b0 = bp[ch0], b1 = bp[ch1];
      #pragma unroll
      for (int j = 0; j < 4; j++){
        int row = rowbase + j;
        if (row < NN){
          qf[(size_t)row * 128 + ch0] = acc0[tt][j] + b0;
          qf[(size_t)row * 128 + ch1] = acc1[tt][j] + b1;
        }
      }
    }
  } else if (part == 3){
    #pragma unroll
    for (int tt = 0; tt < 4; tt++){
      int ch0 = tt * 16 + r, ch1 = 64 + tt * 16 + r;
      float b0 = bp[384 + ch0], b1 = bp[384 + ch1];
      #pragma unroll
      for (int j = 0; j < 4; j++){
        int row = rowbase + j;
        if (row < NN){
          sk[(size_t)row * 128 + ch0] = acc0[tt][j] + b0;
          sk[(size_t)row * 128 + ch1] = acc1[tt][j] + b1;
        }
      }
    }
  } else {
    int chbase = (part - 1) * 64;
    #pragma unroll
    for (int tt = 0; tt < 4; tt++){
      int ch = chbase + tt * 16 + r;
      float bk = bp[cb0 * 64 + tt * 16 + r];
      float bv = bp[cb1 * 64 + tt * 16 + r];
      #pragma unroll
      for (int j = 0; j < 4; j++){
        int row = rowbase + j;
        if (row < NN){
          float kk4 = acc0[tt][j] + bk;
          float vv = acc1[tt][j] + bv;
          kvb[(size_t)row * 128 + ch] = f2bf(kk4) | (f2bf(vv) << 16);
        }
      }
    }
  }
}

// One wave per (node, head). 4 edges per wave iteration: 16 lanes per edge
// (grp = lane>>4 picks the edge, l = lane&15 picks 4 channels 4l..4l+3).
__global__ __launch_bounds__(256) void edge_k(const float* __restrict__ qf,
    const unsigned* __restrict__ kvb, const unsigned short* __restrict__ eab_us,
    const float* __restrict__ qe, const float* __restrict__ ewT,
    const int* __restrict__ row_ptr, const int* __restrict__ src_s,
    float* __restrict__ attn){
  int wv = (blockIdx.x * 256 + threadIdx.x) >> 6;
  if (wv >= NN * 2) return;
  int lane = threadIdx.x & 63;
  int n = wv >> 1, h = wv & 1;
  int grp = lane >> 4, l = lane & 15;
  float4 qv = *(const float4*)(qf + (size_t)n * 128 + h * 64 + 4 * l);
  float q0 = qv.x * SCALE_L2E, q1 = qv.y * SCALE_L2E;
  float q2 = qv.z * SCALE_L2E, q3 = qv.w * SCALE_L2E;
  float qel = qe[(size_t)n * 32 + h * 16 + l];
  int beg = row_ptr[n], end = row_ptr[n + 1];
  int nb = end - beg;
  float a0 = 0.f, a1 = 0.f, a2 = 0.f, a3 = 0.f, den = 0.f, tl = 0.f;
  int hoff = h * 64 + 4 * l;
  for (int cb = 0; cb < nb; cb += 64){
    int sv = (cb + lane < nb) ? src_s[beg + cb + lane] : 0;
    int m = min(64, nb - cb);
    for (int u = 0; u < m; u += 8){
      int eA = u + grp, eB = u + 4 + grp;        // both < 64 (u <= 56)
      int sA = __shfl(sv, eA);
      int sB = __shfl(sv, eB);
      uint4 kvA = *(const uint4*)(kvb + (size_t)sA * 128 + hoff);
      uint4 kvB = *(const uint4*)(kvb + (size_t)sB * 128 + hoff);
      size_t gA = (size_t)(beg + cb + eA); if (gA >= NE) gA = NE - 1;
      size_t gB = (size_t)(beg + cb + eB); if (gB >= NE) gB = NE - 1;
      unsigned short eaAu = eab_us[gA * 16 + l];
      unsigned short eaBu = eab_us[gB * 16 + l];
      {
        float eaf = __uint_as_float((unsigned)eaAu << 16);
        float k0 = __uint_as_float(kvA.x << 16), v0 = __uint_as_float(kvA.x & 0xffff0000u);
        float k1 = __uint_as_float(kvA.y << 16), v1 = __uint_as_float(kvA.y & 0xffff0000u);
        float k2 = __uint_as_float(kvA.z << 16), v2 = __uint_as_float(kvA.z & 0xffff0000u);
        float k3 = __uint_as_float(kvA.w << 16), v3 = __uint_as_float(kvA.w & 0xffff0000u);
        float p = fmaf(q0, k0, fmaf(q1, k1, fmaf(q2, k2, fmaf(q3, k3, qel * eaf))));
        p += __shfl_xor(p, 1); p += __shfl_xor(p, 2);
        p += __shfl_xor(p, 4); p += __shfl_xor(p, 8);
        float w = exp2f(p);
        if (eA >= m) w = 0.f;
        a0 = fmaf(v0, w, a0); a1 = fmaf(v1, w, a1);
        a2 = fmaf(v2, w, a2); a3 = fmaf(v3, w, a3);
        den += w; tl = fmaf(eaf, w, tl);
      }
      {
        float eaf = __uint_as_float((unsigned)eaBu << 16);
        float k0 = __uint_as_float(kvB.x << 16), v0 = __uint_as_float(kvB.x & 0xffff0000u);
        float k1 = __uint_as_float(kvB.y << 16), v1 = __uint_as_float(kvB.y & 0xffff0000u);
        float k2 = __uint_as_float(kvB.z << 16), v2 = __uint_as_float(kvB.z & 0xffff0000u);
        float k3 = __uint_as_float(kvB.w << 16), v3 = __uint_as_float(kvB.w & 0xffff0000u);
        float p = fmaf(q0, k0, fmaf(q1, k1, fmaf(q2, k2, fmaf(q3, k3, qel * eaf))));
        p += __shfl_xor(p, 1); p += __shfl_xor(p, 2);
        p += __shfl_xor(p, 4); p += __shfl_xor(p, 8);
        float w = exp2f(p);
        if (eB >= m) w = 0.f;
        a0 = fmaf(v0, w, a0); a1 = fmaf(v1, w, a1);
        a2 = fmaf(v2, w, a2); a3 = fmaf(v3, w, a3);
        den += w; tl = fmaf(eaf, w, tl);
      }
    }
  }
  a0 += __shfl_xor(a0, 16); a0 += __shfl_xor(a0, 32);
  a1 += __shfl_xor(a1, 16); a1 += __shfl_xor(a1, 32);
  a2 += __shfl_xor(a2, 16); a2 += __shfl_xor(a2, 32);
  a3 += __shfl_xor(a3, 16); a3 += __shfl_xor(a3, 32);
  den += __shfl_xor(den, 16); den += __shfl_xor(den, 32);
  tl  += __shfl_xor(tl, 16);  tl  += __shfl_xor(tl, 32);
  float e0 = 0.f, e1 = 0.f, e2 = 0.f, e3 = 0.f;
  const float* ewp = ewT + (size_t)h * 16 * 64 + 4 * l;
  #pragma unroll
  for (int d = 0; d < 16; d++){
    float td = __shfl(tl, d);
    float4 w4 = *(const float4*)(ewp + d * 64);
    e0 = fmaf(w4.x, td, e0); e1 = fmaf(w4.y, td, e1);
    e2 = fmaf(w4.z, td, e2); e3 = fmaf(w4.w, td, e3);
  }
  float inv = den > 0.f ? 1.f / den : 0.f;
  float4 o;
  o.x = (a0 + e0) * inv; o.y = (a1 + e1) * inv;
  o.z = (a2 + e2) * inv; o.w = (a3 + e3) * inv;
  *(float4*)(attn + (size_t)n * 128 + h * 64 + 4 * l) = o;
}

// beta-gate combine + [128->64] proj + leaky relu + BN partial sums.
__global__ __launch_bounds__(256) void combine_k(const float* __restrict__ attn,
    const float* __restrict__ sk, const float* __restrict__ bw,
    const float* __restrict__ tw, const float* __restrict__ tb,
    float* __restrict__ h2, float* __restrict__ bn_acc){
  __shared__ float twT[128][65];
  __shared__ float hcs[4][128];
  __shared__ float bsum[64], bsq[64];
  int t = threadIdx.x;
  int lane = t & 63, wv = t >> 6;
  for (int i = t; i < 64 * 128; i += 256){
    int j = i >> 7, k = i & 127;
    twT[k][j] = tw[i];
  }
  if (t < 64){ bsum[t] = 0.f; bsq[t] = 0.f; }
  __syncthreads();
  float bw0 = bw[lane],       bw1 = bw[64 + lane];
  float bwr0 = bw[128 + lane], bwr1 = bw[192 + lane];
  float bwd0 = bw[256 + lane], bwd1 = bw[320 + lane];
  float tbv = tb[lane];
  float rs = 0.f, rq = 0.f;
  int base_node = blockIdx.x * 16 + wv * 4;
  for (int it = 0; it < 4; it++){
    int n = base_node + it;
    bool valid = n < NN;
    float o0 = 0.f, o1 = 0.f, r0 = 0.f, r1 = 0.f;
    if (valid){
      o0 = attn[(size_t)n * 128 + lane];
      o1 = attn[(size_t)n * 128 + 64 + lane];
      r0 = sk[(size_t)n * 128 + lane];
      r1 = sk[(size_t)n * 128 + 64 + lane];
    }
    float p = o0 * bw0 + o1 * bw1 + r0 * bwr0 + r1 * bwr1 + (o0 - r0) * bwd0 + (o1 - r1) * bwd1;
    #pragma unroll
    for (int off = 32; off >= 1; off >>= 1) p += __shfl_xor(p, off);
    float beta = 1.f / (1.f + __expf(-p));
    float hc0 = beta * r0 + (1.f - beta) * o0;
    float hc1 = beta * r1 + (1.f - beta) * o1;
    hcs[wv][lane] = hc0;
    hcs[wv][64 + lane] = hc1;
    __syncthreads();
    float s = tbv;
    #pragma unroll 8
    for (int k = 0; k < 128; k++) s += hcs[wv][k] * twT[k][lane];
    __syncthreads();
    if (valid){
      float hv = s > 0.f ? s : 0.01f * s;
      h2[(size_t)n * 64 + lane] = hv;
      rs += hv; rq += hv * hv;
    }
  }
  atomicAdd(&bsum[lane], rs);
  atomicAdd(&bsq[lane], rq);
  __syncthreads();
  if (t < 64){
    atomicAdd(&bn_acc[t], bsum[t]);
    atomicAdd(&bn_acc[64 + t], bsq[t]);
  }
}

__global__ void bn_final_k(const float* __restrict__ bn_acc, const float* __restrict__ bnw,
                           const float* __restrict__ bnb, float* __restrict__ ss){
  int j = threadIdx.x;
  if (j < 64){
    float m = bn_acc[j] / (float)NN;
    float v = bn_acc[64 + j] / (float)NN - m * m;
    float sc = bnw[j] * rsqrtf(v + EPS_BN);
    ss[j] = sc;
    ss[64 + j] = bnb[j] - m * sc;
  }
}

// BN apply -> split bf16 h in FRAGMENT-MAJOR layout (NK=2) + pooled max/sum
__global__ __launch_bounds__(256) void bn_apply_k(const float* __restrict__ h2,
    const float* __restrict__ ss, const int* __restrict__ batch,
    unsigned short* __restrict__ hbh, unsigned short* __restrict__ hbl,
    float* __restrict__ gsum, unsigned* __restrict__ gmax,
    int do_pool){
  int wid = (blockIdx.x * 256 + threadIdx.x) >> 6;
  int lane = threadIdx.x & 63;
  const int CH = (NN + 1023) / 1024;
  int start = wid * CH;
  int end = start + CH; if (end > NN) end = NN;
  float sc = ss[lane], sh = ss[64 + lane];
  int kk = lane >> 5, kg = (lane & 31) >> 3, j = lane & 7;
  int curg = -1; float lmax = 0.f, lsum = 0.f;
  for (int n = start; n < end; n++){
    float v = h2[(size_t)n * 64 + lane] * sc + sh;
    size_t idx = fragidx((n >> 4), 2, kk, kg * 16 + (n & 15), j);
    f2bf_split(v, &hbh[idx], &hbl[idx]);
    if (do_pool){
      int g = batch[n];
      if (g != curg){
        if (curg >= 0){
          atomicAdd(&gsum[curg * 64 + lane], lsum);
          atomicMax(&gmax[curg * 64 + lane], encf(lmax));
        }
        curg = g; lmax = v; lsum = v;
      } else {
        lmax = fmaxf(lmax, v); lsum += v;
      }
    }
  }
  if (do_pool && curg >= 0){
    atomicAdd(&gsum[curg * 64 + lane], lsum);
    atomicMax(&gmax[curg * 64 + lane], encf(lmax));
  }
}

__global__ void pool_final_k(const float* __restrict__ gsum, const unsigned* __restrict__ gmax,
                             const int* __restrict__ counts, float* __restrict__ gr){
  int i = blockIdx.x * 256 + threadIdx.x;
  if (i < NG * 64){
    int g = i >> 6, j = i & 63;
    unsigned e = gmax[i];
    float mx = e ? decf(e) : 0.f;
    int c = counts[g]; if (c < 1) c = 1;
    gr[g * 128 + j]       += mx;
    gr[g * 128 + 64 + j]  += gsum[i] / (float)c;
  }
}

extern "C" void kernel_launch(void* const* d_in, const int* in_sizes, int n_in,
                              void* d_out, int out_size, void* d_ws, size_t ws_size,
                              hipStream_t stream){
  const float* x     = (const float*)d_in[0];
  const float* ea    = (const float*)d_in[1];
  const int*   eidx  = (const int*)d_in[2];
  const int*   batch = (const int*)d_in[3];
  const float* c1_qw = (const float*)d_in[4];
  const float* c1_qb = (const float*)d_in[5];
  const float* c1_kw = (const float*)d_in[6];
  const float* c1_kb = (const float*)d_in[7];
  const float* c1_vw = (const float*)d_in[8];
  const float* c1_vb = (const float*)d_in[9];
  const float* c1_ew = (const float*)d_in[10];
  const float* c1_skw= (const float*)d_in[11];
  const float* c1_skb= (const float*)d_in[12];
  const float* c1_bw = (const float*)d_in[13];
  const float* c1_tw = (const float*)d_in[14];
  const float* c1_tb = (const float*)d_in[15];
  const float* c1_bnw= (const float*)d_in[16];
  const float* c1_bnb= (const float*)d_in[17];
  const float* L_qw  = (const float*)d_in[18];
  const float* L_qb  = (const float*)d_in[19];
  const float* L_kw  = (const float*)d_in[20];
  const float* L_kb  = (const float*)d_in[21];
  const float* L_vw  = (const float*)d_in[22];
  const float* L_vb  = (const float*)d_in[23];
  const float* L_ew  = (const float*)d_in[24];
  const float* L_skw = (const float*)d_in[25];
  const float* L_skb = (const float*)d_in[26];
  const float* L_bw  = (const float*)d_in[27];
  const float* L_tw  = (const float*)d_in[28];
  const float* L_tb  = (const float*)d_in[29];
  const float* L_bnw = (const float*)d_in[30];
  const float* L_bnb = (const float*)d_in[31];
  const int* srcs = eidx;
  const int* dsts = eidx + NE;

  char* p = (char*)d_ws;
  auto carve = [&](size_t bytes) -> void* {
    void* r = (void*)p;
    p += (bytes + 255) & ~(size_t)255;
    return r;
  };
  unsigned short* Wh = (unsigned short*)carve(512 * 128 * sizeof(unsigned short));
  unsigned short* Wl = (unsigned short*)carve(512 * 128 * sizeof(unsigned short));
  float*    bp     = (float*)carve(512 * sizeof(float));
  float*    qf     = (float*)carve((size_t)NN * 128 * sizeof(float));
  float*    skb_   = (float*)carve((size_t)NN * 128 * sizeof(float));
  unsigned* kvb    = (unsigned*)carve((size_t)NN * 128 * sizeof(unsigned));
  unsigned* eab    = (unsigned*)carve((size_t)NE * 8 * sizeof(unsigned));
  float*    qe     = (float*)carve((size_t)NN * 32 * sizeof(float));
  float*    ewT    = (float*)carve(2048 * sizeof(float));
  float*    attn   = (float*)carve((size_t)NN * 128 * sizeof(float));
  unsigned short* xbh = (unsigned short*)carve((size_t)NN * FIN * sizeof(unsigned short));
  unsigned short* xbl = (unsigned short*)carve((size_t)NN * FIN * sizeof(unsigned short));
  unsigned short* hbh = (unsigned short*)carve((size_t)NN * 64 * sizeof(unsigned short));
  unsigned short* hbl = (unsigned short*)carve((size_t)NN * 64 * sizeof(unsigned short));
  float*    h2     = (float*)carve((size_t)NN * 64 * sizeof(float));
  float*    bn_acc = (float*)carve(128 * sizeof(float));
  float*    ss     = (float*)carve(128 * sizeof(float));
  float*    gsum   = (float*)carve((size_t)NG * 64 * sizeof(float));
  unsigned* gmax   = (unsigned*)carve((size_t)NG * 64 * sizeof(unsigned));
  int*      deg    = (int*)carve(NN * sizeof(int));
  int*      row_ptr= (int*)carve((NN + 1) * sizeof(int));
  int*      eid    = (int*)carve((size_t)NE * sizeof(int));
  int*      src_s  = (int*)carve((size_t)NE * sizeof(int));
  int*      counts = (int*)carve(NG * sizeof(int));
  int*      starts = (int*)carve((NG + 1) * sizeof(int));
  int*      bsums  = (int*)carve(256 * sizeof(int));

  hipMemsetAsync(d_out, 0, (size_t)out_size * sizeof(float), stream);
  hipMemsetAsync(deg, 0, NN * sizeof(int), stream);
  hist_k<<<(NE + 255) / 256, 256, 0, stream>>>(dsts, deg);
  bounds_k<<<(NN + 255) / 256, 256, 0, stream>>>(batch, starts);
  counts_from_starts_k<<<1, 64, 0, stream>>>(starts, counts);
  scan1_k<<<SCAN_B, 256, 0, stream>>>(deg, bsums);
  scan2_k<<<1, 256, 0, stream>>>(bsums);
  scan3_k<<<SCAN_B, 256, 0, stream>>>(deg, bsums, row_ptr);
  cursor_k<<<(NN + 255) / 256, 256, 0, stream>>>(row_ptr, deg);   // reuse deg as cursor
  scatter_k<<<(NE + 255) / 256, 256, 0, stream>>>(dsts, srcs, deg, eid, src_s);
  pack_ea_k<<<(NE * 2 + 255) / 256, 256, 0, stream>>>(ea, eid, eab);
  tobf2_k<<<(NN * FIN + 255) / 256, 256, 0, stream>>>(x, xbh, xbl);

  const unsigned short* hin_h = xbh;
  const unsigned short* hin_l = xbl;
  for (int L = 0; L < 4; L++){
    int D = (L == 0) ? FIN : EMB;
    const float *qw,*qb,*kw,*kb,*vw,*vb,*eww,*skw,*skb,*bww,*tw,*tb,*bnw,*bnb;
    if (L == 0){
      qw=c1_qw; qb=c1_qb; kw=c1_kw; kb=c1_kb; vw=c1_vw; vb=c1_vb;
      eww=c1_ew; skw=c1_skw; skb=c1_skb; bww=c1_bw; tw=c1_tw; tb=c1_tb;
      bnw=c1_bnw; bnb=c1_bnb;
    } else {
      int i = L - 1;
      qw = L_qw + (size_t)i * HCC * EMB;  qb = L_qb + (size_t)i * HCC;
      kw = L_kw + (size_t)i * HCC * EMB;  kb = L_kb + (size_t)i * HCC;
      vw = L_vw + (size_t)i * HCC * EMB;  vb = L_vb + (size_t)i * HCC;
      eww= L_ew + (size_t)i * HCC * EDIM;
      skw= L_skw+ (size_t)i * HCC * EMB;  skb= L_skb+ (size_t)i * HCC;
      bww= L_bw + (size_t)i * 3 * HCC;
      tw = L_tw + (size_t)i * EMB * HCC;  tb = L_tb + (size_t)i * EMB;
      bnw= L_bnw+ (size_t)i * EMB;        bnb= L_bnb+ (size_t)i * EMB;
    }
    pack2_k<<<(512 * D + 255) / 256, 256, 0, stream>>>(qw, kw, vw, skw, qb, kb, vb, skb, Wh, Wl, bp, D);
    dim3 gg((NN + 63) / 64, 4);
    if (D == 128) gemm5_k<128><<<gg, 256, 0, stream>>>(hin_h, hin_l, Wh, Wl, bp, qf, kvb, skb_);
    else          gemm5_k<64><<<gg, 256, 0, stream>>>(hin_h, hin_l, Wh, Wl, bp, qf, kvb, skb_);
    qe_k<<<(NN + 7) / 8, 256, 0, stream>>>(qf, eww, qe);
    ewt_k<<<8, 256, 0, stream>>>(eww, ewT);
    edge_k<<<(NN * 2 * 64 + 255) / 256, 256, 0, stream>>>(qf, kvb, (const unsigned short*)eab, qe, ewT, row_ptr, src_s, attn);
    hipMemsetAsync(bn_acc, 0, 128 * sizeof(float), stream);
    combine_k<<<(NN + 15) / 16, 256, 0, stream>>>(attn, skb_, bww, tw, tb, h2, bn_acc);
    bn_final_k<<<1, 64, 0, stream>>>(bn_acc, bnw, bnb, ss);
    if (L > 0) hipMemsetAsync(gsum, 0, 2 * NG * 64 * sizeof(float), stream);
    bn_apply_k<<<256, 256, 0, stream>>>(h2, ss, batch, hbh, hbl, gsum, gmax, (L > 0) ? 1 : 0);
    if (L > 0) pool_final_k<<<(NG * 64 + 255) / 256, 256, 0, stream>>>(gsum, gmax, counts, (float*)d_out);
    hin_h = hbh; hin_l = hbl;
  }
}

// Round 12
// 979.936 us; speedup vs baseline: 1.4373x; 1.2501x over previous
//
#include <hip/hip_runtime.h>

#define NN 50000
#define NE 800000
#define FIN 128
#define EDIM 16
#define EMB 64
#define NH 2
#define NLAYERS 3
#define NG 64
#define HCC 128
#define INV_SQRT_D 0.125f
#define EPS_BN 1e-5f
#define SCAN_B 196   // ceil(NN/256)
#define SCALE_L2E 0.18033688f   // 0.125 * log2(e)
#define NRT (NN / 16)            // 3125 row tiles

typedef __attribute__((ext_vector_type(8))) short bf16x8;
typedef __attribute__((ext_vector_type(4))) float f32x4;

__device__ __forceinline__ unsigned encf(float f){
  unsigned u = __float_as_uint(f);
  return (u & 0x80000000u) ? ~u : (u | 0x80000000u);
}
__device__ __forceinline__ float decf(unsigned e){
  unsigned u = (e & 0x80000000u) ? (e ^ 0x80000000u) : ~e;
  return __uint_as_float(u);
}
__device__ __forceinline__ unsigned f2bf(float x){   // RNE bf16, returned in low 16
  unsigned u = __float_as_uint(x);
  return (u + 0x7fffu + ((u >> 16) & 1u)) >> 16;
}
// split fp32 -> hi + lo bf16 (a ~= hi + lo, |lo| <= 2^-9 |a|)
__device__ __forceinline__ void f2bf_split(float x, unsigned short* hi, unsigned short* lo){
  unsigned h = f2bf(x);
  float hf = __uint_as_float(h << 16);
  *hi = (unsigned short)h;
  *lo = (unsigned short)f2bf(x - hf);
}
// fragment-major index: element (tile16, kk, lane, j) -> flat offset (in halves)
__device__ __forceinline__ size_t fragidx(int tile, int NK, int kk, int lane, int j){
  return (((size_t)tile * NK + kk) * 64 + lane) * 8 + j;
}

__global__ void hist_k(const int* __restrict__ dst, int* __restrict__ deg){
  int i = blockIdx.x * 256 + threadIdx.x;
  if (i < NE) atomicAdd(&deg[dst[i]], 1);
}

// batch_index is sorted: group starts via boundary detection, no atomics.
__global__ void bounds_k(const int* __restrict__ batch, int* __restrict__ starts){
  int i = blockIdx.x * 256 + threadIdx.x;
  if (i >= NN) return;
  int g = batch[i];
  int gp = (i == 0) ? -1 : batch[i - 1];
  for (int gg = gp + 1; gg <= g; gg++) starts[gg] = i;
  if (i == NN - 1){
    for (int gg = g + 1; gg <= NG; gg++) starts[gg] = NN;
  }
}

__global__ void counts_from_starts_k(const int* __restrict__ starts, int* __restrict__ counts){
  int g = threadIdx.x;
  if (g < NG) counts[g] = starts[g + 1] - starts[g];
}

__global__ void scan1_k(const int* __restrict__ deg, int* __restrict__ bsums){
  __shared__ int lds[256];
  int b = blockIdx.x, t = threadIdx.x;
  int idx = b * 256 + t;
  lds[t] = (idx < NN) ? deg[idx] : 0;
  __syncthreads();
  for (int off = 128; off >= 1; off >>= 1){
    if (t < off) lds[t] += lds[t + off];
    __syncthreads();
  }
  if (t == 0) bsums[b] = lds[0];
}

__global__ void scan2_k(int* __restrict__ bsums){
  __shared__ int lds[256];
  int t = threadIdx.x;
  int v = (t < SCAN_B) ? bsums[t] : 0;
  int x = v;
  lds[t] = x;
  __syncthreads();
  for (int off = 1; off < 256; off <<= 1){
    int y = (t >= off) ? lds[t - off] : 0;
    __syncthreads();
    x += y;
    lds[t] = x;
    __syncthreads();
  }
  if (t < SCAN_B) bsums[t] = x - v;   // exclusive
}

__global__ void scan3_k(const int* __restrict__ deg, const int* __restrict__ bsums,
                        int* __restrict__ row_ptr){
  __shared__ int lds[256];
  int b = blockIdx.x, t = threadIdx.x;
  int idx = b * 256 + t;
  int v = (idx < NN) ? deg[idx] : 0;
  int x = v;
  lds[t] = x;
  __syncthreads();
  for (int off = 1; off < 256; off <<= 1){
    int y = (t >= off) ? lds[t - off] : 0;
    __syncthreads();
    x += y;
    lds[t] = x;
    __syncthreads();
  }
  if (idx <= NN) row_ptr[idx] = bsums[b] + x - v;
}

__global__ void cursor_k(const int* __restrict__ row_ptr, int* __restrict__ cur){
  int i = blockIdx.x * 256 + threadIdx.x;
  if (i < NN) cur[i] = row_ptr[i];
}

__global__ void scatter_k(const int* __restrict__ dst, const int* __restrict__ src,
                          int* __restrict__ cur, int* __restrict__ eid,
                          int* __restrict__ src_s){
  int i = blockIdx.x * 256 + threadIdx.x;
  if (i < NE){
    int p = atomicAdd(&cur[dst[i]], 1);
    eid[p] = i;
    src_s[p] = src[i];
  }
}

// edge_attr -> bf16, reordered into CSR position order. thread = (p, half-row)
__global__ void pack_ea_k(const float* __restrict__ ea, const int* __restrict__ eid,
                          unsigned* __restrict__ eab){
  int i = blockIdx.x * 256 + threadIdx.x;
  if (i >= NE * 2) return;
  int p = i >> 1, half = i & 1;
  int e = eid[p];
  const float* s = ea + (size_t)e * 16 + half * 8;
  float4 a = *(const float4*)(s);
  float4 b = *(const float4*)(s + 4);
  uint4 o;
  o.x = f2bf(a.x) | (f2bf(a.y) << 16);
  o.y = f2bf(a.z) | (f2bf(a.w) << 16);
  o.z = f2bf(b.x) | (f2bf(b.y) << 16);
  o.w = f2bf(b.z) | (f2bf(b.w) << 16);
  ((uint4*)eab)[(size_t)p * 2 + half] = o;
}

// x (fp32, NN x 128) -> split bf16 in MFMA-fragment-major layout (NK=4)
__global__ void tobf2_k(const float* __restrict__ in, unsigned short* __restrict__ hi,
                        unsigned short* __restrict__ lo){
  int i = blockIdx.x * 256 + threadIdx.x;
  if (i >= NN * 128) return;
  int n = i >> 7, c = i & 127;
  int rt = n >> 4, rr = n & 15;
  int kk = c >> 5, kg = (c & 31) >> 3, j = c & 7;
  size_t idx = fragidx(rt, 4, kk, kg * 16 + rr, j);
  f2bf_split(in[i], &hi[idx], &lo[idx]);
}

// pack q/k/v/skip weights into split-bf16 FRAGMENT-MAJOR W2 + fp32 bias bp[512]
__global__ void pack2_k(const float* __restrict__ qw, const float* __restrict__ kw,
                        const float* __restrict__ vw, const float* __restrict__ skw,
                        const float* __restrict__ qb, const float* __restrict__ kb,
                        const float* __restrict__ vb, const float* __restrict__ skb,
                        unsigned short* __restrict__ W2h, unsigned short* __restrict__ W2l,
                        float* __restrict__ bp, int D){
  int i = blockIdx.x * 256 + threadIdx.x;
  int NK = D / 32;
  if (i < 512 * D){
    int c = i / D, d = i - c * D;
    const float* w = (c < 128) ? qw : (c < 256) ? kw : (c < 384) ? vw : skw;
    int tile = c >> 4, rr = c & 15;
    int kk = d >> 5, kg = (d & 31) >> 3, j = d & 7;
    size_t idx = fragidx(tile, NK, kk, kg * 16 + rr, j);
    f2bf_split(w[(c & 127) * D + d], &W2h[idx], &W2l[idx]);
  }
  if (i < 512){
    const float* b = (i < 128) ? qb : (i < 256) ? kb : (i < 384) ? vb : skb;
    bp[i] = b[i & 127];
  }
}

// tw [64][128] -> split-bf16 fragment-major (4 col tiles, NK=4)
__global__ void pack_tw_k(const float* __restrict__ tw, unsigned short* __restrict__ twh,
                          unsigned short* __restrict__ twl){
  int i = blockIdx.x * 256 + threadIdx.x;
  if (i >= 64 * 128) return;
  int col = i >> 7, k = i & 127;
  int ct = col >> 4, rr = col & 15;
  int kk = k >> 5, kg = (k & 31) >> 3, j = k & 7;
  size_t idx = fragidx(ct, 4, kk, kg * 16 + rr, j);
  f2bf_split(tw[i], &twh[idx], &twl[idx]);
}

// qe[n, h, d] = (sum_c q[n,h,c] * ew[h*64+c, d]) * SCALE_L2E
__global__ __launch_bounds__(256) void qe_k(const float* __restrict__ qf,
    const float* __restrict__ ew, float* __restrict__ qe){
  __shared__ float ews[2048];
  int t = threadIdx.x;
  for (int i = t; i < 2048; i += 256) ews[i] = ew[i];
  __syncthreads();
  int g = t >> 5;
  int hd = t & 31;
  int h = hd >> 4, d = hd & 15;
  int n = blockIdx.x * 8 + g;
  if (n >= NN) return;
  const float* qp = qf + (size_t)n * 128 + h * 64;
  float s = 0.f;
  #pragma unroll 8
  for (int c = 0; c < 64; c++)
    s += qp[c] * ews[(h * 64 + c) * 16 + d];
  qe[(size_t)n * 32 + hd] = s * SCALE_L2E;
}

// ewT[h][d][c] = ew[h*64+c][d]
__global__ void ewt_k(const float* __restrict__ ew, float* __restrict__ ewT){
  int i = blockIdx.x * 256 + threadIdx.x;
  if (i < 2048){
    int c = i >> 4, d = i & 15;
    ewT[((c >> 6) * 16 + d) * 64 + (c & 63)] = ew[i];
  }
}

// Fused qkvs GEMM with FRAGMENT-MAJOR operands (round-11 version, unchanged).
template<int D>
__global__ __launch_bounds__(256, 4) void gemm5_k(const unsigned short* __restrict__ A2h,
                                                  const unsigned short* __restrict__ A2l,
                                                  const unsigned short* __restrict__ W2h,
                                                  const unsigned short* __restrict__ W2l,
                                                  const float* __restrict__ bp,
                                                  float* __restrict__ qf,
                                                  unsigned* __restrict__ kvb,
                                                  float* __restrict__ sk){
  const int NK = D / 32;
  int t = threadIdx.x;
  int w = t >> 6, lane = t & 63;
  int brow = blockIdx.x * 64 + w * 16;
  int part = blockIdx.y;
  int r = lane & 15, kg = lane >> 4;
  int rt = brow >> 4; if (rt > NRT - 1) rt = NRT - 1;
  int cb0 = (part == 0) ? 0 : (part == 1) ? 2 : (part == 2) ? 3 : 6;
  int cb1 = (part == 0) ? 1 : (part == 1) ? 4 : (part == 2) ? 5 : 7;
  f32x4 acc0[4], acc1[4];
  #pragma unroll
  for (int tt = 0; tt < 4; tt++){
    acc0[tt] = (f32x4){0.f,0.f,0.f,0.f};
    acc1[tt] = (f32x4){0.f,0.f,0.f,0.f};
  }
  const unsigned short* a2hp = A2h + ((size_t)rt * NK) * 512 + lane * 8;
  const unsigned short* a2lp = A2l + ((size_t)rt * NK) * 512 + lane * 8;
  #pragma unroll
  for (int kk = 0; kk < NK; kk++){
    bf16x8 ah = *(const bf16x8*)(a2hp + kk * 512);
    bf16x8 al = *(const bf16x8*)(a2lp + kk * 512);
    bf16x8 b0h[4], b0l[4], b1h[4], b1l[4];
    #pragma unroll
    for (int tt = 0; tt < 4; tt++){
      size_t i0 = fragidx(cb0 * 4 + tt, NK, kk, lane, 0);
      size_t i1 = fragidx(cb1 * 4 + tt, NK, kk, lane, 0);
      b0h[tt] = *(const bf16x8*)(W2h + i0);
      b0l[tt] = *(const bf16x8*)(W2l + i0);
      b1h[tt] = *(const bf16x8*)(W2h + i1);
      b1l[tt] = *(const bf16x8*)(W2l + i1);
    }
    #pragma unroll
    for (int tt = 0; tt < 4; tt++){
      acc0[tt] = __builtin_amdgcn_mfma_f32_16x16x32_bf16(ah, b0h[tt], acc0[tt], 0, 0, 0);
      acc1[tt] = __builtin_amdgcn_mfma_f32_16x16x32_bf16(ah, b1h[tt], acc1[tt], 0, 0, 0);
      acc0[tt] = __builtin_amdgcn_mfma_f32_16x16x32_bf16(al, b0h[tt], acc0[tt], 0, 0, 0);
      acc1[tt] = __builtin_amdgcn_mfma_f32_16x16x32_bf16(al, b1h[tt], acc1[tt], 0, 0, 0);
      acc0[tt] = __builtin_amdgcn_mfma_f32_16x16x32_bf16(ah, b0l[tt], acc0[tt], 0, 0, 0);
      acc1[tt] = __builtin_amdgcn_mfma_f32_16x16x32_bf16(ah, b1l[tt], acc1[tt], 0, 0, 0);
    }
  }
  int rowbase = brow + kg * 4;
  if (part == 0){
    #pragma unroll
    for (int tt = 0; tt < 4; tt++){
      int ch0 = tt * 16 + r, ch1 = 64 + tt * 16 + r;
      float b0 = bp[ch0], b1 = bp[ch1];
      #pragma unroll
      for (int j = 0; j < 4; j++){
        int row = rowbase + j;
        if (row < NN){
          qf[(size_t)row * 128 + ch0] = acc0[tt][j] + b0;
          qf[(size_t)row * 128 + ch1] = acc1[tt][j] + b1;
        }
      }
    }
  } else if (part == 3){
    #pragma unroll
    for (int tt = 0; tt < 4; tt++){
      int ch0 = tt * 16 + r, ch1 = 64 + tt * 16 + r;
      float b0 = bp[384 + ch0], b1 = bp[384 + ch1];
      #pragma unroll
      for (int j = 0; j < 4; j++){
        int row = rowbase + j;
        if (row < NN){
          sk[(size_t)row * 128 + ch0] = acc0[tt][j] + b0;
          sk[(size_t)row * 128 + ch1] = acc1[tt][j] + b1;
        }
      }
    }
  } else {
    int chbase = (part - 1) * 64;
    #pragma unroll
    for (int tt = 0; tt < 4; tt++){
      int ch = chbase + tt * 16 + r;
      float bk = bp[cb0 * 64 + tt * 16 + r];
      float bv = bp[cb1 * 64 + tt * 16 + r];
      #pragma unroll
      for (int j = 0; j < 4; j++){
        int row = rowbase + j;
        if (row < NN){
          float kk4 = acc0[tt][j] + bk;
          float vv = acc1[tt][j] + bv;
          kvb[(size_t)row * 128 + ch] = f2bf(kk4) | (f2bf(vv) << 16);
        }
      }
    }
  }
}

// One wave per (node, head). 4 edges per wave iteration (round-11 version).
__global__ __launch_bounds__(256) void edge_k(const float* __restrict__ qf,
    const unsigned* __restrict__ kvb, const unsigned short* __restrict__ eab_us,
    const float* __restrict__ qe, const float* __restrict__ ewT,
    const int* __restrict__ row_ptr, const int* __restrict__ src_s,
    float* __restrict__ attn){
  int wv = (blockIdx.x * 256 + threadIdx.x) >> 6;
  if (wv >= NN * 2) return;
  int lane = threadIdx.x & 63;
  int n = wv >> 1, h = wv & 1;
  int grp = lane >> 4, l = lane & 15;
  float4 qv = *(const float4*)(qf + (size_t)n * 128 + h * 64 + 4 * l);
  float q0 = qv.x * SCALE_L2E, q1 = qv.y * SCALE_L2E;
  float q2 = qv.z * SCALE_L2E, q3 = qv.w * SCALE_L2E;
  float qel = qe[(size_t)n * 32 + h * 16 + l];
  int beg = row_ptr[n], end = row_ptr[n + 1];
  int nb = end - beg;
  float a0 = 0.f, a1 = 0.f, a2 = 0.f, a3 = 0.f, den = 0.f, tl = 0.f;
  int hoff = h * 64 + 4 * l;
  for (int cb = 0; cb < nb; cb += 64){
    int sv = (cb + lane < nb) ? src_s[beg + cb + lane] : 0;
    int m = min(64, nb - cb);
    for (int u = 0; u < m; u += 8){
      int eA = u + grp, eB = u + 4 + grp;
      int sA = __shfl(sv, eA);
      int sB = __shfl(sv, eB);
      uint4 kvA = *(const uint4*)(kvb + (size_t)sA * 128 + hoff);
      uint4 kvB = *(const uint4*)(kvb + (size_t)sB * 128 + hoff);
      size_t gA = (size_t)(beg + cb + eA); if (gA >= NE) gA = NE - 1;
      size_t gB = (size_t)(beg + cb + eB); if (gB >= NE) gB = NE - 1;
      unsigned short eaAu = eab_us[gA * 16 + l];
      unsigned short eaBu = eab_us[gB * 16 + l];
      {
        float eaf = __uint_as_float((unsigned)eaAu << 16);
        float k0 = __uint_as_float(kvA.x << 16), v0 = __uint_as_float(kvA.x & 0xffff0000u);
        float k1 = __uint_as_float(kvA.y << 16), v1 = __uint_as_float(kvA.y & 0xffff0000u);
        float k2 = __uint_as_float(kvA.z << 16), v2 = __uint_as_float(kvA.z & 0xffff0000u);
        float k3 = __uint_as_float(kvA.w << 16), v3 = __uint_as_float(kvA.w & 0xffff0000u);
        float p = fmaf(q0, k0, fmaf(q1, k1, fmaf(q2, k2, fmaf(q3, k3, qel * eaf))));
        p += __shfl_xor(p, 1); p += __shfl_xor(p, 2);
        p += __shfl_xor(p, 4); p += __shfl_xor(p, 8);
        float w = exp2f(p);
        if (eA >= m) w = 0.f;
        a0 = fmaf(v0, w, a0); a1 = fmaf(v1, w, a1);
        a2 = fmaf(v2, w, a2); a3 = fmaf(v3, w, a3);
        den += w; tl = fmaf(eaf, w, tl);
      }
      {
        float eaf = __uint_as_float((unsigned)eaBu << 16);
        float k0 = __uint_as_float(kvB.x << 16), v0 = __uint_as_float(kvB.x & 0xffff0000u);
        float k1 = __uint_as_float(kvB.y << 16), v1 = __uint_as_float(kvB.y & 0xffff0000u);
        float k2 = __uint_as_float(kvB.z << 16), v2 = __uint_as_float(kvB.z & 0xffff0000u);
        float k3 = __uint_as_float(kvB.w << 16), v3 = __uint_as_float(kvB.w & 0xffff0000u);
        float p = fmaf(q0, k0, fmaf(q1, k1, fmaf(q2, k2, fmaf(q3, k3, qel * eaf))));
        p += __shfl_xor(p, 1); p += __shfl_xor(p, 2);
        p += __shfl_xor(p, 4); p += __shfl_xor(p, 8);
        float w = exp2f(p);
        if (eB >= m) w = 0.f;
        a0 = fmaf(v0, w, a0); a1 = fmaf(v1, w, a1);
        a2 = fmaf(v2, w, a2); a3 = fmaf(v3, w, a3);
        den += w; tl = fmaf(eaf, w, tl);
      }
    }
  }
  a0 += __shfl_xor(a0, 16); a0 += __shfl_xor(a0, 32);
  a1 += __shfl_xor(a1, 16); a1 += __shfl_xor(a1, 32);
  a2 += __shfl_xor(a2, 16); a2 += __shfl_xor(a2, 32);
  a3 += __shfl_xor(a3, 16); a3 += __shfl_xor(a3, 32);
  den += __shfl_xor(den, 16); den += __shfl_xor(den, 32);
  tl  += __shfl_xor(tl, 16);  tl  += __shfl_xor(tl, 32);
  float e0 = 0.f, e1 = 0.f, e2 = 0.f, e3 = 0.f;
  const float* ewp = ewT + (size_t)h * 16 * 64 + 4 * l;
  #pragma unroll
  for (int d = 0; d < 16; d++){
    float td = __shfl(tl, d);
    float4 w4 = *(const float4*)(ewp + d * 64);
    e0 = fmaf(w4.x, td, e0); e1 = fmaf(w4.y, td, e1);
    e2 = fmaf(w4.z, td, e2); e3 = fmaf(w4.w, td, e3);
  }
  float inv = den > 0.f ? 1.f / den : 0.f;
  float4 o;
  o.x = (a0 + e0) * inv; o.y = (a1 + e1) * inv;
  o.z = (a2 + e2) * inv; o.w = (a3 + e3) * inv;
  *(float4*)(attn + (size_t)n * 128 + h * 64 + 4 * l) = o;
}

// MFMA combine: block = 64 nodes. Phase 1: beta-gate with 4 lanes/node
// (no barriers in the gate), hc -> split-bf16 A-fragments in LDS.
// Phase 2: per-wave 16x64 projection via 48 MFMAs vs fragment-major tw,
// fused leaky-relu + h2 store + BN-stat reduction.
__global__ __launch_bounds__(256) void combine2_k(const float* __restrict__ attn,
    const float* __restrict__ sk, const float* __restrict__ bw,
    const unsigned short* __restrict__ twh, const unsigned short* __restrict__ twl,
    const float* __restrict__ tb, float* __restrict__ h2, float* __restrict__ bn_acc){
  __shared__ bf16x8 afh[4][4][64];   // [wave][kk][lane]
  __shared__ bf16x8 afl[4][4][64];
  __shared__ float bws[384];
  __shared__ float bsum[64], bsq[64];
  int t = threadIdx.x;
  for (int i = t; i < 384; i += 256) bws[i] = bw[i];
  if (t < 64){ bsum[t] = 0.f; bsq[t] = 0.f; }
  int nl = t >> 2, q = t & 3;          // node-local 0..63, channel quarter
  int n = blockIdx.x * 64 + nl;
  bool valid = n < NN;
  float o[32], r[32];
  if (valid){
    const float* ap = attn + (size_t)n * 128 + q * 32;
    const float* sp = sk   + (size_t)n * 128 + q * 32;
    #pragma unroll
    for (int i = 0; i < 32; i += 4){
      float4 va = *(const float4*)(ap + i);
      float4 vr = *(const float4*)(sp + i);
      o[i] = va.x; o[i+1] = va.y; o[i+2] = va.z; o[i+3] = va.w;
      r[i] = vr.x; r[i+1] = vr.y; r[i+2] = vr.z; r[i+3] = vr.w;
    }
  } else {
    #pragma unroll
    for (int i = 0; i < 32; i++){ o[i] = 0.f; r[i] = 0.f; }
  }
  __syncthreads();   // bws ready
  float pp = 0.f;
  #pragma unroll
  for (int i = 0; i < 32; i++){
    int c = q * 32 + i;
    pp += o[i] * bws[c] + r[i] * bws[128 + c] + (o[i] - r[i]) * bws[256 + c];
  }
  pp += __shfl_xor(pp, 1); pp += __shfl_xor(pp, 2);
  float beta = 1.f / (1.f + __expf(-pp));
  int w2 = t >> 6;
  int r0 = (t & 63) >> 2;
  #pragma unroll
  for (int kg = 0; kg < 4; kg++){
    bf16x8 hv, lv;
    #pragma unroll
    for (int j = 0; j < 8; j++){
      int i = kg * 8 + j;
      float hc = o[i] + beta * (r[i] - o[i]);
      unsigned hb = f2bf(hc);
      hv[j] = (short)hb;
      lv[j] = (short)f2bf(hc - __uint_as_float(hb << 16));
    }
    afh[w2][q][kg * 16 + r0] = hv;
    afl[w2][q][kg * 16 + r0] = lv;
  }
  __syncthreads();
  int w = t >> 6, lane = t & 63;
  bf16x8 ah[4], al[4];
  #pragma unroll
  for (int kk = 0; kk < 4; kk++){ ah[kk] = afh[w][kk][lane]; al[kk] = afl[w][kk][lane]; }
  int brow = blockIdx.x * 64 + w * 16;
  #pragma unroll
  for (int ct = 0; ct < 4; ct++){
    f32x4 acc = (f32x4){0.f,0.f,0.f,0.f};
    #pragma unroll
    for (int kk = 0; kk < 4; kk++){
      size_t idx = (((size_t)(ct * 4 + kk)) * 64 + lane) * 8;
      bf16x8 bh = *(const bf16x8*)(twh + idx);
      bf16x8 bl = *(const bf16x8*)(twl + idx);
      acc = __builtin_amdgcn_mfma_f32_16x16x32_bf16(ah[kk], bh, acc, 0, 0, 0);
      acc = __builtin_amdgcn_mfma_f32_16x16x32_bf16(al[kk], bh, acc, 0, 0, 0);
      acc = __builtin_amdgcn_mfma_f32_16x16x32_bf16(ah[kk], bl, acc, 0, 0, 0);
    }
    int col = ct * 16 + (lane & 15);
    float bias = tb[col];
    float ps = 0.f, pq = 0.f;
    #pragma unroll
    for (int j = 0; j < 4; j++){
      int row = brow + (lane >> 4) * 4 + j;
      float s = acc[j] + bias;
      float v = s > 0.f ? s : 0.01f * s;
      if (row < NN){
        h2[(size_t)row * 64 + col] = v;
        ps += v; pq += v * v;
      }
    }
    ps += __shfl_xor(ps, 16); ps += __shfl_xor(ps, 32);
    pq += __shfl_xor(pq, 16); pq += __shfl_xor(pq, 32);
    if (lane < 16){
      atomicAdd(&bsum[col], ps);
      atomicAdd(&bsq[col], pq);
    }
  }
  __syncthreads();
  if (t < 64){
    atomicAdd(&bn_acc[t], bsum[t]);
    atomicAdd(&bn_acc[64 + t], bsq[t]);
  }
}

__global__ void bn_final_k(const float* __restrict__ bn_acc, const float* __restrict__ bnw,
                           const float* __restrict__ bnb, float* __restrict__ ss){
  int j = threadIdx.x;
  if (j < 64){
    float m = bn_acc[j] / (float)NN;
    float v = bn_acc[64 + j] / (float)NN - m * m;
    float sc = bnw[j] * rsqrtf(v + EPS_BN);
    ss[j] = sc;
    ss[64 + j] = bnb[j] - m * sc;
  }
}

// BN apply -> split bf16 h in FRAGMENT-MAJOR layout (NK=2) + pooled max/sum
__global__ __launch_bounds__(256) void bn_apply_k(const float* __restrict__ h2,
    const float* __restrict__ ss, const int* __restrict__ batch,
    unsigned short* __restrict__ hbh, unsigned short* __restrict__ hbl,
    float* __restrict__ gsum, unsigned* __restrict__ gmax,
    int do_pool){
  int wid = (blockIdx.x * 256 + threadIdx.x) >> 6;
  int lane = threadIdx.x & 63;
  const int CH = (NN + 1023) / 1024;
  int start = wid * CH;
  int end = start + CH; if (end > NN) end = NN;
  float sc = ss[lane], sh = ss[64 + lane];
  int kk = lane >> 5, kg = (lane & 31) >> 3, j = lane & 7;
  int curg = -1; float lmax = 0.f, lsum = 0.f;
  for (int n = start; n < end; n++){
    float v = h2[(size_t)n * 64 + lane] * sc + sh;
    size_t idx = fragidx((n >> 4), 2, kk, kg * 16 + (n & 15), j);
    f2bf_split(v, &hbh[idx], &hbl[idx]);
    if (do_pool){
      int g = batch[n];
      if (g != curg){
        if (curg >= 0){
          atomicAdd(&gsum[curg * 64 + lane], lsum);
          atomicMax(&gmax[curg * 64 + lane], encf(lmax));
        }
        curg = g; lmax = v; lsum = v;
      } else {
        lmax = fmaxf(lmax, v); lsum += v;
      }
    }
  }
  if (do_pool && curg >= 0){
    atomicAdd(&gsum[curg * 64 + lane], lsum);
    atomicMax(&gmax[curg * 64 + lane], encf(lmax));
  }
}

__global__ void pool_final_k(const float* __restrict__ gsum, const unsigned* __restrict__ gmax,
                             const int* __restrict__ counts, float* __restrict__ gr){
  int i = blockIdx.x * 256 + threadIdx.x;
  if (i < NG * 64){
    int g = i >> 6, j = i & 63;
    unsigned e = gmax[i];
    float mx = e ? decf(e) : 0.f;
    int c = counts[g]; if (c < 1) c = 1;
    gr[g * 128 + j]       += mx;
    gr[g * 128 + 64 + j]  += gsum[i] / (float)c;
  }
}

extern "C" void kernel_launch(void* const* d_in, const int* in_sizes, int n_in,
                              void* d_out, int out_size, void* d_ws, size_t ws_size,
                              hipStream_t stream){
  const float* x     = (const float*)d_in[0];
  const float* ea    = (const float*)d_in[1];
  const int*   eidx  = (const int*)d_in[2];
  const int*   batch = (const int*)d_in[3];
  const float* c1_qw = (const float*)d_in[4];
  const float* c1_qb = (const float*)d_in[5];
  const float* c1_kw = (const float*)d_in[6];
  const float* c1_kb = (const float*)d_in[7];
  const float* c1_vw = (const float*)d_in[8];
  const float* c1_vb = (const float*)d_in[9];
  const float* c1_ew = (const float*)d_in[10];
  const float* c1_skw= (const float*)d_in[11];
  const float* c1_skb= (const float*)d_in[12];
  const float* c1_bw = (const float*)d_in[13];
  const float* c1_tw = (const float*)d_in[14];
  const float* c1_tb = (const float*)d_in[15];
  const float* c1_bnw= (const float*)d_in[16];
  const float* c1_bnb= (const float*)d_in[17];
  const float* L_qw  = (const float*)d_in[18];
  const float* L_qb  = (const float*)d_in[19];
  const float* L_kw  = (const float*)d_in[20];
  const float* L_kb  = (const float*)d_in[21];
  const float* L_vw  = (const float*)d_in[22];
  const float* L_vb  = (const float*)d_in[23];
  const float* L_ew  = (const float*)d_in[24];
  const float* L_skw = (const float*)d_in[25];
  const float* L_skb = (const float*)d_in[26];
  const float* L_bw  = (const float*)d_in[27];
  const float* L_tw  = (const float*)d_in[28];
  const float* L_tb  = (const float*)d_in[29];
  const float* L_bnw = (const float*)d_in[30];
  const float* L_bnb = (const float*)d_in[31];
  const int* srcs = eidx;
  const int* dsts = eidx + NE;

  char* p = (char*)d_ws;
  auto carve = [&](size_t bytes) -> void* {
    void* r = (void*)p;
    p += (bytes + 255) & ~(size_t)255;
    return r;
  };
  unsigned short* Wh = (unsigned short*)carve(512 * 128 * sizeof(unsigned short));
  unsigned short* Wl = (unsigned short*)carve(512 * 128 * sizeof(unsigned short));
  float*    bp     = (float*)carve(512 * sizeof(float));
  unsigned short* twph = (unsigned short*)carve(64 * 128 * sizeof(unsigned short));
  unsigned short* twpl = (unsigned short*)carve(64 * 128 * sizeof(unsigned short));
  float*    qf     = (float*)carve((size_t)NN * 128 * sizeof(float));
  float*    skb_   = (float*)carve((size_t)NN * 128 * sizeof(float));
  unsigned* kvb    = (unsigned*)carve((size_t)NN * 128 * sizeof(unsigned));
  unsigned* eab    = (unsigned*)carve((size_t)NE * 8 * sizeof(unsigned));
  float*    qe     = (float*)carve((size_t)NN * 32 * sizeof(float));
  float*    ewT    = (float*)carve(2048 * sizeof(float));
  float*    attn   = (float*)carve((size_t)NN * 128 * sizeof(float));
  unsigned short* xbh = (unsigned short*)carve((size_t)NN * FIN * sizeof(unsigned short));
  unsigned short* xbl = (unsigned short*)carve((size_t)NN * FIN * sizeof(unsigned short));
  unsigned short* hbh = (unsigned short*)carve((size_t)NN * 64 * sizeof(unsigned short));
  unsigned short* hbl = (unsigned short*)carve((size_t)NN * 64 * sizeof(unsigned short));
  float*    h2     = (float*)carve((size_t)NN * 64 * sizeof(float));
  float*    bn_acc = (float*)carve(128 * sizeof(float));
  float*    ss     = (float*)carve(128 * sizeof(float));
  float*    gsum   = (float*)carve((size_t)NG * 64 * sizeof(float));
  unsigned* gmax   = (unsigned*)carve((size_t)NG * 64 * sizeof(unsigned));
  int*      deg    = (int*)carve(NN * sizeof(int));
  int*      row_ptr= (int*)carve((NN + 1) * sizeof(int));
  int*      eid    = (int*)carve((size_t)NE * sizeof(int));
  int*      src_s  = (int*)carve((size_t)NE * sizeof(int));
  int*      counts = (int*)carve(NG * sizeof(int));
  int*      starts = (int*)carve((NG + 1) * sizeof(int));
  int*      bsums  = (int*)carve(256 * sizeof(int));

  hipMemsetAsync(d_out, 0, (size_t)out_size * sizeof(float), stream);
  hipMemsetAsync(deg, 0, NN * sizeof(int), stream);
  hist_k<<<(NE + 255) / 256, 256, 0, stream>>>(dsts, deg);
  bounds_k<<<(NN + 255) / 256, 256, 0, stream>>>(batch, starts);
  counts_from_starts_k<<<1, 64, 0, stream>>>(starts, counts);
  scan1_k<<<SCAN_B, 256, 0, stream>>>(deg, bsums);
  scan2_k<<<1, 256, 0, stream>>>(bsums);
  scan3_k<<<SCAN_B, 256, 0, stream>>>(deg, bsums, row_ptr);
  cursor_k<<<(NN + 255) / 256, 256, 0, stream>>>(row_ptr, deg);   // reuse deg as cursor
  scatter_k<<<(NE + 255) / 256, 256, 0, stream>>>(dsts, srcs, deg, eid, src_s);
  pack_ea_k<<<(NE * 2 + 255) / 256, 256, 0, stream>>>(ea, eid, eab);
  tobf2_k<<<(NN * FIN + 255) / 256, 256, 0, stream>>>(x, xbh, xbl);

  const unsigned short* hin_h = xbh;
  const unsigned short* hin_l = xbl;
  for (int L = 0; L < 4; L++){
    int D = (L == 0) ? FIN : EMB;
    const float *qw,*qb,*kw,*kb,*vw,*vb,*eww,*skw,*skb,*bww,*tw,*tb,*bnw,*bnb;
    if (L == 0){
      qw=c1_qw; qb=c1_qb; kw=c1_kw; kb=c1_kb; vw=c1_vw; vb=c1_vb;
      eww=c1_ew; skw=c1_skw; skb=c1_skb; bww=c1_bw; tw=c1_tw; tb=c1_tb;
      bnw=c1_bnw; bnb=c1_bnb;
    } else {
      int i = L - 1;
      qw = L_qw + (size_t)i * HCC * EMB;  qb = L_qb + (size_t)i * HCC;
      kw = L_kw + (size_t)i * HCC * EMB;  kb = L_kb + (size_t)i * HCC;
      vw = L_vw + (size_t)i * HCC * EMB;  vb = L_vb + (size_t)i * HCC;
      eww= L_ew + (size_t)i * HCC * EDIM;
      skw= L_skw+ (size_t)i * HCC * EMB;  skb= L_skb+ (size_t)i * HCC;
      bww= L_bw + (size_t)i * 3 * HCC;
      tw = L_tw + (size_t)i * EMB * HCC;  tb = L_tb + (size_t)i * EMB;
      bnw= L_bnw+ (size_t)i * EMB;        bnb= L_bnb+ (size_t)i * EMB;
    }
    pack2_k<<<(512 * D + 255) / 256, 256, 0, stream>>>(qw, kw, vw, skw, qb, kb, vb, skb, Wh, Wl, bp, D);
    pack_tw_k<<<32, 256, 0, stream>>>(tw, twph, twpl);
    dim3 gg((NN + 63) / 64, 4);
    if (D == 128) gemm5_k<128><<<gg, 256, 0, stream>>>(hin_h, hin_l, Wh, Wl, bp, qf, kvb, skb_);
    else          gemm5_k<64><<<gg, 256, 0, stream>>>(hin_h, hin_l, Wh, Wl, bp, qf, kvb, skb_);
    qe_k<<<(NN + 7) / 8, 256, 0, stream>>>(qf, eww, qe);
    ewt_k<<<8, 256, 0, stream>>>(eww, ewT);
    edge_k<<<(NN * 2 * 64 + 255) / 256, 256, 0, stream>>>(qf, kvb, (const unsigned short*)eab, qe, ewT, row_ptr, src_s, attn);
    hipMemsetAsync(bn_acc, 0, 128 * sizeof(float), stream);
    combine2_k<<<(NN + 63) / 64, 256, 0, stream>>>(attn, skb_, bww, twph, twpl, tb, h2, bn_acc);
    bn_final_k<<<1, 64, 0, stream>>>(bn_acc, bnw, bnb, ss);
    if (L > 0) hipMemsetAsync(gsum, 0, 2 * NG * 64 * sizeof(float), stream);
    bn_apply_k<<<256, 256, 0, stream>>>(h2, ss, batch, hbh, hbl, gsum, gmax, (L > 0) ? 1 : 0);
    if (L > 0) pool_final_k<<<(NG * 64 + 255) / 256, 256, 0, stream>>>(gsum, gmax, counts, (float*)d_out);
    hin_h = hbh; hin_l = hbl;
  }
}

// Round 13
// 923.808 us; speedup vs baseline: 1.5246x; 1.0608x over previous
//
#include <hip/hip_runtime.h>

#define NN 50000
#define NE 800000
#define FIN 128
#define EDIM 16
#define EMB 64
#define NH 2
#define NLAYERS 3
#define NG 64
#define HCC 128
#define INV_SQRT_D 0.125f
#define EPS_BN 1e-5f
#define SCAN_B 196   // ceil(NN/256)
#define SCALE_L2E 0.18033688f   // 0.125 * log2(e)
#define NRT (NN / 16)            // 3125 row tiles

typedef __attribute__((ext_vector_type(8))) short bf16x8;
typedef __attribute__((ext_vector_type(4))) float f32x4;

__device__ __forceinline__ unsigned encf(float f){
  unsigned u = __float_as_uint(f);
  return (u & 0x80000000u) ? ~u : (u | 0x80000000u);
}
__device__ __forceinline__ float decf(unsigned e){
  unsigned u = (e & 0x80000000u) ? (e ^ 0x80000000u) : ~e;
  return __uint_as_float(u);
}
__device__ __forceinline__ unsigned f2bf(float x){   // RNE bf16, returned in low 16
  unsigned u = __float_as_uint(x);
  return (u + 0x7fffu + ((u >> 16) & 1u)) >> 16;
}
// split fp32 -> hi + lo bf16 (a ~= hi + lo, |lo| <= 2^-9 |a|)
__device__ __forceinline__ void f2bf_split(float x, unsigned short* hi, unsigned short* lo){
  unsigned h = f2bf(x);
  float hf = __uint_as_float(h << 16);
  *hi = (unsigned short)h;
  *lo = (unsigned short)f2bf(x - hf);
}
// fragment-major index: element (tile16, kk, lane, j) -> flat offset (in halves)
__device__ __forceinline__ size_t fragidx(int tile, int NK, int kk, int lane, int j){
  return (((size_t)tile * NK + kk) * 64 + lane) * 8 + j;
}

__global__ void hist_k(const int* __restrict__ dst, int* __restrict__ deg){
  int i = blockIdx.x * 256 + threadIdx.x;
  if (i < NE) atomicAdd(&deg[dst[i]], 1);
}

// batch_index is sorted: group starts via boundary detection, no atomics.
__global__ void bounds_k(const int* __restrict__ batch, int* __restrict__ starts){
  int i = blockIdx.x * 256 + threadIdx.x;
  if (i >= NN) return;
  int g = batch[i];
  int gp = (i == 0) ? -1 : batch[i - 1];
  for (int gg = gp + 1; gg <= g; gg++) starts[gg] = i;
  if (i == NN - 1){
    for (int gg = g + 1; gg <= NG; gg++) starts[gg] = NN;
  }
}

__global__ void counts_from_starts_k(const int* __restrict__ starts, int* __restrict__ counts){
  int g = threadIdx.x;
  if (g < NG) counts[g] = starts[g + 1] - starts[g];
}

__global__ void scan1_k(const int* __restrict__ deg, int* __restrict__ bsums){
  __shared__ int lds[256];
  int b = blockIdx.x, t = threadIdx.x;
  int idx = b * 256 + t;
  lds[t] = (idx < NN) ? deg[idx] : 0;
  __syncthreads();
  for (int off = 128; off >= 1; off >>= 1){
    if (t < off) lds[t] += lds[t + off];
    __syncthreads();
  }
  if (t == 0) bsums[b] = lds[0];
}

__global__ void scan2_k(int* __restrict__ bsums){
  __shared__ int lds[256];
  int t = threadIdx.x;
  int v = (t < SCAN_B) ? bsums[t] : 0;
  int x = v;
  lds[t] = x;
  __syncthreads();
  for (int off = 1; off < 256; off <<= 1){
    int y = (t >= off) ? lds[t - off] : 0;
    __syncthreads();
    x += y;
    lds[t] = x;
    __syncthreads();
  }
  if (t < SCAN_B) bsums[t] = x - v;   // exclusive
}

__global__ void scan3_k(const int* __restrict__ deg, const int* __restrict__ bsums,
                        int* __restrict__ row_ptr){
  __shared__ int lds[256];
  int b = blockIdx.x, t = threadIdx.x;
  int idx = b * 256 + t;
  int v = (idx < NN) ? deg[idx] : 0;
  int x = v;
  lds[t] = x;
  __syncthreads();
  for (int off = 1; off < 256; off <<= 1){
    int y = (t >= off) ? lds[t - off] : 0;
    __syncthreads();
    x += y;
    lds[t] = x;
    __syncthreads();
  }
  if (idx <= NN) row_ptr[idx] = bsums[b] + x - v;
}

__global__ void cursor_k(const int* __restrict__ row_ptr, int* __restrict__ cur){
  int i = blockIdx.x * 256 + threadIdx.x;
  if (i < NN) cur[i] = row_ptr[i];
}

__global__ void scatter_k(const int* __restrict__ dst, const int* __restrict__ src,
                          int* __restrict__ cur, int* __restrict__ eid,
                          int* __restrict__ src_s){
  int i = blockIdx.x * 256 + threadIdx.x;
  if (i < NE){
    int p = atomicAdd(&cur[dst[i]], 1);
    eid[p] = i;
    src_s[p] = src[i];
  }
}

// edge_attr -> bf16, reordered into CSR position order. thread = (p, half-row)
__global__ void pack_ea_k(const float* __restrict__ ea, const int* __restrict__ eid,
                          unsigned* __restrict__ eab){
  int i = blockIdx.x * 256 + threadIdx.x;
  if (i >= NE * 2) return;
  int p = i >> 1, half = i & 1;
  int e = eid[p];
  const float* s = ea + (size_t)e * 16 + half * 8;
  float4 a = *(const float4*)(s);
  float4 b = *(const float4*)(s + 4);
  uint4 o;
  o.x = f2bf(a.x) | (f2bf(a.y) << 16);
  o.y = f2bf(a.z) | (f2bf(a.w) << 16);
  o.z = f2bf(b.x) | (f2bf(b.y) << 16);
  o.w = f2bf(b.z) | (f2bf(b.w) << 16);
  ((uint4*)eab)[(size_t)p * 2 + half] = o;
}

// x (fp32, NN x 128) -> split bf16 in MFMA-fragment-major layout (NK=4)
__global__ void tobf2_k(const float* __restrict__ in, unsigned short* __restrict__ hi,
                        unsigned short* __restrict__ lo){
  int i = blockIdx.x * 256 + threadIdx.x;
  if (i >= NN * 128) return;
  int n = i >> 7, c = i & 127;
  int rt = n >> 4, rr = n & 15;
  int kk = c >> 5, kg = (c & 31) >> 3, j = c & 7;
  size_t idx = fragidx(rt, 4, kk, kg * 16 + rr, j);
  f2bf_split(in[i], &hi[idx], &lo[idx]);
}

// pack q/k/v/skip weights into split-bf16 FRAGMENT-MAJOR W2 + fp32 bias bp[512]
__global__ void pack2_k(const float* __restrict__ qw, const float* __restrict__ kw,
                        const float* __restrict__ vw, const float* __restrict__ skw,
                        const float* __restrict__ qb, const float* __restrict__ kb,
                        const float* __restrict__ vb, const float* __restrict__ skb,
                        unsigned short* __restrict__ W2h, unsigned short* __restrict__ W2l,
                        float* __restrict__ bp, int D){
  int i = blockIdx.x * 256 + threadIdx.x;
  int NK = D / 32;
  if (i < 512 * D){
    int c = i / D, d = i - c * D;
    const float* w = (c < 128) ? qw : (c < 256) ? kw : (c < 384) ? vw : skw;
    int tile = c >> 4, rr = c & 15;
    int kk = d >> 5, kg = (d & 31) >> 3, j = d & 7;
    size_t idx = fragidx(tile, NK, kk, kg * 16 + rr, j);
    f2bf_split(w[(c & 127) * D + d], &W2h[idx], &W2l[idx]);
  }
  if (i < 512){
    const float* b = (i < 128) ? qb : (i < 256) ? kb : (i < 384) ? vb : skb;
    bp[i] = b[i & 127];
  }
}

// tw [64][128] -> split-bf16 fragment-major (4 col tiles, NK=4)
__global__ void pack_tw_k(const float* __restrict__ tw, unsigned short* __restrict__ twh,
                          unsigned short* __restrict__ twl){
  int i = blockIdx.x * 256 + threadIdx.x;
  if (i >= 64 * 128) return;
  int col = i >> 7, k = i & 127;
  int ct = col >> 4, rr = col & 15;
  int kk = k >> 5, kg = (k & 31) >> 3, j = k & 7;
  size_t idx = fragidx(ct, 4, kk, kg * 16 + rr, j);
  f2bf_split(tw[i], &twh[idx], &twl[idx]);
}

// block-diag ew -> split-bf16 fragment-major B for the t->extra MFMA.
// bd[k][c] (k=0..31 dims both heads, c=0..127 channels): bd[k][c] = ew[c][k&15]
// if (k>>4)==(c>>6) else 0.
__global__ void bdpack_k(const float* __restrict__ ew, unsigned short* __restrict__ bdh,
                         unsigned short* __restrict__ bdl){
  int i = blockIdx.x * 256 + threadIdx.x;
  if (i >= 32 * 128) return;
  int k = i >> 7, c = i & 127;
  float val = ((k >> 4) == (c >> 6)) ? ew[c * 16 + (k & 15)] : 0.f;
  int ct = c >> 4, rr = c & 15;
  int kg = k >> 3, j = k & 7;         // kg in 0..3 (lane = kg*16+rr), k = kg*8+j
  size_t idx = ((size_t)(ct * 64 + kg * 16 + rr)) * 8 + j;
  f2bf_split(val, &bdh[idx], &bdl[idx]);
}

// qe[n, h, d] = (sum_c q[n,h,c] * ew[h*64+c, d]) * SCALE_L2E
__global__ __launch_bounds__(256) void qe_k(const float* __restrict__ qf,
    const float* __restrict__ ew, float* __restrict__ qe){
  __shared__ float ews[2048];
  int t = threadIdx.x;
  for (int i = t; i < 2048; i += 256) ews[i] = ew[i];
  __syncthreads();
  int g = t >> 5;
  int hd = t & 31;
  int h = hd >> 4, d = hd & 15;
  int n = blockIdx.x * 8 + g;
  if (n >= NN) return;
  const float* qp = qf + (size_t)n * 128 + h * 64;
  float s = 0.f;
  #pragma unroll 8
  for (int c = 0; c < 64; c++)
    s += qp[c] * ews[(h * 64 + c) * 16 + d];
  qe[(size_t)n * 32 + hd] = s * SCALE_L2E;
}

// Fused qkvs GEMM with FRAGMENT-MAJOR operands (unchanged from round 12).
template<int D>
__global__ __launch_bounds__(256, 4) void gemm5_k(const unsigned short* __restrict__ A2h,
                                                  const unsigned short* __restrict__ A2l,
                                                  const unsigned short* __restrict__ W2h,
                                                  const unsigned short* __restrict__ W2l,
                                                  const float* __restrict__ bp,
                                                  float* __restrict__ qf,
                                                  unsigned* __restrict__ kvb,
                                                  float* __restrict__ sk){
  const int NK = D / 32;
  int t = threadIdx.x;
  int w = t >> 6, lane = t & 63;
  int brow = blockIdx.x * 64 + w * 16;
  int part = blockIdx.y;
  int r = lane & 15, kg = lane >> 4;
  int rt = brow >> 4; if (rt > NRT - 1) rt = NRT - 1;
  int cb0 = (part == 0) ? 0 : (part == 1) ? 2 : (part == 2) ? 3 : 6;
  int cb1 = (part == 0) ? 1 : (part == 1) ? 4 : (part == 2) ? 5 : 7;
  f32x4 acc0[4], acc1[4];
  #pragma unroll
  for (int tt = 0; tt < 4; tt++){
    acc0[tt] = (f32x4){0.f,0.f,0.f,0.f};
    acc1[tt] = (f32x4){0.f,0.f,0.f,0.f};
  }
  const unsigned short* a2hp = A2h + ((size_t)rt * NK) * 512 + lane * 8;
  const unsigned short* a2lp = A2l + ((size_t)rt * NK) * 512 + lane * 8;
  #pragma unroll
  for (int kk = 0; kk < NK; kk++){
    bf16x8 ah = *(const bf16x8*)(a2hp + kk * 512);
    bf16x8 al = *(const bf16x8*)(a2lp + kk * 512);
    bf16x8 b0h[4], b0l[4], b1h[4], b1l[4];
    #pragma unroll
    for (int tt = 0; tt < 4; tt++){
      size_t i0 = fragidx(cb0 * 4 + tt, NK, kk, lane, 0);
      size_t i1 = fragidx(cb1 * 4 + tt, NK, kk, lane, 0);
      b0h[tt] = *(const bf16x8*)(W2h + i0);
      b0l[tt] = *(const bf16x8*)(W2l + i0);
      b1h[tt] = *(const bf16x8*)(W2h + i1);
      b1l[tt] = *(const bf16x8*)(W2l + i1);
    }
    #pragma unroll
    for (int tt = 0; tt < 4; tt++){
      acc0[tt] = __builtin_amdgcn_mfma_f32_16x16x32_bf16(ah, b0h[tt], acc0[tt], 0, 0, 0);
      acc1[tt] = __builtin_amdgcn_mfma_f32_16x16x32_bf16(ah, b1h[tt], acc1[tt], 0, 0, 0);
      acc0[tt] = __builtin_amdgcn_mfma_f32_16x16x32_bf16(al, b0h[tt], acc0[tt], 0, 0, 0);
      acc1[tt] = __builtin_amdgcn_mfma_f32_16x16x32_bf16(al, b1h[tt], acc1[tt], 0, 0, 0);
      acc0[tt] = __builtin_amdgcn_mfma_f32_16x16x32_bf16(ah, b0l[tt], acc0[tt], 0, 0, 0);
      acc1[tt] = __builtin_amdgcn_mfma_f32_16x16x32_bf16(ah, b1l[tt], acc1[tt], 0, 0, 0);
    }
  }
  int rowbase = brow + kg * 4;
  if (part == 0){
    #pragma unroll
    for (int tt = 0; tt < 4; tt++){
      int ch0 = tt * 16 + r, ch1 = 64 + tt * 16 + r;
      float b0 = bp[ch0], b1 = bp[ch1];
      #pragma unroll
      for (int j = 0; j < 4; j++){
        int row = rowbase + j;
        if (row < NN){
          qf[(size_t)row * 128 + ch0] = acc0[tt][j] + b0;
          qf[(size_t)row * 128 + ch1] = acc1[tt][j] + b1;
        }
      }
    }
  } else if (part == 3){
    #pragma unroll
    for (int tt = 0; tt < 4; tt++){
      int ch0 = tt * 16 + r, ch1 = 64 + tt * 16 + r;
      float b0 = bp[384 + ch0], b1 = bp[384 + ch1];
      #pragma unroll
      for (int j = 0; j < 4; j++){
        int row = rowbase + j;
        if (row < NN){
          sk[(size_t)row * 128 + ch0] = acc0[tt][j] + b0;
          sk[(size_t)row * 128 + ch1] = acc1[tt][j] + b1;
        }
      }
    }
  } else {
    int chbase = (part - 1) * 64;
    #pragma unroll
    for (int tt = 0; tt < 4; tt++){
      int ch = chbase + tt * 16 + r;
      float bk = bp[cb0 * 64 + tt * 16 + r];
      float bv = bp[cb1 * 64 + tt * 16 + r];
      #pragma unroll
      for (int j = 0; j < 4; j++){
        int row = rowbase + j;
        if (row < NN){
          float kk4 = acc0[tt][j] + bk;
          float vv = acc1[tt][j] + bv;
          kvb[(size_t)row * 128 + ch] = f2bf(kk4) | (f2bf(vv) << 16);
        }
      }
    }
  }
}

// One wave per NODE, both heads: lane = grp*16 + h*8 + l8.
// Each lane owns 8 channels of head h (2 uint4 kv loads); grp in 0..3 = edge
// slot (4 edges in flight, 8 per unrolled iteration). Logit reduce = 3-step
// 8-lane shfl. Outputs RAW acc + t[16]/head + den/head; ew@t and the division
// are deferred to combine2 (MFMA there).
__global__ __launch_bounds__(256) void edge_k(const float* __restrict__ qf,
    const unsigned* __restrict__ kvb, const unsigned* __restrict__ eab_u,
    const float* __restrict__ qe, const int* __restrict__ row_ptr,
    const int* __restrict__ src_s, float* __restrict__ accp,
    float* __restrict__ tbuf, float* __restrict__ dbuf){
  int n = (blockIdx.x * 256 + threadIdx.x) >> 6;
  if (n >= NN) return;
  int lane = threadIdx.x & 63;
  int grp = lane >> 4;
  int h = (lane >> 3) & 1;
  int l8 = lane & 7;
  int chb = h * 64 + l8 * 8;
  float q[8];
  {
    float4 qa = *(const float4*)(qf + (size_t)n * 128 + chb);
    float4 qb = *(const float4*)(qf + (size_t)n * 128 + chb + 4);
    q[0] = qa.x * SCALE_L2E; q[1] = qa.y * SCALE_L2E;
    q[2] = qa.z * SCALE_L2E; q[3] = qa.w * SCALE_L2E;
    q[4] = qb.x * SCALE_L2E; q[5] = qb.y * SCALE_L2E;
    q[6] = qb.z * SCALE_L2E; q[7] = qb.w * SCALE_L2E;
  }
  float2 qe2 = *(const float2*)(qe + (size_t)n * 32 + h * 16 + 2 * l8);
  int beg = row_ptr[n], end = row_ptr[n + 1];
  int nb = end - beg;
  float a0=0.f,a1=0.f,a2=0.f,a3=0.f,a4=0.f,a5=0.f,a6=0.f,a7=0.f;
  float den = 0.f, t0 = 0.f, t1 = 0.f;
  for (int cb = 0; cb < nb; cb += 64){
    int sv = (cb + lane < nb) ? src_s[beg + cb + lane] : 0;
    int m = min(64, nb - cb);
    for (int u = 0; u < m; u += 8){
      #pragma unroll
      for (int half = 0; half < 2; half++){
        int e = u + half * 4 + grp;              // < 64 always
        int s = __shfl(sv, e);
        const unsigned* kp = kvb + (size_t)s * 128 + chb;
        uint4 kv0 = *(const uint4*)(kp);
        uint4 kv1 = *(const uint4*)(kp + 4);
        size_t g = (size_t)(beg + cb + e); if (g >= NE) g = NE - 1;
        unsigned eau = eab_u[g * 8 + l8];
        float ea0 = __uint_as_float(eau << 16);
        float ea1 = __uint_as_float(eau & 0xffff0000u);
        float k0 = __uint_as_float(kv0.x << 16), v0 = __uint_as_float(kv0.x & 0xffff0000u);
        float k1 = __uint_as_float(kv0.y << 16), v1 = __uint_as_float(kv0.y & 0xffff0000u);
        float k2 = __uint_as_float(kv0.z << 16), v2 = __uint_as_float(kv0.z & 0xffff0000u);
        float k3 = __uint_as_float(kv0.w << 16), v3 = __uint_as_float(kv0.w & 0xffff0000u);
        float k4 = __uint_as_float(kv1.x << 16), v4 = __uint_as_float(kv1.x & 0xffff0000u);
        float k5 = __uint_as_float(kv1.y << 16), v5 = __uint_as_float(kv1.y & 0xffff0000u);
        float k6 = __uint_as_float(kv1.z << 16), v6 = __uint_as_float(kv1.z & 0xffff0000u);
        float k7 = __uint_as_float(kv1.w << 16), v7 = __uint_as_float(kv1.w & 0xffff0000u);
        float p = fmaf(q[0], k0, fmaf(q[1], k1, fmaf(q[2], k2, fmaf(q[3], k3,
                  fmaf(q[4], k4, fmaf(q[5], k5, fmaf(q[6], k6, fmaf(q[7], k7,
                  fmaf(qe2.x, ea0, qe2.y * ea1)))))))));
        p += __shfl_xor(p, 1); p += __shfl_xor(p, 2); p += __shfl_xor(p, 4);
        float w = exp2f(p);
        if (e >= m) w = 0.f;
        a0 = fmaf(v0, w, a0); a1 = fmaf(v1, w, a1);
        a2 = fmaf(v2, w, a2); a3 = fmaf(v3, w, a3);
        a4 = fmaf(v4, w, a4); a5 = fmaf(v5, w, a5);
        a6 = fmaf(v6, w, a6); a7 = fmaf(v7, w, a7);
        den += w; t0 = fmaf(ea0, w, t0); t1 = fmaf(ea1, w, t1);
      }
    }
  }
  // reduce across the 4 edge-slot groups (xor 16, 32); heads stay separate.
  a0 += __shfl_xor(a0, 16); a0 += __shfl_xor(a0, 32);
  a1 += __shfl_xor(a1, 16); a1 += __shfl_xor(a1, 32);
  a2 += __shfl_xor(a2, 16); a2 += __shfl_xor(a2, 32);
  a3 += __shfl_xor(a3, 16); a3 += __shfl_xor(a3, 32);
  a4 += __shfl_xor(a4, 16); a4 += __shfl_xor(a4, 32);
  a5 += __shfl_xor(a5, 16); a5 += __shfl_xor(a5, 32);
  a6 += __shfl_xor(a6, 16); a6 += __shfl_xor(a6, 32);
  a7 += __shfl_xor(a7, 16); a7 += __shfl_xor(a7, 32);
  den += __shfl_xor(den, 16); den += __shfl_xor(den, 32);
  t0 += __shfl_xor(t0, 16); t0 += __shfl_xor(t0, 32);
  t1 += __shfl_xor(t1, 16); t1 += __shfl_xor(t1, 32);
  if (lane < 16){
    float4 o0 = {a0, a1, a2, a3};
    float4 o1 = {a4, a5, a6, a7};
    *(float4*)(accp + (size_t)n * 128 + chb) = o0;
    *(float4*)(accp + (size_t)n * 128 + chb + 4) = o1;
    *(float2*)(tbuf + (size_t)n * 32 + h * 16 + 2 * l8) = make_float2(t0, t1);
    if (l8 == 0) dbuf[(size_t)n * 2 + h] = den;
  }
}

// MFMA combine v2: block = 64 nodes.
// Phase 0: extra = t @ blockdiag(ew) via split-bf16 MFMA -> LDS ext[64][132].
// Phase 1: o = (acc + extra)/den; beta gate (4 lanes/node); hc -> A-frags LDS.
// Phase 2: projection [64,128]@[128,64] via MFMA + leaky-relu + BN stats.
__global__ __launch_bounds__(256) void combine2_k(const float* __restrict__ accp,
    const float* __restrict__ sk, const float* __restrict__ bw,
    const unsigned short* __restrict__ twh, const unsigned short* __restrict__ twl,
    const float* __restrict__ tb, const unsigned short* __restrict__ bdh,
    const unsigned short* __restrict__ bdl, const float* __restrict__ tbuf,
    const float* __restrict__ dbuf, float* __restrict__ h2, float* __restrict__ bn_acc){
  __shared__ float ext[64][132];
  __shared__ bf16x8 afh[4][4][64];   // [wave][kk][lane]
  __shared__ bf16x8 afl[4][4][64];
  __shared__ float bws[384];
  __shared__ float bsum[64], bsq[64];
  int t = threadIdx.x;
  int w = t >> 6, lane = t & 63;
  for (int i = t; i < 384; i += 256) bws[i] = bw[i];
  if (t < 64){ bsum[t] = 0.f; bsq[t] = 0.f; }
  // ---- phase 0: t -> extra via MFMA ----
  {
    int row = lane & 15, kg = lane >> 4;
    int nrow = blockIdx.x * 64 + w * 16 + row;
    if (nrow >= NN) nrow = NN - 1;
    float4 tva = *(const float4*)(tbuf + (size_t)nrow * 32 + kg * 8);
    float4 tvb = *(const float4*)(tbuf + (size_t)nrow * 32 + kg * 8 + 4);
    float tv[8] = {tva.x, tva.y, tva.z, tva.w, tvb.x, tvb.y, tvb.z, tvb.w};
    bf16x8 th, tlw;
    #pragma unroll
    for (int j = 0; j < 8; j++){
      unsigned hb = f2bf(tv[j]);
      th[j] = (short)hb;
      tlw[j] = (short)f2bf(tv[j] - __uint_as_float(hb << 16));
    }
    #pragma unroll
    for (int ct = 0; ct < 8; ct++){
      f32x4 ae = (f32x4){0.f,0.f,0.f,0.f};
      size_t idx = ((size_t)(ct * 64 + lane)) * 8;
      bf16x8 bh = *(const bf16x8*)(bdh + idx);
      bf16x8 bl = *(const bf16x8*)(bdl + idx);
      ae = __builtin_amdgcn_mfma_f32_16x16x32_bf16(th, bh, ae, 0, 0, 0);
      ae = __builtin_amdgcn_mfma_f32_16x16x32_bf16(tlw, bh, ae, 0, 0, 0);
      ae = __builtin_amdgcn_mfma_f32_16x16x32_bf16(th, bl, ae, 0, 0, 0);
      #pragma unroll
      for (int j = 0; j < 4; j++)
        ext[w * 16 + kg * 4 + j][ct * 16 + row] = ae[j];
    }
  }
  // ---- phase 1: beta gate ----
  int nl = t >> 2, q = t & 3;
  int n = blockIdx.x * 64 + nl;
  bool valid = n < NN;
  float o[32], r[32];
  if (valid){
    const float* ap = accp + (size_t)n * 128 + q * 32;
    const float* sp = sk   + (size_t)n * 128 + q * 32;
    #pragma unroll
    for (int i = 0; i < 32; i += 4){
      float4 va = *(const float4*)(ap + i);
      float4 vr = *(const float4*)(sp + i);
      o[i] = va.x; o[i+1] = va.y; o[i+2] = va.z; o[i+3] = va.w;
      r[i] = vr.x; r[i+1] = vr.y; r[i+2] = vr.z; r[i+3] = vr.w;
    }
  } else {
    #pragma unroll
    for (int i = 0; i < 32; i++){ o[i] = 0.f; r[i] = 0.f; }
  }
  float dh = valid ? dbuf[(size_t)n * 2 + (q >> 1)] : 0.f;
  float invden = dh > 0.f ? 1.f / dh : 0.f;
  __syncthreads();   // ext + bws ready
  #pragma unroll
  for (int i = 0; i < 32; i++)
    o[i] = (o[i] + ext[nl][q * 32 + i]) * invden;
  float pp = 0.f;
  #pragma unroll
  for (int i = 0; i < 32; i++){
    int c = q * 32 + i;
    pp += o[i] * bws[c] + r[i] * bws[128 + c] + (o[i] - r[i]) * bws[256 + c];
  }
  pp += __shfl_xor(pp, 1); pp += __shfl_xor(pp, 2);
  float beta = 1.f / (1.f + __expf(-pp));
  int w2 = t >> 6;
  int r0 = (t & 63) >> 2;
  #pragma unroll
  for (int kg = 0; kg < 4; kg++){
    bf16x8 hv, lv;
    #pragma unroll
    for (int j = 0; j < 8; j++){
      int i = kg * 8 + j;
      float hc = o[i] + beta * (r[i] - o[i]);
      unsigned hb = f2bf(hc);
      hv[j] = (short)hb;
      lv[j] = (short)f2bf(hc - __uint_as_float(hb << 16));
    }
    afh[w2][q][kg * 16 + r0] = hv;
    afl[w2][q][kg * 16 + r0] = lv;
  }
  __syncthreads();
  // ---- phase 2: projection ----
  bf16x8 ah[4], al[4];
  #pragma unroll
  for (int kk = 0; kk < 4; kk++){ ah[kk] = afh[w][kk][lane]; al[kk] = afl[w][kk][lane]; }
  int brow = blockIdx.x * 64 + w * 16;
  #pragma unroll
  for (int ct = 0; ct < 4; ct++){
    f32x4 acc = (f32x4){0.f,0.f,0.f,0.f};
    #pragma unroll
    for (int kk = 0; kk < 4; kk++){
      size_t idx = (((size_t)(ct * 4 + kk)) * 64 + lane) * 8;
      bf16x8 bh = *(const bf16x8*)(twh + idx);
      bf16x8 bl = *(const bf16x8*)(twl + idx);
      acc = __builtin_amdgcn_mfma_f32_16x16x32_bf16(ah[kk], bh, acc, 0, 0, 0);
      acc = __builtin_amdgcn_mfma_f32_16x16x32_bf16(al[kk], bh, acc, 0, 0, 0);
      acc = __builtin_amdgcn_mfma_f32_16x16x32_bf16(ah[kk], bl, acc, 0, 0, 0);
    }
    int col = ct * 16 + (lane & 15);
    float bias = tb[col];
    float ps = 0.f, pq = 0.f;
    #pragma unroll
    for (int j = 0; j < 4; j++){
      int row = brow + (lane >> 4) * 4 + j;
      float s = acc[j] + bias;
      float v = s > 0.f ? s : 0.01f * s;
      if (row < NN){
        h2[(size_t)row * 64 + col] = v;
        ps += v; pq += v * v;
      }
    }
    ps += __shfl_xor(ps, 16); ps += __shfl_xor(ps, 32);
    pq += __shfl_xor(pq, 16); pq += __shfl_xor(pq, 32);
    if (lane < 16){
      atomicAdd(&bsum[col], ps);
      atomicAdd(&bsq[col], pq);
    }
  }
  __syncthreads();
  if (t < 64){
    atomicAdd(&bn_acc[t], bsum[t]);
    atomicAdd(&bn_acc[64 + t], bsq[t]);
  }
}

__global__ void bn_final_k(const float* __restrict__ bn_acc, const float* __restrict__ bnw,
                           const float* __restrict__ bnb, float* __restrict__ ss){
  int j = threadIdx.x;
  if (j < 64){
    float m = bn_acc[j] / (float)NN;
    float v = bn_acc[64 + j] / (float)NN - m * m;
    float sc = bnw[j] * rsqrtf(v + EPS_BN);
    ss[j] = sc;
    ss[64 + j] = bnb[j] - m * sc;
  }
}

// BN apply -> split bf16 h in FRAGMENT-MAJOR layout (NK=2) + pooled max/sum
__global__ __launch_bounds__(256) void bn_apply_k(const float* __restrict__ h2,
    const float* __restrict__ ss, const int* __restrict__ batch,
    unsigned short* __restrict__ hbh, unsigned short* __restrict__ hbl,
    float* __restrict__ gsum, unsigned* __restrict__ gmax,
    int do_pool){
  int wid = (blockIdx.x * 256 + threadIdx.x) >> 6;
  int lane = threadIdx.x & 63;
  const int CH = (NN + 1023) / 1024;
  int start = wid * CH;
  int end = start + CH; if (end > NN) end = NN;
  float sc = ss[lane], sh = ss[64 + lane];
  int kk = lane >> 5, kg = (lane & 31) >> 3, j = lane & 7;
  int curg = -1; float lmax = 0.f, lsum = 0.f;
  for (int n = start; n < end; n++){
    float v = h2[(size_t)n * 64 + lane] * sc + sh;
    size_t idx = fragidx((n >> 4), 2, kk, kg * 16 + (n & 15), j);
    f2bf_split(v, &hbh[idx], &hbl[idx]);
    if (do_pool){
      int g = batch[n];
      if (g != curg){
        if (curg >= 0){
          atomicAdd(&gsum[curg * 64 + lane], lsum);
          atomicMax(&gmax[curg * 64 + lane], encf(lmax));
        }
        curg = g; lmax = v; lsum = v;
      } else {
        lmax = fmaxf(lmax, v); lsum += v;
      }
    }
  }
  if (do_pool && curg >= 0){
    atomicAdd(&gsum[curg * 64 + lane], lsum);
    atomicMax(&gmax[curg * 64 + lane], encf(lmax));
  }
}

__global__ void pool_final_k(const float* __restrict__ gsum, const unsigned* __restrict__ gmax,
                             const int* __restrict__ counts, float* __restrict__ gr){
  int i = blockIdx.x * 256 + threadIdx.x;
  if (i < NG * 64){
    int g = i >> 6, j = i & 63;
    unsigned e = gmax[i];
    float mx = e ? decf(e) : 0.f;
    int c = counts[g]; if (c < 1) c = 1;
    gr[g * 128 + j]       += mx;
    gr[g * 128 + 64 + j]  += gsum[i] / (float)c;
  }
}

extern "C" void kernel_launch(void* const* d_in, const int* in_sizes, int n_in,
                              void* d_out, int out_size, void* d_ws, size_t ws_size,
                              hipStream_t stream){
  const float* x     = (const float*)d_in[0];
  const float* ea    = (const float*)d_in[1];
  const int*   eidx  = (const int*)d_in[2];
  const int*   batch = (const int*)d_in[3];
  const float* c1_qw = (const float*)d_in[4];
  const float* c1_qb = (const float*)d_in[5];
  const float* c1_kw = (const float*)d_in[6];
  const float* c1_kb = (const float*)d_in[7];
  const float* c1_vw = (const float*)d_in[8];
  const float* c1_vb = (const float*)d_in[9];
  const float* c1_ew = (const float*)d_in[10];
  const float* c1_skw= (const float*)d_in[11];
  const float* c1_skb= (const float*)d_in[12];
  const float* c1_bw = (const float*)d_in[13];
  const float* c1_tw = (const float*)d_in[14];
  const float* c1_tb = (const float*)d_in[15];
  const float* c1_bnw= (const float*)d_in[16];
  const float* c1_bnb= (const float*)d_in[17];
  const float* L_qw  = (const float*)d_in[18];
  const float* L_qb  = (const float*)d_in[19];
  const float* L_kw  = (const float*)d_in[20];
  const float* L_kb  = (const float*)d_in[21];
  const float* L_vw  = (const float*)d_in[22];
  const float* L_vb  = (const float*)d_in[23];
  const float* L_ew  = (const float*)d_in[24];
  const float* L_skw = (const float*)d_in[25];
  const float* L_skb = (const float*)d_in[26];
  const float* L_bw  = (const float*)d_in[27];
  const float* L_tw  = (const float*)d_in[28];
  const float* L_tb  = (const float*)d_in[29];
  const float* L_bnw = (const float*)d_in[30];
  const float* L_bnb = (const float*)d_in[31];
  const int* srcs = eidx;
  const int* dsts = eidx + NE;

  char* p = (char*)d_ws;
  auto carve = [&](size_t bytes) -> void* {
    void* r = (void*)p;
    p += (bytes + 255) & ~(size_t)255;
    return r;
  };
  unsigned short* Wh = (unsigned short*)carve(512 * 128 * sizeof(unsigned short));
  unsigned short* Wl = (unsigned short*)carve(512 * 128 * sizeof(unsigned short));
  float*    bp     = (float*)carve(512 * sizeof(float));
  unsigned short* twph = (unsigned short*)carve(64 * 128 * sizeof(unsigned short));
  unsigned short* twpl = (unsigned short*)carve(64 * 128 * sizeof(unsigned short));
  unsigned short* bdh = (unsigned short*)carve(32 * 128 * sizeof(unsigned short));
  unsigned short* bdl = (unsigned short*)carve(32 * 128 * sizeof(unsigned short));
  float*    qf     = (float*)carve((size_t)NN * 128 * sizeof(float));
  float*    skb_   = (float*)carve((size_t)NN * 128 * sizeof(float));
  unsigned* kvb    = (unsigned*)carve((size_t)NN * 128 * sizeof(unsigned));
  unsigned* eab    = (unsigned*)carve((size_t)NE * 8 * sizeof(unsigned));
  float*    qe     = (float*)carve((size_t)NN * 32 * sizeof(float));
  float*    attn   = (float*)carve((size_t)NN * 128 * sizeof(float));
  float*    tbuf   = (float*)carve((size_t)NN * 32 * sizeof(float));
  float*    dbuf   = (float*)carve((size_t)NN * 2 * sizeof(float));
  unsigned short* xbh = (unsigned short*)carve((size_t)NN * FIN * sizeof(unsigned short));
  unsigned short* xbl = (unsigned short*)carve((size_t)NN * FIN * sizeof(unsigned short));
  unsigned short* hbh = (unsigned short*)carve((size_t)NN * 64 * sizeof(unsigned short));
  unsigned short* hbl = (unsigned short*)carve((size_t)NN * 64 * sizeof(unsigned short));
  float*    h2     = (float*)carve((size_t)NN * 64 * sizeof(float));
  float*    bn_acc = (float*)carve(128 * sizeof(float));
  float*    ss     = (float*)carve(128 * sizeof(float));
  float*    gsum   = (float*)carve((size_t)NG * 64 * sizeof(float));
  unsigned* gmax   = (unsigned*)carve((size_t)NG * 64 * sizeof(unsigned));
  int*      deg    = (int*)carve(NN * sizeof(int));
  int*      row_ptr= (int*)carve((NN + 1) * sizeof(int));
  int*      eid    = (int*)carve((size_t)NE * sizeof(int));
  int*      src_s  = (int*)carve((size_t)NE * sizeof(int));
  int*      counts = (int*)carve(NG * sizeof(int));
  int*      starts = (int*)carve((NG + 1) * sizeof(int));
  int*      bsums  = (int*)carve(256 * sizeof(int));

  hipMemsetAsync(d_out, 0, (size_t)out_size * sizeof(float), stream);
  hipMemsetAsync(deg, 0, NN * sizeof(int), stream);
  hist_k<<<(NE + 255) / 256, 256, 0, stream>>>(dsts, deg);
  bounds_k<<<(NN + 255) / 256, 256, 0, stream>>>(batch, starts);
  counts_from_starts_k<<<1, 64, 0, stream>>>(starts, counts);
  scan1_k<<<SCAN_B, 256, 0, stream>>>(deg, bsums);
  scan2_k<<<1, 256, 0, stream>>>(bsums);
  scan3_k<<<SCAN_B, 256, 0, stream>>>(deg, bsums, row_ptr);
  cursor_k<<<(NN + 255) / 256, 256, 0, stream>>>(row_ptr, deg);   // reuse deg as cursor
  scatter_k<<<(NE + 255) / 256, 256, 0, stream>>>(dsts, srcs, deg, eid, src_s);
  pack_ea_k<<<(NE * 2 + 255) / 256, 256, 0, stream>>>(ea, eid, eab);
  tobf2_k<<<(NN * FIN + 255) / 256, 256, 0, stream>>>(x, xbh, xbl);

  const unsigned short* hin_h = xbh;
  const unsigned short* hin_l = xbl;
  for (int L = 0; L < 4; L++){
    int D = (L == 0) ? FIN : EMB;
    const float *qw,*qb,*kw,*kb,*vw,*vb,*eww,*skw,*skb,*bww,*tw,*tb,*bnw,*bnb;
    if (L == 0){
      qw=c1_qw; qb=c1_qb; kw=c1_kw; kb=c1_kb; vw=c1_vw; vb=c1_vb;
      eww=c1_ew; skw=c1_skw; skb=c1_skb; bww=c1_bw; tw=c1_tw; tb=c1_tb;
      bnw=c1_bnw; bnb=c1_bnb;
    } else {
      int i = L - 1;
      qw = L_qw + (size_t)i * HCC * EMB;  qb = L_qb + (size_t)i * HCC;
      kw = L_kw + (size_t)i * HCC * EMB;  kb = L_kb + (size_t)i * HCC;
      vw = L_vw + (size_t)i * HCC * EMB;  vb = L_vb + (size_t)i * HCC;
      eww= L_ew + (size_t)i * HCC * EDIM;
      skw= L_skw+ (size_t)i * HCC * EMB;  skb= L_skb+ (size_t)i * HCC;
      bww= L_bw + (size_t)i * 3 * HCC;
      tw = L_tw + (size_t)i * EMB * HCC;  tb = L_tb + (size_t)i * EMB;
      bnw= L_bnw+ (size_t)i * EMB;        bnb= L_bnb+ (size_t)i * EMB;
    }
    pack2_k<<<(512 * D + 255) / 256, 256, 0, stream>>>(qw, kw, vw, skw, qb, kb, vb, skb, Wh, Wl, bp, D);
    pack_tw_k<<<32, 256, 0, stream>>>(tw, twph, twpl);
    bdpack_k<<<16, 256, 0, stream>>>(eww, bdh, bdl);
    dim3 gg((NN + 63) / 64, 4);
    if (D == 128) gemm5_k<128><<<gg, 256, 0, stream>>>(hin_h, hin_l, Wh, Wl, bp, qf, kvb, skb_);
    else          gemm5_k<64><<<gg, 256, 0, stream>>>(hin_h, hin_l, Wh, Wl, bp, qf, kvb, skb_);
    qe_k<<<(NN + 7) / 8, 256, 0, stream>>>(qf, eww, qe);
    edge_k<<<(NN * 64 + 255) / 256, 256, 0, stream>>>(qf, kvb, eab, qe, row_ptr, src_s, attn, tbuf, dbuf);
    hipMemsetAsync(bn_acc, 0, 128 * sizeof(float), stream);
    combine2_k<<<(NN + 63) / 64, 256, 0, stream>>>(attn, skb_, bww, twph, twpl, tb, bdh, bdl, tbuf, dbuf, h2, bn_acc);
    bn_final_k<<<1, 64, 0, stream>>>(bn_acc, bnw, bnb, ss);
    if (L > 0) hipMemsetAsync(gsum, 0, 2 * NG * 64 * sizeof(float), stream);
    bn_apply_k<<<256, 256, 0, stream>>>(h2, ss, batch, hbh, hbl, gsum, gmax, (L > 0) ? 1 : 0);
    if (L > 0) pool_final_k<<<(NG * 64 + 255) / 256, 256, 0, stream>>>(gsum, gmax, counts, (float*)d_out);
    hin_h = hbh; hin_l = hbl;
  }
}

// Round 14
// 901.730 us; speedup vs baseline: 1.5620x; 1.0245x over previous
//
#include <hip/hip_runtime.h>

#define NN 50000
#define NE 800000
#define FIN 128
#define EDIM 16
#define EMB 64
#define NH 2
#define NLAYERS 3
#define NG 64
#define HCC 128
#define INV_SQRT_D 0.125f
#define EPS_BN 1e-5f
#define SCAN_B 196   // ceil(NN/256)
#define SCALE_L2E 0.18033688f   // 0.125 * log2(e)
#define NRT (NN / 16)            // 3125 row tiles

typedef __attribute__((ext_vector_type(8))) short bf16x8;
typedef __attribute__((ext_vector_type(4))) float f32x4;

__device__ __forceinline__ unsigned encf(float f){
  unsigned u = __float_as_uint(f);
  return (u & 0x80000000u) ? ~u : (u | 0x80000000u);
}
__device__ __forceinline__ float decf(unsigned e){
  unsigned u = (e & 0x80000000u) ? (e ^ 0x80000000u) : ~e;
  return __uint_as_float(u);
}
__device__ __forceinline__ unsigned f2bf(float x){   // RNE bf16, returned in low 16
  unsigned u = __float_as_uint(x);
  return (u + 0x7fffu + ((u >> 16) & 1u)) >> 16;
}
// split fp32 -> hi + lo bf16 (a ~= hi + lo, |lo| <= 2^-9 |a|)
__device__ __forceinline__ void f2bf_split(float x, unsigned short* hi, unsigned short* lo){
  unsigned h = f2bf(x);
  float hf = __uint_as_float(h << 16);
  *hi = (unsigned short)h;
  *lo = (unsigned short)f2bf(x - hf);
}
// fragment-major index: element (tile16, kk, lane, j) -> flat offset (in halves)
__device__ __forceinline__ size_t fragidx(int tile, int NK, int kk, int lane, int j){
  return (((size_t)tile * NK + kk) * 64 + lane) * 8 + j;
}

__global__ void hist_k(const int* __restrict__ dst, int* __restrict__ deg){
  int i = blockIdx.x * 256 + threadIdx.x;
  if (i < NE) atomicAdd(&deg[dst[i]], 1);
}

// batch_index is sorted: group starts via boundary detection, no atomics.
__global__ void bounds_k(const int* __restrict__ batch, int* __restrict__ starts){
  int i = blockIdx.x * 256 + threadIdx.x;
  if (i >= NN) return;
  int g = batch[i];
  int gp = (i == 0) ? -1 : batch[i - 1];
  for (int gg = gp + 1; gg <= g; gg++) starts[gg] = i;
  if (i == NN - 1){
    for (int gg = g + 1; gg <= NG; gg++) starts[gg] = NN;
  }
}

__global__ void counts_from_starts_k(const int* __restrict__ starts, int* __restrict__ counts){
  int g = threadIdx.x;
  if (g < NG) counts[g] = starts[g + 1] - starts[g];
}

__global__ void scan1_k(const int* __restrict__ deg, int* __restrict__ bsums){
  __shared__ int lds[256];
  int b = blockIdx.x, t = threadIdx.x;
  int idx = b * 256 + t;
  lds[t] = (idx < NN) ? deg[idx] : 0;
  __syncthreads();
  for (int off = 128; off >= 1; off >>= 1){
    if (t < off) lds[t] += lds[t + off];
    __syncthreads();
  }
  if (t == 0) bsums[b] = lds[0];
}

__global__ void scan2_k(int* __restrict__ bsums){
  __shared__ int lds[256];
  int t = threadIdx.x;
  int v = (t < SCAN_B) ? bsums[t] : 0;
  int x = v;
  lds[t] = x;
  __syncthreads();
  for (int off = 1; off < 256; off <<= 1){
    int y = (t >= off) ? lds[t - off] : 0;
    __syncthreads();
    x += y;
    lds[t] = x;
    __syncthreads();
  }
  if (t < SCAN_B) bsums[t] = x - v;   // exclusive
}

// scan3 also initializes the scatter cursor (reuses deg as cursor storage).
__global__ void scan3_k(const int* __restrict__ degin, const int* __restrict__ bsums,
                        int* __restrict__ row_ptr, int* __restrict__ cur){
  __shared__ int lds[256];
  int b = blockIdx.x, t = threadIdx.x;
  int idx = b * 256 + t;
  int v = (idx < NN) ? degin[idx] : 0;
  int x = v;
  lds[t] = x;
  __syncthreads();
  for (int off = 1; off < 256; off <<= 1){
    int y = (t >= off) ? lds[t - off] : 0;
    __syncthreads();
    x += y;
    lds[t] = x;
    __syncthreads();
  }
  int val = bsums[b] + x - v;
  if (idx <= NN) row_ptr[idx] = val;
  if (idx < NN) cur[idx] = val;
}

__global__ void scatter_k(const int* __restrict__ dst, const int* __restrict__ src,
                          int* __restrict__ cur, int* __restrict__ eid,
                          int* __restrict__ src_s){
  int i = blockIdx.x * 256 + threadIdx.x;
  if (i < NE){
    int p = atomicAdd(&cur[dst[i]], 1);
    eid[p] = i;
    src_s[p] = src[i];
  }
}

// edge_attr -> bf16, reordered into CSR position order. thread = (p, half-row)
__global__ void pack_ea_k(const float* __restrict__ ea, const int* __restrict__ eid,
                          unsigned* __restrict__ eab){
  int i = blockIdx.x * 256 + threadIdx.x;
  if (i >= NE * 2) return;
  int p = i >> 1, half = i & 1;
  int e = eid[p];
  const float* s = ea + (size_t)e * 16 + half * 8;
  float4 a = *(const float4*)(s);
  float4 b = *(const float4*)(s + 4);
  uint4 o;
  o.x = f2bf(a.x) | (f2bf(a.y) << 16);
  o.y = f2bf(a.z) | (f2bf(a.w) << 16);
  o.z = f2bf(b.x) | (f2bf(b.y) << 16);
  o.w = f2bf(b.z) | (f2bf(b.w) << 16);
  ((uint4*)eab)[(size_t)p * 2 + half] = o;
}

// x (fp32, NN x 128) -> split bf16 in MFMA-fragment-major layout (NK=4)
__global__ void tobf2_k(const float* __restrict__ in, unsigned short* __restrict__ hi,
                        unsigned short* __restrict__ lo){
  int i = blockIdx.x * 256 + threadIdx.x;
  if (i >= NN * 128) return;
  int n = i >> 7, c = i & 127;
  int rt = n >> 4, rr = n & 15;
  int kk = c >> 5, kg = (c & 31) >> 3, j = c & 7;
  size_t idx = fragidx(rt, 4, kk, kg * 16 + rr, j);
  f2bf_split(in[i], &hi[idx], &lo[idx]);
}

// ALL per-layer weight packing fused: qkvs weights (split-bf16 fragment-major)
// + bias, tw fragments, block-diag ew fragments.
__global__ void pack_all_k(const float* __restrict__ qw, const float* __restrict__ kw,
                           const float* __restrict__ vw, const float* __restrict__ skw,
                           const float* __restrict__ qb, const float* __restrict__ kb,
                           const float* __restrict__ vb, const float* __restrict__ skb,
                           const float* __restrict__ tw, const float* __restrict__ ew,
                           unsigned short* __restrict__ W2h, unsigned short* __restrict__ W2l,
                           float* __restrict__ bp,
                           unsigned short* __restrict__ twh, unsigned short* __restrict__ twl,
                           unsigned short* __restrict__ bdh, unsigned short* __restrict__ bdl,
                           int D){
  int i = blockIdx.x * 256 + threadIdx.x;
  int NK = D / 32;
  if (i < 512 * D){
    int c = i / D, d = i - c * D;
    const float* w = (c < 128) ? qw : (c < 256) ? kw : (c < 384) ? vw : skw;
    int tile = c >> 4, rr = c & 15;
    int kk = d >> 5, kg = (d & 31) >> 3, j = d & 7;
    size_t idx = fragidx(tile, NK, kk, kg * 16 + rr, j);
    f2bf_split(w[(c & 127) * D + d], &W2h[idx], &W2l[idx]);
  }
  if (i < 512){
    const float* b = (i < 128) ? qb : (i < 256) ? kb : (i < 384) ? vb : skb;
    bp[i] = b[i & 127];
  }
  if (i < 64 * 128){
    int col = i >> 7, k = i & 127;
    int ct = col >> 4, rr = col & 15;
    int kk = k >> 5, kg = (k & 31) >> 3, j = k & 7;
    size_t idx = fragidx(ct, 4, kk, kg * 16 + rr, j);
    f2bf_split(tw[i], &twh[idx], &twl[idx]);
  }
  if (i < 32 * 128){
    int k = i >> 7, c = i & 127;
    float val = ((k >> 4) == (c >> 6)) ? ew[c * 16 + (k & 15)] : 0.f;
    int ct = c >> 4, rr = c & 15;
    int kg = k >> 3, j = k & 7;
    size_t idx = ((size_t)(ct * 64 + kg * 16 + rr)) * 8 + j;
    f2bf_split(val, &bdh[idx], &bdl[idx]);
  }
}

// qe[n, h, d] = (sum_c q[n,h,c] * ew[h*64+c, d]) * SCALE_L2E
__global__ __launch_bounds__(256) void qe_k(const float* __restrict__ qf,
    const float* __restrict__ ew, float* __restrict__ qe){
  __shared__ float ews[2048];
  int t = threadIdx.x;
  for (int i = t; i < 2048; i += 256) ews[i] = ew[i];
  __syncthreads();
  int g = t >> 5;
  int hd = t & 31;
  int h = hd >> 4, d = hd & 15;
  int n = blockIdx.x * 8 + g;
  if (n >= NN) return;
  const float* qp = qf + (size_t)n * 128 + h * 64;
  float s = 0.f;
  #pragma unroll 8
  for (int c = 0; c < 64; c++)
    s += qp[c] * ews[(h * 64 + c) * 16 + d];
  qe[(size_t)n * 32 + hd] = s * SCALE_L2E;
}

// Fused qkvs GEMM with FRAGMENT-MAJOR operands (unchanged).
template<int D>
__global__ __launch_bounds__(256, 4) void gemm5_k(const unsigned short* __restrict__ A2h,
                                                  const unsigned short* __restrict__ A2l,
                                                  const unsigned short* __restrict__ W2h,
                                                  const unsigned short* __restrict__ W2l,
                                                  const float* __restrict__ bp,
                                                  float* __restrict__ qf,
                                                  unsigned* __restrict__ kvb,
                                                  float* __restrict__ sk){
  const int NK = D / 32;
  int t = threadIdx.x;
  int w = t >> 6, lane = t & 63;
  int brow = blockIdx.x * 64 + w * 16;
  int part = blockIdx.y;
  int r = lane & 15, kg = lane >> 4;
  int rt = brow >> 4; if (rt > NRT - 1) rt = NRT - 1;
  int cb0 = (part == 0) ? 0 : (part == 1) ? 2 : (part == 2) ? 3 : 6;
  int cb1 = (part == 0) ? 1 : (part == 1) ? 4 : (part == 2) ? 5 : 7;
  f32x4 acc0[4], acc1[4];
  #pragma unroll
  for (int tt = 0; tt < 4; tt++){
    acc0[tt] = (f32x4){0.f,0.f,0.f,0.f};
    acc1[tt] = (f32x4){0.f,0.f,0.f,0.f};
  }
  const unsigned short* a2hp = A2h + ((size_t)rt * NK) * 512 + lane * 8;
  const unsigned short* a2lp = A2l + ((size_t)rt * NK) * 512 + lane * 8;
  #pragma unroll
  for (int kk = 0; kk < NK; kk++){
    bf16x8 ah = *(const bf16x8*)(a2hp + kk * 512);
    bf16x8 al = *(const bf16x8*)(a2lp + kk * 512);
    bf16x8 b0h[4], b0l[4], b1h[4], b1l[4];
    #pragma unroll
    for (int tt = 0; tt < 4; tt++){
      size_t i0 = fragidx(cb0 * 4 + tt, NK, kk, lane, 0);
      size_t i1 = fragidx(cb1 * 4 + tt, NK, kk, lane, 0);
      b0h[tt] = *(const bf16x8*)(W2h + i0);
      b0l[tt] = *(const bf16x8*)(W2l + i0);
      b1h[tt] = *(const bf16x8*)(W2h + i1);
      b1l[tt] = *(const bf16x8*)(W2l + i1);
    }
    #pragma unroll
    for (int tt = 0; tt < 4; tt++){
      acc0[tt] = __builtin_amdgcn_mfma_f32_16x16x32_bf16(ah, b0h[tt], acc0[tt], 0, 0, 0);
      acc1[tt] = __builtin_amdgcn_mfma_f32_16x16x32_bf16(ah, b1h[tt], acc1[tt], 0, 0, 0);
      acc0[tt] = __builtin_amdgcn_mfma_f32_16x16x32_bf16(al, b0h[tt], acc0[tt], 0, 0, 0);
      acc1[tt] = __builtin_amdgcn_mfma_f32_16x16x32_bf16(al, b1h[tt], acc1[tt], 0, 0, 0);
      acc0[tt] = __builtin_amdgcn_mfma_f32_16x16x32_bf16(ah, b0l[tt], acc0[tt], 0, 0, 0);
      acc1[tt] = __builtin_amdgcn_mfma_f32_16x16x32_bf16(ah, b1l[tt], acc1[tt], 0, 0, 0);
    }
  }
  int rowbase = brow + kg * 4;
  if (part == 0){
    #pragma unroll
    for (int tt = 0; tt < 4; tt++){
      int ch0 = tt * 16 + r, ch1 = 64 + tt * 16 + r;
      float b0 = bp[ch0], b1 = bp[ch1];
      #pragma unroll
      for (int j = 0; j < 4; j++){
        int row = rowbase + j;
        if (row < NN){
          qf[(size_t)row * 128 + ch0] = acc0[tt][j] + b0;
          qf[(size_t)row * 128 + ch1] = acc1[tt][j] + b1;
        }
      }
    }
  } else if (part == 3){
    #pragma unroll
    for (int tt = 0; tt < 4; tt++){
      int ch0 = tt * 16 + r, ch1 = 64 + tt * 16 + r;
      float b0 = bp[384 + ch0], b1 = bp[384 + ch1];
      #pragma unroll
      for (int j = 0; j < 4; j++){
        int row = rowbase + j;
        if (row < NN){
          sk[(size_t)row * 128 + ch0] = acc0[tt][j] + b0;
          sk[(size_t)row * 128 + ch1] = acc1[tt][j] + b1;
        }
      }
    }
  } else {
    int chbase = (part - 1) * 64;
    #pragma unroll
    for (int tt = 0; tt < 4; tt++){
      int ch = chbase + tt * 16 + r;
      float bk = bp[cb0 * 64 + tt * 16 + r];
      float bv = bp[cb1 * 64 + tt * 16 + r];
      #pragma unroll
      for (int j = 0; j < 4; j++){
        int row = rowbase + j;
        if (row < NN){
          float kk4 = acc0[tt][j] + bk;
          float vv = acc1[tt][j] + bv;
          kvb[(size_t)row * 128 + ch] = f2bf(kk4) | (f2bf(vv) << 16);
        }
      }
    }
  }
}

// One wave per NODE, both heads. Tail-optimized: unmasked full 8-edge steps,
// masked 4/8-edge tail (cuts ~13% wasted edge-visits at Poisson(16) degrees).
#define EDGE_STEP(EOFF, MASKED)                                               \
  {                                                                           \
    int e = (EOFF);                                                           \
    int s = __shfl(sv, e);                                                    \
    const unsigned* kp = kvb + (size_t)s * 128 + chb;                         \
    uint4 kv0 = *(const uint4*)(kp);                                          \
    uint4 kv1 = *(const uint4*)(kp + 4);                                      \
    size_t g = (size_t)(beg + cb + e);                                        \
    if (MASKED && g >= NE) g = NE - 1;                                        \
    unsigned eau = eab_u[g * 8 + l8];                                         \
    float ea0 = __uint_as_float(eau << 16);                                   \
    float ea1 = __uint_as_float(eau & 0xffff0000u);                           \
    float k0 = __uint_as_float(kv0.x << 16), v0 = __uint_as_float(kv0.x & 0xffff0000u); \
    float k1 = __uint_as_float(kv0.y << 16), v1 = __uint_as_float(kv0.y & 0xffff0000u); \
    float k2 = __uint_as_float(kv0.z << 16), v2 = __uint_as_float(kv0.z & 0xffff0000u); \
    float k3 = __uint_as_float(kv0.w << 16), v3 = __uint_as_float(kv0.w & 0xffff0000u); \
    float k4 = __uint_as_float(kv1.x << 16), v4 = __uint_as_float(kv1.x & 0xffff0000u); \
    float k5 = __uint_as_float(kv1.y << 16), v5 = __uint_as_float(kv1.y & 0xffff0000u); \
    float k6 = __uint_as_float(kv1.z << 16), v6 = __uint_as_float(kv1.z & 0xffff0000u); \
    float k7 = __uint_as_float(kv1.w << 16), v7 = __uint_as_float(kv1.w & 0xffff0000u); \
    float p = fmaf(q[0], k0, fmaf(q[1], k1, fmaf(q[2], k2, fmaf(q[3], k3,     \
              fmaf(q[4], k4, fmaf(q[5], k5, fmaf(q[6], k6, fmaf(q[7], k7,     \
              fmaf(qe2.x, ea0, qe2.y * ea1)))))))));                          \
    p += __shfl_xor(p, 1); p += __shfl_xor(p, 2); p += __shfl_xor(p, 4);      \
    float w = exp2f(p);                                                       \
    if (MASKED && e >= m) w = 0.f;                                            \
    a0 = fmaf(v0, w, a0); a1 = fmaf(v1, w, a1);                               \
    a2 = fmaf(v2, w, a2); a3 = fmaf(v3, w, a3);                               \
    a4 = fmaf(v4, w, a4); a5 = fmaf(v5, w, a5);                               \
    a6 = fmaf(v6, w, a6); a7 = fmaf(v7, w, a7);                               \
    den += w; t0 = fmaf(ea0, w, t0); t1 = fmaf(ea1, w, t1);                   \
  }

__global__ __launch_bounds__(256) void edge_k(const float* __restrict__ qf,
    const unsigned* __restrict__ kvb, const unsigned* __restrict__ eab_u,
    const float* __restrict__ qe, const int* __restrict__ row_ptr,
    const int* __restrict__ src_s, float* __restrict__ accp,
    float* __restrict__ tbuf, float* __restrict__ dbuf){
  int n = (blockIdx.x * 256 + threadIdx.x) >> 6;
  if (n >= NN) return;
  int lane = threadIdx.x & 63;
  int grp = lane >> 4;
  int l8 = lane & 7;
  int chb = ((lane >> 3) & 1) * 64 + l8 * 8;
  int h = (lane >> 3) & 1;
  float q[8];
  {
    float4 qa = *(const float4*)(qf + (size_t)n * 128 + chb);
    float4 qb = *(const float4*)(qf + (size_t)n * 128 + chb + 4);
    q[0] = qa.x * SCALE_L2E; q[1] = qa.y * SCALE_L2E;
    q[2] = qa.z * SCALE_L2E; q[3] = qa.w * SCALE_L2E;
    q[4] = qb.x * SCALE_L2E; q[5] = qb.y * SCALE_L2E;
    q[6] = qb.z * SCALE_L2E; q[7] = qb.w * SCALE_L2E;
  }
  float2 qe2 = *(const float2*)(qe + (size_t)n * 32 + h * 16 + 2 * l8);
  int beg = row_ptr[n], end = row_ptr[n + 1];
  int nb = end - beg;
  float a0=0.f,a1=0.f,a2=0.f,a3=0.f,a4=0.f,a5=0.f,a6=0.f,a7=0.f;
  float den = 0.f, t0 = 0.f, t1 = 0.f;
  for (int cb = 0; cb < nb; cb += 64){
    int sv = (cb + lane < nb) ? src_s[beg + cb + lane] : 0;
    int m = min(64, nb - cb);
    int u = 0;
    for (; u + 8 <= m; u += 8){
      EDGE_STEP(u + grp, false)
      EDGE_STEP(u + 4 + grp, false)
    }
    int rem = m - u;
    if (rem > 0){
      EDGE_STEP(u + grp, true)
      if (rem > 4){
        EDGE_STEP(u + 4 + grp, true)
      }
    }
  }
  a0 += __shfl_xor(a0, 16); a0 += __shfl_xor(a0, 32);
  a1 += __shfl_xor(a1, 16); a1 += __shfl_xor(a1, 32);
  a2 += __shfl_xor(a2, 16); a2 += __shfl_xor(a2, 32);
  a3 += __shfl_xor(a3, 16); a3 += __shfl_xor(a3, 32);
  a4 += __shfl_xor(a4, 16); a4 += __shfl_xor(a4, 32);
  a5 += __shfl_xor(a5, 16); a5 += __shfl_xor(a5, 32);
  a6 += __shfl_xor(a6, 16); a6 += __shfl_xor(a6, 32);
  a7 += __shfl_xor(a7, 16); a7 += __shfl_xor(a7, 32);
  den += __shfl_xor(den, 16); den += __shfl_xor(den, 32);
  t0 += __shfl_xor(t0, 16); t0 += __shfl_xor(t0, 32);
  t1 += __shfl_xor(t1, 16); t1 += __shfl_xor(t1, 32);
  if (lane < 16){
    float4 o0 = {a0, a1, a2, a3};
    float4 o1 = {a4, a5, a6, a7};
    *(float4*)(accp + (size_t)n * 128 + chb) = o0;
    *(float4*)(accp + (size_t)n * 128 + chb + 4) = o1;
    *(float2*)(tbuf + (size_t)n * 32 + h * 16 + 2 * l8) = make_float2(t0, t1);
    if (l8 == 0) dbuf[(size_t)n * 2 + h] = den;
  }
}

// MFMA combine v2 (unchanged from round 13).
__global__ __launch_bounds__(256) void combine2_k(const float* __restrict__ accp,
    const float* __restrict__ sk, const float* __restrict__ bw,
    const unsigned short* __restrict__ twh, const unsigned short* __restrict__ twl,
    const float* __restrict__ tb, const unsigned short* __restrict__ bdh,
    const unsigned short* __restrict__ bdl, const float* __restrict__ tbuf,
    const float* __restrict__ dbuf, float* __restrict__ h2, float* __restrict__ bn_acc){
  __shared__ float ext[64][132];
  __shared__ bf16x8 afh[4][4][64];
  __shared__ bf16x8 afl[4][4][64];
  __shared__ float bws[384];
  __shared__ float bsum[64], bsq[64];
  int t = threadIdx.x;
  int w = t >> 6, lane = t & 63;
  for (int i = t; i < 384; i += 256) bws[i] = bw[i];
  if (t < 64){ bsum[t] = 0.f; bsq[t] = 0.f; }
  {
    int row = lane & 15, kg = lane >> 4;
    int nrow = blockIdx.x * 64 + w * 16 + row;
    if (nrow >= NN) nrow = NN - 1;
    float4 tva = *(const float4*)(tbuf + (size_t)nrow * 32 + kg * 8);
    float4 tvb = *(const float4*)(tbuf + (size_t)nrow * 32 + kg * 8 + 4);
    float tv[8] = {tva.x, tva.y, tva.z, tva.w, tvb.x, tvb.y, tvb.z, tvb.w};
    bf16x8 th, tlw;
    #pragma unroll
    for (int j = 0; j < 8; j++){
      unsigned hb = f2bf(tv[j]);
      th[j] = (short)hb;
      tlw[j] = (short)f2bf(tv[j] - __uint_as_float(hb << 16));
    }
    #pragma unroll
    for (int ct = 0; ct < 8; ct++){
      f32x4 ae = (f32x4){0.f,0.f,0.f,0.f};
      size_t idx = ((size_t)(ct * 64 + lane)) * 8;
      bf16x8 bh = *(const bf16x8*)(bdh + idx);
      bf16x8 bl = *(const bf16x8*)(bdl + idx);
      ae = __builtin_amdgcn_mfma_f32_16x16x32_bf16(th, bh, ae, 0, 0, 0);
      ae = __builtin_amdgcn_mfma_f32_16x16x32_bf16(tlw, bh, ae, 0, 0, 0);
      ae = __builtin_amdgcn_mfma_f32_16x16x32_bf16(th, bl, ae, 0, 0, 0);
      #pragma unroll
      for (int j = 0; j < 4; j++)
        ext[w * 16 + kg * 4 + j][ct * 16 + row] = ae[j];
    }
  }
  int nl = t >> 2, q = t & 3;
  int n = blockIdx.x * 64 + nl;
  bool valid = n < NN;
  float o[32], r[32];
  if (valid){
    const float* ap = accp + (size_t)n * 128 + q * 32;
    const float* sp = sk   + (size_t)n * 128 + q * 32;
    #pragma unroll
    for (int i = 0; i < 32; i += 4){
      float4 va = *(const float4*)(ap + i);
      float4 vr = *(const float4*)(sp + i);
      o[i] = va.x; o[i+1] = va.y; o[i+2] = va.z; o[i+3] = va.w;
      r[i] = vr.x; r[i+1] = vr.y; r[i+2] = vr.z; r[i+3] = vr.w;
    }
  } else {
    #pragma unroll
    for (int i = 0; i < 32; i++){ o[i] = 0.f; r[i] = 0.f; }
  }
  float dh = valid ? dbuf[(size_t)n * 2 + (q >> 1)] : 0.f;
  float invden = dh > 0.f ? 1.f / dh : 0.f;
  __syncthreads();
  #pragma unroll
  for (int i = 0; i < 32; i++)
    o[i] = (o[i] + ext[nl][q * 32 + i]) * invden;
  float pp = 0.f;
  #pragma unroll
  for (int i = 0; i < 32; i++){
    int c = q * 32 + i;
    pp += o[i] * bws[c] + r[i] * bws[128 + c] + (o[i] - r[i]) * bws[256 + c];
  }
  pp += __shfl_xor(pp, 1); pp += __shfl_xor(pp, 2);
  float beta = 1.f / (1.f + __expf(-pp));
  int w2 = t >> 6;
  int r0 = (t & 63) >> 2;
  #pragma unroll
  for (int kg = 0; kg < 4; kg++){
    bf16x8 hv, lv;
    #pragma unroll
    for (int j = 0; j < 8; j++){
      int i = kg * 8 + j;
      float hc = o[i] + beta * (r[i] - o[i]);
      unsigned hb = f2bf(hc);
      hv[j] = (short)hb;
      lv[j] = (short)f2bf(hc - __uint_as_float(hb << 16));
    }
    afh[w2][q][kg * 16 + r0] = hv;
    afl[w2][q][kg * 16 + r0] = lv;
  }
  __syncthreads();
  bf16x8 ah[4], al[4];
  #pragma unroll
  for (int kk = 0; kk < 4; kk++){ ah[kk] = afh[w][kk][lane]; al[kk] = afl[w][kk][lane]; }
  int brow = blockIdx.x * 64 + w * 16;
  #pragma unroll
  for (int ct = 0; ct < 4; ct++){
    f32x4 acc = (f32x4){0.f,0.f,0.f,0.f};
    #pragma unroll
    for (int kk = 0; kk < 4; kk++){
      size_t idx = (((size_t)(ct * 4 + kk)) * 64 + lane) * 8;
      bf16x8 bh = *(const bf16x8*)(twh + idx);
      bf16x8 bl = *(const bf16x8*)(twl + idx);
      acc = __builtin_amdgcn_mfma_f32_16x16x32_bf16(ah[kk], bh, acc, 0, 0, 0);
      acc = __builtin_amdgcn_mfma_f32_16x16x32_bf16(al[kk], bh, acc, 0, 0, 0);
      acc = __builtin_amdgcn_mfma_f32_16x16x32_bf16(ah[kk], bl, acc, 0, 0, 0);
    }
    int col = ct * 16 + (lane & 15);
    float bias = tb[col];
    float ps = 0.f, pq = 0.f;
    #pragma unroll
    for (int j = 0; j < 4; j++){
      int row = brow + (lane >> 4) * 4 + j;
      float s = acc[j] + bias;
      float v = s > 0.f ? s : 0.01f * s;
      if (row < NN){
        h2[(size_t)row * 64 + col] = v;
        ps += v; pq += v * v;
      }
    }
    ps += __shfl_xor(ps, 16); ps += __shfl_xor(ps, 32);
    pq += __shfl_xor(pq, 16); pq += __shfl_xor(pq, 32);
    if (lane < 16){
      atomicAdd(&bsum[col], ps);
      atomicAdd(&bsq[col], pq);
    }
  }
  __syncthreads();
  if (t < 64){
    atomicAdd(&bn_acc[t], bsum[t]);
    atomicAdd(&bn_acc[64 + t], bsq[t]);
  }
}

__global__ void bn_final_k(const float* __restrict__ bn_acc, const float* __restrict__ bnw,
                           const float* __restrict__ bnb, float* __restrict__ ss){
  int j = threadIdx.x;
  if (j < 64){
    float m = bn_acc[j] / (float)NN;
    float v = bn_acc[64 + j] / (float)NN - m * m;
    float sc = bnw[j] * rsqrtf(v + EPS_BN);
    ss[j] = sc;
    ss[64 + j] = bnb[j] - m * sc;
  }
}

// BN apply -> split bf16 h in FRAGMENT-MAJOR layout (NK=2) + pooled max/sum
__global__ __launch_bounds__(256) void bn_apply_k(const float* __restrict__ h2,
    const float* __restrict__ ss, const int* __restrict__ batch,
    unsigned short* __restrict__ hbh, unsigned short* __restrict__ hbl,
    float* __restrict__ gsum, unsigned* __restrict__ gmax,
    int do_pool){
  int wid = (blockIdx.x * 256 + threadIdx.x) >> 6;
  int lane = threadIdx.x & 63;
  const int CH = (NN + 1023) / 1024;
  int start = wid * CH;
  int end = start + CH; if (end > NN) end = NN;
  float sc = ss[lane], sh = ss[64 + lane];
  int kk = lane >> 5, kg = (lane & 31) >> 3, j = lane & 7;
  int curg = -1; float lmax = 0.f, lsum = 0.f;
  for (int n = start; n < end; n++){
    float v = h2[(size_t)n * 64 + lane] * sc + sh;
    size_t idx = fragidx((n >> 4), 2, kk, kg * 16 + (n & 15), j);
    f2bf_split(v, &hbh[idx], &hbl[idx]);
    if (do_pool){
      int g = batch[n];
      if (g != curg){
        if (curg >= 0){
          atomicAdd(&gsum[curg * 64 + lane], lsum);
          atomicMax(&gmax[curg * 64 + lane], encf(lmax));
        }
        curg = g; lmax = v; lsum = v;
      } else {
        lmax = fmaxf(lmax, v); lsum += v;
      }
    }
  }
  if (do_pool && curg >= 0){
    atomicAdd(&gsum[curg * 64 + lane], lsum);
    atomicMax(&gmax[curg * 64 + lane], encf(lmax));
  }
}

__global__ void pool_final_k(const float* __restrict__ gsum, const unsigned* __restrict__ gmax,
                             const int* __restrict__ counts, float* __restrict__ gr){
  int i = blockIdx.x * 256 + threadIdx.x;
  if (i < NG * 64){
    int g = i >> 6, j = i & 63;
    unsigned e = gmax[i];
    float mx = e ? decf(e) : 0.f;
    int c = counts[g]; if (c < 1) c = 1;
    gr[g * 128 + j]       += mx;
    gr[g * 128 + 64 + j]  += gsum[i] / (float)c;
  }
}

extern "C" void kernel_launch(void* const* d_in, const int* in_sizes, int n_in,
                              void* d_out, int out_size, void* d_ws, size_t ws_size,
                              hipStream_t stream){
  const float* x     = (const float*)d_in[0];
  const float* ea    = (const float*)d_in[1];
  const int*   eidx  = (const int*)d_in[2];
  const int*   batch = (const int*)d_in[3];
  const float* c1_qw = (const float*)d_in[4];
  const float* c1_qb = (const float*)d_in[5];
  const float* c1_kw = (const float*)d_in[6];
  const float* c1_kb = (const float*)d_in[7];
  const float* c1_vw = (const float*)d_in[8];
  const float* c1_vb = (const float*)d_in[9];
  const float* c1_ew = (const float*)d_in[10];
  const float* c1_skw= (const float*)d_in[11];
  const float* c1_skb= (const float*)d_in[12];
  const float* c1_bw = (const float*)d_in[13];
  const float* c1_tw = (const float*)d_in[14];
  const float* c1_tb = (const float*)d_in[15];
  const float* c1_bnw= (const float*)d_in[16];
  const float* c1_bnb= (const float*)d_in[17];
  const float* L_qw  = (const float*)d_in[18];
  const float* L_qb  = (const float*)d_in[19];
  const float* L_kw  = (const float*)d_in[20];
  const float* L_kb  = (const float*)d_in[21];
  const float* L_vw  = (const float*)d_in[22];
  const float* L_vb  = (const float*)d_in[23];
  const float* L_ew  = (const float*)d_in[24];
  const float* L_skw = (const float*)d_in[25];
  const float* L_skb = (const float*)d_in[26];
  const float* L_bw  = (const float*)d_in[27];
  const float* L_tw  = (const float*)d_in[28];
  const float* L_tb  = (const float*)d_in[29];
  const float* L_bnw = (const float*)d_in[30];
  const float* L_bnb = (const float*)d_in[31];
  const int* srcs = eidx;
  const int* dsts = eidx + NE;

  char* p = (char*)d_ws;
  auto carve = [&](size_t bytes) -> void* {
    void* r = (void*)p;
    p += (bytes + 255) & ~(size_t)255;
    return r;
  };
  unsigned short* Wh = (unsigned short*)carve(512 * 128 * sizeof(unsigned short));
  unsigned short* Wl = (unsigned short*)carve(512 * 128 * sizeof(unsigned short));
  float*    bp     = (float*)carve(512 * sizeof(float));
  unsigned short* twph = (unsigned short*)carve(64 * 128 * sizeof(unsigned short));
  unsigned short* twpl = (unsigned short*)carve(64 * 128 * sizeof(unsigned short));
  unsigned short* bdh = (unsigned short*)carve(32 * 128 * sizeof(unsigned short));
  unsigned short* bdl = (unsigned short*)carve(32 * 128 * sizeof(unsigned short));
  float*    qf     = (float*)carve((size_t)NN * 128 * sizeof(float));
  float*    skb_   = (float*)carve((size_t)NN * 128 * sizeof(float));
  unsigned* kvb    = (unsigned*)carve((size_t)NN * 128 * sizeof(unsigned));
  unsigned* eab    = (unsigned*)carve((size_t)NE * 8 * sizeof(unsigned));
  float*    qe     = (float*)carve((size_t)NN * 32 * sizeof(float));
  float*    attn   = (float*)carve((size_t)NN * 128 * sizeof(float));
  float*    tbuf   = (float*)carve((size_t)NN * 32 * sizeof(float));
  float*    dbuf   = (float*)carve((size_t)NN * 2 * sizeof(float));
  unsigned short* xbh = (unsigned short*)carve((size_t)NN * FIN * sizeof(unsigned short));
  unsigned short* xbl = (unsigned short*)carve((size_t)NN * FIN * sizeof(unsigned short));
  unsigned short* hbh = (unsigned short*)carve((size_t)NN * 64 * sizeof(unsigned short));
  unsigned short* hbl = (unsigned short*)carve((size_t)NN * 64 * sizeof(unsigned short));
  float*    h2     = (float*)carve((size_t)NN * 64 * sizeof(float));
  // contiguous zero block: bn_acc[4][128] + gsum[3][NG*64] + gmax[3][NG*64]
  float*    bn_acc4 = (float*)carve(4 * 128 * sizeof(float));
  float*    gsum3  = (float*)carve(3 * (size_t)NG * 64 * sizeof(float));
  unsigned* gmax3  = (unsigned*)carve(3 * (size_t)NG * 64 * sizeof(unsigned));
  float*    ss     = (float*)carve(128 * sizeof(float));
  int*      deg    = (int*)carve(NN * sizeof(int));
  int*      row_ptr= (int*)carve((NN + 1) * sizeof(int));
  int*      eid    = (int*)carve((size_t)NE * sizeof(int));
  int*      src_s  = (int*)carve((size_t)NE * sizeof(int));
  int*      counts = (int*)carve(NG * sizeof(int));
  int*      starts = (int*)carve((NG + 1) * sizeof(int));
  int*      bsums  = (int*)carve(256 * sizeof(int));

  size_t zero_bytes = (4 * 128 * sizeof(float) + 255 & ~(size_t)255)
                    + (3 * (size_t)NG * 64 * sizeof(float) + 255 & ~(size_t)255)
                    + (3 * (size_t)NG * 64 * sizeof(unsigned) + 255 & ~(size_t)255);
  hipMemsetAsync(d_out, 0, (size_t)out_size * sizeof(float), stream);
  hipMemsetAsync(deg, 0, NN * sizeof(int), stream);
  hipMemsetAsync(bn_acc4, 0, zero_bytes, stream);
  hist_k<<<(NE + 255) / 256, 256, 0, stream>>>(dsts, deg);
  bounds_k<<<(NN + 255) / 256, 256, 0, stream>>>(batch, starts);
  counts_from_starts_k<<<1, 64, 0, stream>>>(starts, counts);
  scan1_k<<<SCAN_B, 256, 0, stream>>>(deg, bsums);
  scan2_k<<<1, 256, 0, stream>>>(bsums);
  scan3_k<<<SCAN_B, 256, 0, stream>>>(deg, bsums, row_ptr, deg);  // deg becomes cursor
  scatter_k<<<(NE + 255) / 256, 256, 0, stream>>>(dsts, srcs, deg, eid, src_s);
  pack_ea_k<<<(NE * 2 + 255) / 256, 256, 0, stream>>>(ea, eid, eab);
  tobf2_k<<<(NN * FIN + 255) / 256, 256, 0, stream>>>(x, xbh, xbl);

  const unsigned short* hin_h = xbh;
  const unsigned short* hin_l = xbl;
  for (int L = 0; L < 4; L++){
    int D = (L == 0) ? FIN : EMB;
    const float *qw,*qb,*kw,*kb,*vw,*vb,*eww,*skw,*skb,*bww,*tw,*tb,*bnw,*bnb;
    if (L == 0){
      qw=c1_qw; qb=c1_qb; kw=c1_kw; kb=c1_kb; vw=c1_vw; vb=c1_vb;
      eww=c1_ew; skw=c1_skw; skb=c1_skb; bww=c1_bw; tw=c1_tw; tb=c1_tb;
      bnw=c1_bnw; bnb=c1_bnb;
    } else {
      int i = L - 1;
      qw = L_qw + (size_t)i * HCC * EMB;  qb = L_qb + (size_t)i * HCC;
      kw = L_kw + (size_t)i * HCC * EMB;  kb = L_kb + (size_t)i * HCC;
      vw = L_vw + (size_t)i * HCC * EMB;  vb = L_vb + (size_t)i * HCC;
      eww= L_ew + (size_t)i * HCC * EDIM;
      skw= L_skw+ (size_t)i * HCC * EMB;  skb= L_skb+ (size_t)i * HCC;
      bww= L_bw + (size_t)i * 3 * HCC;
      tw = L_tw + (size_t)i * EMB * HCC;  tb = L_tb + (size_t)i * EMB;
      bnw= L_bnw+ (size_t)i * EMB;        bnb= L_bnb+ (size_t)i * EMB;
    }
    float* bn_acc = bn_acc4 + L * 128;
    float* gsum = gsum3 + (size_t)(L > 0 ? L - 1 : 0) * NG * 64;
    unsigned* gmax = gmax3 + (size_t)(L > 0 ? L - 1 : 0) * NG * 64;
    pack_all_k<<<256, 256, 0, stream>>>(qw, kw, vw, skw, qb, kb, vb, skb, tw, eww,
                                        Wh, Wl, bp, twph, twpl, bdh, bdl, D);
    dim3 gg((NN + 63) / 64, 4);
    if (D == 128) gemm5_k<128><<<gg, 256, 0, stream>>>(hin_h, hin_l, Wh, Wl, bp, qf, kvb, skb_);
    else          gemm5_k<64><<<gg, 256, 0, stream>>>(hin_h, hin_l, Wh, Wl, bp, qf, kvb, skb_);
    qe_k<<<(NN + 7) / 8, 256, 0, stream>>>(qf, eww, qe);
    edge_k<<<(NN * 64 + 255) / 256, 256, 0, stream>>>(qf, kvb, eab, qe, row_ptr, src_s, attn, tbuf, dbuf);
    combine2_k<<<(NN + 63) / 64, 256, 0, stream>>>(attn, skb_, bww, twph, twpl, tb, bdh, bdl, tbuf, dbuf, h2, bn_acc);
    bn_final_k<<<1, 64, 0, stream>>>(bn_acc, bnw, bnb, ss);
    bn_apply_k<<<256, 256, 0, stream>>>(h2, ss, batch, hbh, hbl, gsum, gmax, (L > 0) ? 1 : 0);
    if (L > 0) pool_final_k<<<(NG * 64 + 255) / 256, 256, 0, stream>>>(gsum, gmax, counts, (float*)d_out);
    hin_h = hbh; hin_l = hbl;
  }
}

// Round 15
// 806.889 us; speedup vs baseline: 1.7456x; 1.1175x over previous
//
#include <hip/hip_runtime.h>

#define NN 50000
#define NE 800000
#define FIN 128
#define EDIM 16
#define EMB 64
#define NH 2
#define NLAYERS 3
#define NG 64
#define HCC 128
#define INV_SQRT_D 0.125f
#define EPS_BN 1e-5f
#define SCAN_B 196   // ceil(NN/256)
#define SCALE_L2E 0.18033688f   // 0.125 * log2(e)
#define NRT (NN / 16)            // 3125 row tiles

typedef __attribute__((ext_vector_type(8))) short bf16x8;
typedef __attribute__((ext_vector_type(4))) float f32x4;

__device__ __forceinline__ unsigned encf(float f){
  unsigned u = __float_as_uint(f);
  return (u & 0x80000000u) ? ~u : (u | 0x80000000u);
}
__device__ __forceinline__ float decf(unsigned e){
  unsigned u = (e & 0x80000000u) ? (e ^ 0x80000000u) : ~e;
  return __uint_as_float(u);
}
__device__ __forceinline__ unsigned f2bf(float x){   // RNE bf16, returned in low 16
  unsigned u = __float_as_uint(x);
  return (u + 0x7fffu + ((u >> 16) & 1u)) >> 16;
}
// split fp32 -> hi + lo bf16 (a ~= hi + lo, |lo| <= 2^-9 |a|)
__device__ __forceinline__ void f2bf_split(float x, unsigned short* hi, unsigned short* lo){
  unsigned h = f2bf(x);
  float hf = __uint_as_float(h << 16);
  *hi = (unsigned short)h;
  *lo = (unsigned short)f2bf(x - hf);
}
// fragment-major index: element (tile16, kk, lane, j) -> flat offset (in halves)
__device__ __forceinline__ size_t fragidx(int tile, int NK, int kk, int lane, int j){
  return (((size_t)tile * NK + kk) * 64 + lane) * 8 + j;
}

__global__ void hist_k(const int* __restrict__ dst, int* __restrict__ deg){
  int i = blockIdx.x * 256 + threadIdx.x;
  if (i < NE) atomicAdd(&deg[dst[i]], 1);
}

__global__ void bounds_k(const int* __restrict__ batch, int* __restrict__ starts){
  int i = blockIdx.x * 256 + threadIdx.x;
  if (i >= NN) return;
  int g = batch[i];
  int gp = (i == 0) ? -1 : batch[i - 1];
  for (int gg = gp + 1; gg <= g; gg++) starts[gg] = i;
  if (i == NN - 1){
    for (int gg = g + 1; gg <= NG; gg++) starts[gg] = NN;
  }
}

__global__ void counts_from_starts_k(const int* __restrict__ starts, int* __restrict__ counts){
  int g = threadIdx.x;
  if (g < NG) counts[g] = starts[g + 1] - starts[g];
}

__global__ void scan1_k(const int* __restrict__ deg, int* __restrict__ bsums){
  __shared__ int lds[256];
  int b = blockIdx.x, t = threadIdx.x;
  int idx = b * 256 + t;
  lds[t] = (idx < NN) ? deg[idx] : 0;
  __syncthreads();
  for (int off = 128; off >= 1; off >>= 1){
    if (t < off) lds[t] += lds[t + off];
    __syncthreads();
  }
  if (t == 0) bsums[b] = lds[0];
}

__global__ void scan2_k(int* __restrict__ bsums){
  __shared__ int lds[256];
  int t = threadIdx.x;
  int v = (t < SCAN_B) ? bsums[t] : 0;
  int x = v;
  lds[t] = x;
  __syncthreads();
  for (int off = 1; off < 256; off <<= 1){
    int y = (t >= off) ? lds[t - off] : 0;
    __syncthreads();
    x += y;
    lds[t] = x;
    __syncthreads();
  }
  if (t < SCAN_B) bsums[t] = x - v;   // exclusive
}

// scan3 also initializes the scatter cursor.
__global__ void scan3_k(const int* __restrict__ degin, const int* __restrict__ bsums,
                        int* __restrict__ row_ptr, int* __restrict__ cur){
  __shared__ int lds[256];
  int b = blockIdx.x, t = threadIdx.x;
  int idx = b * 256 + t;
  int v = (idx < NN) ? degin[idx] : 0;
  int x = v;
  lds[t] = x;
  __syncthreads();
  for (int off = 1; off < 256; off <<= 1){
    int y = (t >= off) ? lds[t - off] : 0;
    __syncthreads();
    x += y;
    lds[t] = x;
    __syncthreads();
  }
  int val = bsums[b] + x - v;
  if (idx <= NN) row_ptr[idx] = val;
  if (idx < NN) cur[idx] = val;
}

__global__ void scatter_k(const int* __restrict__ dst, const int* __restrict__ src,
                          int* __restrict__ cur, int* __restrict__ eid,
                          int* __restrict__ src_s){
  int i = blockIdx.x * 256 + threadIdx.x;
  if (i < NE){
    int p = atomicAdd(&cur[dst[i]], 1);
    eid[p] = i;
    src_s[p] = src[i];
  }
}

// edge_attr -> bf16, reordered into CSR position order.
__global__ void pack_ea_k(const float* __restrict__ ea, const int* __restrict__ eid,
                          unsigned* __restrict__ eab){
  int i = blockIdx.x * 256 + threadIdx.x;
  if (i >= NE * 2) return;
  int p = i >> 1, half = i & 1;
  int e = eid[p];
  const float* s = ea + (size_t)e * 16 + half * 8;
  float4 a = *(const float4*)(s);
  float4 b = *(const float4*)(s + 4);
  uint4 o;
  o.x = f2bf(a.x) | (f2bf(a.y) << 16);
  o.y = f2bf(a.z) | (f2bf(a.w) << 16);
  o.z = f2bf(b.x) | (f2bf(b.y) << 16);
  o.w = f2bf(b.z) | (f2bf(b.w) << 16);
  ((uint4*)eab)[(size_t)p * 2 + half] = o;
}

// x (fp32, NN x 128) -> split bf16 in MFMA-fragment-major layout (NK=4)
__global__ void tobf2_k(const float* __restrict__ in, unsigned short* __restrict__ hi,
                        unsigned short* __restrict__ lo){
  int i = blockIdx.x * 256 + threadIdx.x;
  if (i >= NN * 128) return;
  int n = i >> 7, c = i & 127;
  int rt = n >> 4, rr = n & 15;
  int kk = c >> 5, kg = (c & 31) >> 3, j = c & 7;
  size_t idx = fragidx(rt, 4, kk, kg * 16 + rr, j);
  f2bf_split(in[i], &hi[idx], &lo[idx]);
}

// ALL per-layer weight packing fused, WITH BN folding (use_ss: W'=W*sc, b'=b+W.sh).
__global__ void pack_all_k(const float* __restrict__ qw, const float* __restrict__ kw,
                           const float* __restrict__ vw, const float* __restrict__ skw,
                           const float* __restrict__ qb, const float* __restrict__ kb,
                           const float* __restrict__ vb, const float* __restrict__ skb,
                           const float* __restrict__ tw, const float* __restrict__ ew,
                           const float* __restrict__ ss, int use_ss,
                           unsigned short* __restrict__ W2h, unsigned short* __restrict__ W2l,
                           float* __restrict__ bp,
                           unsigned short* __restrict__ twh, unsigned short* __restrict__ twl,
                           unsigned short* __restrict__ bdh, unsigned short* __restrict__ bdl,
                           int D){
  int i = blockIdx.x * 256 + threadIdx.x;
  int NK = D / 32;
  if (i < 512 * D){
    int c = i / D, d = i - c * D;
    const float* w = (c < 128) ? qw : (c < 256) ? kw : (c < 384) ? vw : skw;
    float wv = w[(c & 127) * D + d];
    if (use_ss) wv *= ss[d];
    int tile = c >> 4, rr = c & 15;
    int kk = d >> 5, kg = (d & 31) >> 3, j = d & 7;
    size_t idx = fragidx(tile, NK, kk, kg * 16 + rr, j);
    f2bf_split(wv, &W2h[idx], &W2l[idx]);
  }
  if (i < 512){
    const float* b = (i < 128) ? qb : (i < 256) ? kb : (i < 384) ? vb : skb;
    const float* w = (i < 128) ? qw : (i < 256) ? kw : (i < 384) ? vw : skw;
    float bb = b[i & 127];
    if (use_ss){
      float acc = 0.f;
      const float* wr = w + (size_t)(i & 127) * 64;
      #pragma unroll 8
      for (int c = 0; c < 64; c++) acc += wr[c] * ss[64 + c];
      bb += acc;
    }
    bp[i] = bb;
  }
  if (i < 64 * 128){
    int col = i >> 7, k = i & 127;
    int ct = col >> 4, rr = col & 15;
    int kk = k >> 5, kg = (k & 31) >> 3, j = k & 7;
    size_t idx = fragidx(ct, 4, kk, kg * 16 + rr, j);
    f2bf_split(tw[i], &twh[idx], &twl[idx]);
  }
  if (i < 32 * 128){
    int k = i >> 7, c = i & 127;
    float val = ((k >> 4) == (c >> 6)) ? ew[c * 16 + (k & 15)] : 0.f;
    int ct = c >> 4, rr = c & 15;
    int kg = k >> 3, j = k & 7;
    size_t idx = ((size_t)(ct * 64 + kg * 16 + rr)) * 8 + j;
    f2bf_split(val, &bdh[idx], &bdl[idx]);
  }
}

// Fused qkvs GEMM, fragment-major; part0 additionally computes qe via LDS
// (q-tile block-resident) and stores q as bf16 with SCALE_L2E prefolded.
template<int D>
__global__ __launch_bounds__(256, 4) void gemm6_k(const unsigned short* __restrict__ A2h,
                                                  const unsigned short* __restrict__ A2l,
                                                  const unsigned short* __restrict__ W2h,
                                                  const unsigned short* __restrict__ W2l,
                                                  const float* __restrict__ bp,
                                                  const float* __restrict__ ew,
                                                  unsigned short* __restrict__ qb16,
                                                  float* __restrict__ qe,
                                                  unsigned* __restrict__ kvb,
                                                  float* __restrict__ sk){
  __shared__ float qs[64][128];
  __shared__ float ews[2048];
  const int NK = D / 32;
  int t = threadIdx.x;
  int w = t >> 6, lane = t & 63;
  int brow = blockIdx.x * 64 + w * 16;
  int part = blockIdx.y;
  int r = lane & 15, kg = lane >> 4;
  int rt = brow >> 4; if (rt > NRT - 1) rt = NRT - 1;
  int cb0 = (part == 0) ? 0 : (part == 1) ? 2 : (part == 2) ? 3 : 6;
  int cb1 = (part == 0) ? 1 : (part == 1) ? 4 : (part == 2) ? 5 : 7;
  f32x4 acc0[4], acc1[4];
  #pragma unroll
  for (int tt = 0; tt < 4; tt++){
    acc0[tt] = (f32x4){0.f,0.f,0.f,0.f};
    acc1[tt] = (f32x4){0.f,0.f,0.f,0.f};
  }
  const unsigned short* a2hp = A2h + ((size_t)rt * NK) * 512 + lane * 8;
  const unsigned short* a2lp = A2l + ((size_t)rt * NK) * 512 + lane * 8;
  #pragma unroll
  for (int kk = 0; kk < NK; kk++){
    bf16x8 ah = *(const bf16x8*)(a2hp + kk * 512);
    bf16x8 al = *(const bf16x8*)(a2lp + kk * 512);
    bf16x8 b0h[4], b0l[4], b1h[4], b1l[4];
    #pragma unroll
    for (int tt = 0; tt < 4; tt++){
      size_t i0 = fragidx(cb0 * 4 + tt, NK, kk, lane, 0);
      size_t i1 = fragidx(cb1 * 4 + tt, NK, kk, lane, 0);
      b0h[tt] = *(const bf16x8*)(W2h + i0);
      b0l[tt] = *(const bf16x8*)(W2l + i0);
      b1h[tt] = *(const bf16x8*)(W2h + i1);
      b1l[tt] = *(const bf16x8*)(W2l + i1);
    }
    #pragma unroll
    for (int tt = 0; tt < 4; tt++){
      acc0[tt] = __builtin_amdgcn_mfma_f32_16x16x32_bf16(ah, b0h[tt], acc0[tt], 0, 0, 0);
      acc1[tt] = __builtin_amdgcn_mfma_f32_16x16x32_bf16(ah, b1h[tt], acc1[tt], 0, 0, 0);
      acc0[tt] = __builtin_amdgcn_mfma_f32_16x16x32_bf16(al, b0h[tt], acc0[tt], 0, 0, 0);
      acc1[tt] = __builtin_amdgcn_mfma_f32_16x16x32_bf16(al, b1h[tt], acc1[tt], 0, 0, 0);
      acc0[tt] = __builtin_amdgcn_mfma_f32_16x16x32_bf16(ah, b0l[tt], acc0[tt], 0, 0, 0);
      acc1[tt] = __builtin_amdgcn_mfma_f32_16x16x32_bf16(ah, b1l[tt], acc1[tt], 0, 0, 0);
    }
  }
  int rowbase = brow + kg * 4;
  if (part == 0){
    for (int i = t; i < 2048; i += 256) ews[i] = ew[i];
    #pragma unroll
    for (int tt = 0; tt < 4; tt++){
      int ch0 = tt * 16 + r, ch1 = 64 + tt * 16 + r;
      float b0 = bp[ch0], b1 = bp[ch1];
      #pragma unroll
      for (int j = 0; j < 4; j++){
        int row = rowbase + j;
        float v0 = acc0[tt][j] + b0;
        float v1 = acc1[tt][j] + b1;
        qs[w * 16 + kg * 4 + j][ch0] = v0;
        qs[w * 16 + kg * 4 + j][ch1] = v1;
        if (row < NN){
          qb16[(size_t)row * 128 + ch0] = (unsigned short)f2bf(v0 * SCALE_L2E);
          qb16[(size_t)row * 128 + ch1] = (unsigned short)f2bf(v1 * SCALE_L2E);
        }
      }
    }
    __syncthreads();
    #pragma unroll
    for (int i = 0; i < 8; i++){
      int idx = t + 256 * i;           // 0..2047
      int nl = idx >> 5, hd = idx & 31;
      int h = hd >> 4, d = hd & 15;
      float s = 0.f;
      #pragma unroll 8
      for (int c = 0; c < 64; c++)
        s += qs[nl][h * 64 + c] * ews[(h * 64 + c) * 16 + d];
      int n = blockIdx.x * 64 + nl;
      if (n < NN) qe[(size_t)n * 32 + hd] = s * SCALE_L2E;
    }
  } else if (part == 3){
    #pragma unroll
    for (int tt = 0; tt < 4; tt++){
      int ch0 = tt * 16 + r, ch1 = 64 + tt * 16 + r;
      float b0 = bp[384 + ch0], b1 = bp[384 + ch1];
      #pragma unroll
      for (int j = 0; j < 4; j++){
        int row = rowbase + j;
        if (row < NN){
          sk[(size_t)row * 128 + ch0] = acc0[tt][j] + b0;
          sk[(size_t)row * 128 + ch1] = acc1[tt][j] + b1;
        }
      }
    }
  } else {
    int chbase = (part - 1) * 64;
    #pragma unroll
    for (int tt = 0; tt < 4; tt++){
      int ch = chbase + tt * 16 + r;
      float bk = bp[cb0 * 64 + tt * 16 + r];
      float bv = bp[cb1 * 64 + tt * 16 + r];
      #pragma unroll
      for (int j = 0; j < 4; j++){
        int row = rowbase + j;
        if (row < NN){
          float kk4 = acc0[tt][j] + bk;
          float vv = acc1[tt][j] + bv;
          kvb[(size_t)row * 128 + ch] = f2bf(kk4) | (f2bf(vv) << 16);
        }
      }
    }
  }
}

// One wave per NODE, both heads; q read as prescaled bf16.
#define EDGE_STEP(EOFF, MASKED)                                               \
  {                                                                           \
    int e = (EOFF);                                                           \
    int s = __shfl(sv, e);                                                    \
    const unsigned* kp = kvb + (size_t)s * 128 + chb;                         \
    uint4 kv0 = *(const uint4*)(kp);                                          \
    uint4 kv1 = *(const uint4*)(kp + 4);                                      \
    size_t g = (size_t)(beg + cb + e);                                        \
    if (MASKED && g >= NE) g = NE - 1;                                        \
    unsigned eau = eab_u[g * 8 + l8];                                         \
    float ea0 = __uint_as_float(eau << 16);                                   \
    float ea1 = __uint_as_float(eau & 0xffff0000u);                           \
    float k0 = __uint_as_float(kv0.x << 16), v0 = __uint_as_float(kv0.x & 0xffff0000u); \
    float k1 = __uint_as_float(kv0.y << 16), v1 = __uint_as_float(kv0.y & 0xffff0000u); \
    float k2 = __uint_as_float(kv0.z << 16), v2 = __uint_as_float(kv0.z & 0xffff0000u); \
    float k3 = __uint_as_float(kv0.w << 16), v3 = __uint_as_float(kv0.w & 0xffff0000u); \
    float k4 = __uint_as_float(kv1.x << 16), v4 = __uint_as_float(kv1.x & 0xffff0000u); \
    float k5 = __uint_as_float(kv1.y << 16), v5 = __uint_as_float(kv1.y & 0xffff0000u); \
    float k6 = __uint_as_float(kv1.z << 16), v6 = __uint_as_float(kv1.z & 0xffff0000u); \
    float k7 = __uint_as_float(kv1.w << 16), v7 = __uint_as_float(kv1.w & 0xffff0000u); \
    float p = fmaf(q[0], k0, fmaf(q[1], k1, fmaf(q[2], k2, fmaf(q[3], k3,     \
              fmaf(q[4], k4, fmaf(q[5], k5, fmaf(q[6], k6, fmaf(q[7], k7,     \
              fmaf(qe2.x, ea0, qe2.y * ea1)))))))));                          \
    p += __shfl_xor(p, 1); p += __shfl_xor(p, 2); p += __shfl_xor(p, 4);      \
    float w = exp2f(p);                                                       \
    if (MASKED && e >= m) w = 0.f;                                            \
    a0 = fmaf(v0, w, a0); a1 = fmaf(v1, w, a1);                               \
    a2 = fmaf(v2, w, a2); a3 = fmaf(v3, w, a3);                               \
    a4 = fmaf(v4, w, a4); a5 = fmaf(v5, w, a5);                               \
    a6 = fmaf(v6, w, a6); a7 = fmaf(v7, w, a7);                               \
    den += w; t0 = fmaf(ea0, w, t0); t1 = fmaf(ea1, w, t1);                   \
  }

__global__ __launch_bounds__(256) void edge_k(const unsigned short* __restrict__ qb16,
    const unsigned* __restrict__ kvb, const unsigned* __restrict__ eab_u,
    const float* __restrict__ qe, const int* __restrict__ row_ptr,
    const int* __restrict__ src_s, float* __restrict__ accp,
    float* __restrict__ tbuf, float* __restrict__ dbuf){
  int n = (blockIdx.x * 256 + threadIdx.x) >> 6;
  if (n >= NN) return;
  int lane = threadIdx.x & 63;
  int grp = lane >> 4;
  int l8 = lane & 7;
  int h = (lane >> 3) & 1;
  int chb = h * 64 + l8 * 8;
  float q[8];
  {
    uint4 qv = *(const uint4*)(qb16 + (size_t)n * 128 + chb);
    q[0] = __uint_as_float(qv.x << 16); q[1] = __uint_as_float(qv.x & 0xffff0000u);
    q[2] = __uint_as_float(qv.y << 16); q[3] = __uint_as_float(qv.y & 0xffff0000u);
    q[4] = __uint_as_float(qv.z << 16); q[5] = __uint_as_float(qv.z & 0xffff0000u);
    q[6] = __uint_as_float(qv.w << 16); q[7] = __uint_as_float(qv.w & 0xffff0000u);
  }
  float2 qe2 = *(const float2*)(qe + (size_t)n * 32 + h * 16 + 2 * l8);
  int beg = row_ptr[n], end = row_ptr[n + 1];
  int nb = end - beg;
  float a0=0.f,a1=0.f,a2=0.f,a3=0.f,a4=0.f,a5=0.f,a6=0.f,a7=0.f;
  float den = 0.f, t0 = 0.f, t1 = 0.f;
  for (int cb = 0; cb < nb; cb += 64){
    int sv = (cb + lane < nb) ? src_s[beg + cb + lane] : 0;
    int m = min(64, nb - cb);
    int u = 0;
    for (; u + 8 <= m; u += 8){
      EDGE_STEP(u + grp, false)
      EDGE_STEP(u + 4 + grp, false)
    }
    int rem = m - u;
    if (rem > 0){
      EDGE_STEP(u + grp, true)
      if (rem > 4){
        EDGE_STEP(u + 4 + grp, true)
      }
    }
  }
  a0 += __shfl_xor(a0, 16); a0 += __shfl_xor(a0, 32);
  a1 += __shfl_xor(a1, 16); a1 += __shfl_xor(a1, 32);
  a2 += __shfl_xor(a2, 16); a2 += __shfl_xor(a2, 32);
  a3 += __shfl_xor(a3, 16); a3 += __shfl_xor(a3, 32);
  a4 += __shfl_xor(a4, 16); a4 += __shfl_xor(a4, 32);
  a5 += __shfl_xor(a5, 16); a5 += __shfl_xor(a5, 32);
  a6 += __shfl_xor(a6, 16); a6 += __shfl_xor(a6, 32);
  a7 += __shfl_xor(a7, 16); a7 += __shfl_xor(a7, 32);
  den += __shfl_xor(den, 16); den += __shfl_xor(den, 32);
  t0 += __shfl_xor(t0, 16); t0 += __shfl_xor(t0, 32);
  t1 += __shfl_xor(t1, 16); t1 += __shfl_xor(t1, 32);
  if (lane < 16){
    float4 o0 = {a0, a1, a2, a3};
    float4 o1 = {a4, a5, a6, a7};
    *(float4*)(accp + (size_t)n * 128 + chb) = o0;
    *(float4*)(accp + (size_t)n * 128 + chb + 4) = o1;
    *(float2*)(tbuf + (size_t)n * 32 + h * 16 + 2 * l8) = make_float2(t0, t1);
    if (l8 == 0) dbuf[(size_t)n * 2 + h] = den;
  }
}

// MFMA combine v3: emits next-layer GEMM fragments directly (BN folded into
// next layer's weights); h2 fp32 written only when pooling is needed.
__global__ __launch_bounds__(256) void combine3_k(const float* __restrict__ accp,
    const float* __restrict__ sk, const float* __restrict__ bw,
    const unsigned short* __restrict__ twh, const unsigned short* __restrict__ twl,
    const float* __restrict__ tb, const unsigned short* __restrict__ bdh,
    const unsigned short* __restrict__ bdl, const float* __restrict__ tbuf,
    const float* __restrict__ dbuf, unsigned short* __restrict__ hbh,
    unsigned short* __restrict__ hbl, float* __restrict__ h2,
    float* __restrict__ bn_acc, int do_pool){
  __shared__ float ext[64][132];
  __shared__ bf16x8 afh[4][4][64];
  __shared__ bf16x8 afl[4][4][64];
  __shared__ float bws[384];
  __shared__ float bsum[64], bsq[64];
  int t = threadIdx.x;
  int w = t >> 6, lane = t & 63;
  for (int i = t; i < 384; i += 256) bws[i] = bw[i];
  if (t < 64){ bsum[t] = 0.f; bsq[t] = 0.f; }
  {
    int row = lane & 15, kg = lane >> 4;
    int nrow = blockIdx.x * 64 + w * 16 + row;
    if (nrow >= NN) nrow = NN - 1;
    float4 tva = *(const float4*)(tbuf + (size_t)nrow * 32 + kg * 8);
    float4 tvb = *(const float4*)(tbuf + (size_t)nrow * 32 + kg * 8 + 4);
    float tv[8] = {tva.x, tva.y, tva.z, tva.w, tvb.x, tvb.y, tvb.z, tvb.w};
    bf16x8 th, tlw;
    #pragma unroll
    for (int j = 0; j < 8; j++){
      unsigned hb = f2bf(tv[j]);
      th[j] = (short)hb;
      tlw[j] = (short)f2bf(tv[j] - __uint_as_float(hb << 16));
    }
    #pragma unroll
    for (int ct = 0; ct < 8; ct++){
      f32x4 ae = (f32x4){0.f,0.f,0.f,0.f};
      size_t idx = ((size_t)(ct * 64 + lane)) * 8;
      bf16x8 bh = *(const bf16x8*)(bdh + idx);
      bf16x8 bl = *(const bf16x8*)(bdl + idx);
      ae = __builtin_amdgcn_mfma_f32_16x16x32_bf16(th, bh, ae, 0, 0, 0);
      ae = __builtin_amdgcn_mfma_f32_16x16x32_bf16(tlw, bh, ae, 0, 0, 0);
      ae = __builtin_amdgcn_mfma_f32_16x16x32_bf16(th, bl, ae, 0, 0, 0);
      #pragma unroll
      for (int j = 0; j < 4; j++)
        ext[w * 16 + kg * 4 + j][ct * 16 + row] = ae[j];
    }
  }
  int nl = t >> 2, q = t & 3;
  int n = blockIdx.x * 64 + nl;
  bool valid = n < NN;
  float o[32], r[32];
  if (valid){
    const float* ap = accp + (size_t)n * 128 + q * 32;
    const float* sp = sk   + (size_t)n * 128 + q * 32;
    #pragma unroll
    for (int i = 0; i < 32; i += 4){
      float4 va = *(const float4*)(ap + i);
      float4 vr = *(const float4*)(sp + i);
      o[i] = va.x; o[i+1] = va.y; o[i+2] = va.z; o[i+3] = va.w;
      r[i] = vr.x; r[i+1] = vr.y; r[i+2] = vr.z; r[i+3] = vr.w;
    }
  } else {
    #pragma unroll
    for (int i = 0; i < 32; i++){ o[i] = 0.f; r[i] = 0.f; }
  }
  float dh = valid ? dbuf[(size_t)n * 2 + (q >> 1)] : 0.f;
  float invden = dh > 0.f ? 1.f / dh : 0.f;
  __syncthreads();
  #pragma unroll
  for (int i = 0; i < 32; i++)
    o[i] = (o[i] + ext[nl][q * 32 + i]) * invden;
  float pp = 0.f;
  #pragma unroll
  for (int i = 0; i < 32; i++){
    int c = q * 32 + i;
    pp += o[i] * bws[c] + r[i] * bws[128 + c] + (o[i] - r[i]) * bws[256 + c];
  }
  pp += __shfl_xor(pp, 1); pp += __shfl_xor(pp, 2);
  float beta = 1.f / (1.f + __expf(-pp));
  int w2 = t >> 6;
  int r0 = (t & 63) >> 2;
  #pragma unroll
  for (int kg = 0; kg < 4; kg++){
    bf16x8 hv, lv;
    #pragma unroll
    for (int j = 0; j < 8; j++){
      int i = kg * 8 + j;
      float hc = o[i] + beta * (r[i] - o[i]);
      unsigned hb = f2bf(hc);
      hv[j] = (short)hb;
      lv[j] = (short)f2bf(hc - __uint_as_float(hb << 16));
    }
    afh[w2][q][kg * 16 + r0] = hv;
    afl[w2][q][kg * 16 + r0] = lv;
  }
  __syncthreads();
  bf16x8 ah[4], al[4];
  #pragma unroll
  for (int kk = 0; kk < 4; kk++){ ah[kk] = afh[w][kk][lane]; al[kk] = afl[w][kk][lane]; }
  int brow = blockIdx.x * 64 + w * 16;
  int tile = blockIdx.x * 4 + w;
  #pragma unroll
  for (int ct = 0; ct < 4; ct++){
    f32x4 acc = (f32x4){0.f,0.f,0.f,0.f};
    #pragma unroll
    for (int kk = 0; kk < 4; kk++){
      size_t idx = (((size_t)(ct * 4 + kk)) * 64 + lane) * 8;
      bf16x8 bh = *(const bf16x8*)(twh + idx);
      bf16x8 bl = *(const bf16x8*)(twl + idx);
      acc = __builtin_amdgcn_mfma_f32_16x16x32_bf16(ah[kk], bh, acc, 0, 0, 0);
      acc = __builtin_amdgcn_mfma_f32_16x16x32_bf16(al[kk], bh, acc, 0, 0, 0);
      acc = __builtin_amdgcn_mfma_f32_16x16x32_bf16(ah[kk], bl, acc, 0, 0, 0);
    }
    int col = ct * 16 + (lane & 15);
    float bias = tb[col];
    int kk2 = col >> 5, kg2 = (col & 31) >> 3, jj = col & 7;
    float ps = 0.f, pq = 0.f;
    #pragma unroll
    for (int j = 0; j < 4; j++){
      int rr = (lane >> 4) * 4 + j;
      int row = brow + rr;
      float s = acc[j] + bias;
      float v = s > 0.f ? s : 0.01f * s;
      if (tile < NRT){
        size_t fidx = fragidx(tile, 2, kk2, kg2 * 16 + rr, jj);
        unsigned hb = f2bf(v);
        hbh[fidx] = (unsigned short)hb;
        hbl[fidx] = (unsigned short)f2bf(v - __uint_as_float(hb << 16));
      }
      if (row < NN){
        if (do_pool) h2[(size_t)row * 64 + col] = v;
        ps += v; pq += v * v;
      }
    }
    ps += __shfl_xor(ps, 16); ps += __shfl_xor(ps, 32);
    pq += __shfl_xor(pq, 16); pq += __shfl_xor(pq, 32);
    if (lane < 16){
      atomicAdd(&bsum[col], ps);
      atomicAdd(&bsq[col], pq);
    }
  }
  __syncthreads();
  if (t < 64){
    atomicAdd(&bn_acc[t], bsum[t]);
    atomicAdd(&bn_acc[64 + t], bsq[t]);
  }
}

__global__ void bn_final_k(const float* __restrict__ bn_acc, const float* __restrict__ bnw,
                           const float* __restrict__ bnb, float* __restrict__ ss){
  int j = threadIdx.x;
  if (j < 64){
    float m = bn_acc[j] / (float)NN;
    float v = bn_acc[64 + j] / (float)NN - m * m;
    float sc = bnw[j] * rsqrtf(v + EPS_BN);
    ss[j] = sc;
    ss[64 + j] = bnb[j] - m * sc;
  }
}

// pooling only (normalized on the fly): reads h2, sorted-batch max/sum
__global__ __launch_bounds__(256) void pool_scan_k(const float* __restrict__ h2,
    const float* __restrict__ ss, const int* __restrict__ batch,
    float* __restrict__ gsum, unsigned* __restrict__ gmax){
  int wid = (blockIdx.x * 256 + threadIdx.x) >> 6;
  int lane = threadIdx.x & 63;
  const int CH = (NN + 1023) / 1024;
  int start = wid * CH;
  int end = start + CH; if (end > NN) end = NN;
  float sc = ss[lane], sh = ss[64 + lane];
  int curg = -1; float lmax = 0.f, lsum = 0.f;
  for (int n = start; n < end; n++){
    float v = h2[(size_t)n * 64 + lane] * sc + sh;
    int g = batch[n];
    if (g != curg){
      if (curg >= 0){
        atomicAdd(&gsum[curg * 64 + lane], lsum);
        atomicMax(&gmax[curg * 64 + lane], encf(lmax));
      }
      curg = g; lmax = v; lsum = v;
    } else {
      lmax = fmaxf(lmax, v); lsum += v;
    }
  }
  if (curg >= 0){
    atomicAdd(&gsum[curg * 64 + lane], lsum);
    atomicMax(&gmax[curg * 64 + lane], encf(lmax));
  }
}

// one final pool reduction over all 3 pooled layers
__global__ void pool_final_all_k(const float* __restrict__ gsum3, const unsigned* __restrict__ gmax3,
                                 const int* __restrict__ counts, float* __restrict__ gr){
  int i = blockIdx.x * 256 + threadIdx.x;
  if (i >= NG * 64) return;
  int g = i >> 6, j = i & 63;
  int c = counts[g]; if (c < 1) c = 1;
  float msum = 0.f, ssum = 0.f;
  #pragma unroll
  for (int L = 0; L < 3; L++){
    unsigned e = gmax3[(size_t)L * NG * 64 + i];
    msum += e ? decf(e) : 0.f;
    ssum += gsum3[(size_t)L * NG * 64 + i] / (float)c;
  }
  gr[g * 128 + j]      += msum;
  gr[g * 128 + 64 + j] += ssum;
}

extern "C" void kernel_launch(void* const* d_in, const int* in_sizes, int n_in,
                              void* d_out, int out_size, void* d_ws, size_t ws_size,
                              hipStream_t stream){
  const float* x     = (const float*)d_in[0];
  const float* ea    = (const float*)d_in[1];
  const int*   eidx  = (const int*)d_in[2];
  const int*   batch = (const int*)d_in[3];
  const float* c1_qw = (const float*)d_in[4];
  const float* c1_qb = (const float*)d_in[5];
  const float* c1_kw = (const float*)d_in[6];
  const float* c1_kb = (const float*)d_in[7];
  const float* c1_vw = (const float*)d_in[8];
  const float* c1_vb = (const float*)d_in[9];
  const float* c1_ew = (const float*)d_in[10];
  const float* c1_skw= (const float*)d_in[11];
  const float* c1_skb= (const float*)d_in[12];
  const float* c1_bw = (const float*)d_in[13];
  const float* c1_tw = (const float*)d_in[14];
  const float* c1_tb = (const float*)d_in[15];
  const float* c1_bnw= (const float*)d_in[16];
  const float* c1_bnb= (const float*)d_in[17];
  const float* L_qw  = (const float*)d_in[18];
  const float* L_qb  = (const float*)d_in[19];
  const float* L_kw  = (const float*)d_in[20];
  const float* L_kb  = (const float*)d_in[21];
  const float* L_vw  = (const float*)d_in[22];
  const float* L_vb  = (const float*)d_in[23];
  const float* L_ew  = (const float*)d_in[24];
  const float* L_skw = (const float*)d_in[25];
  const float* L_skb = (const float*)d_in[26];
  const float* L_bw  = (const float*)d_in[27];
  const float* L_tw  = (const float*)d_in[28];
  const float* L_tb  = (const float*)d_in[29];
  const float* L_bnw = (const float*)d_in[30];
  const float* L_bnb = (const float*)d_in[31];
  const int* srcs = eidx;
  const int* dsts = eidx + NE;

  char* p = (char*)d_ws;
  auto carve = [&](size_t bytes) -> void* {
    void* r = (void*)p;
    p += (bytes + 255) & ~(size_t)255;
    return r;
  };
  unsigned short* Wh = (unsigned short*)carve(512 * 128 * sizeof(unsigned short));
  unsigned short* Wl = (unsigned short*)carve(512 * 128 * sizeof(unsigned short));
  float*    bp     = (float*)carve(512 * sizeof(float));
  unsigned short* twph = (unsigned short*)carve(64 * 128 * sizeof(unsigned short));
  unsigned short* twpl = (unsigned short*)carve(64 * 128 * sizeof(unsigned short));
  unsigned short* bdh = (unsigned short*)carve(32 * 128 * sizeof(unsigned short));
  unsigned short* bdl = (unsigned short*)carve(32 * 128 * sizeof(unsigned short));
  unsigned short* qb16 = (unsigned short*)carve((size_t)NN * 128 * sizeof(unsigned short));
  float*    skb_   = (float*)carve((size_t)NN * 128 * sizeof(float));
  unsigned* kvb    = (unsigned*)carve((size_t)NN * 128 * sizeof(unsigned));
  unsigned* eab    = (unsigned*)carve((size_t)NE * 8 * sizeof(unsigned));
  float*    qe     = (float*)carve((size_t)NN * 32 * sizeof(float));
  float*    attn   = (float*)carve((size_t)NN * 128 * sizeof(float));
  float*    tbuf   = (float*)carve((size_t)NN * 32 * sizeof(float));
  float*    dbuf   = (float*)carve((size_t)NN * 2 * sizeof(float));
  unsigned short* xbh = (unsigned short*)carve((size_t)NN * FIN * sizeof(unsigned short));
  unsigned short* xbl = (unsigned short*)carve((size_t)NN * FIN * sizeof(unsigned short));
  unsigned short* hbh = (unsigned short*)carve((size_t)NN * 64 * sizeof(unsigned short));
  unsigned short* hbl = (unsigned short*)carve((size_t)NN * 64 * sizeof(unsigned short));
  float*    h2     = (float*)carve((size_t)NN * 64 * sizeof(float));
  // contiguous zero block: bn_acc[4][128] + gsum[3][NG*64] + gmax[3][NG*64]
  float*    bn_acc4 = (float*)carve(4 * 128 * sizeof(float));
  float*    gsum3  = (float*)carve(3 * (size_t)NG * 64 * sizeof(float));
  unsigned* gmax3  = (unsigned*)carve(3 * (size_t)NG * 64 * sizeof(unsigned));
  float*    ss     = (float*)carve(128 * sizeof(float));
  int*      deg    = (int*)carve(NN * sizeof(int));
  int*      row_ptr= (int*)carve((NN + 1) * sizeof(int));
  int*      eid    = (int*)carve((size_t)NE * sizeof(int));
  int*      src_s  = (int*)carve((size_t)NE * sizeof(int));
  int*      counts = (int*)carve(NG * sizeof(int));
  int*      starts = (int*)carve((NG + 1) * sizeof(int));
  int*      bsums  = (int*)carve(256 * sizeof(int));

  size_t zero_bytes = ((4 * 128 * sizeof(float) + 255) & ~(size_t)255)
                    + ((3 * (size_t)NG * 64 * sizeof(float) + 255) & ~(size_t)255)
                    + ((3 * (size_t)NG * 64 * sizeof(unsigned) + 255) & ~(size_t)255);
  hipMemsetAsync(d_out, 0, (size_t)out_size * sizeof(float), stream);
  hipMemsetAsync(deg, 0, NN * sizeof(int), stream);
  hipMemsetAsync(bn_acc4, 0, zero_bytes, stream);
  hist_k<<<(NE + 255) / 256, 256, 0, stream>>>(dsts, deg);
  bounds_k<<<(NN + 255) / 256, 256, 0, stream>>>(batch, starts);
  counts_from_starts_k<<<1, 64, 0, stream>>>(starts, counts);
  scan1_k<<<SCAN_B, 256, 0, stream>>>(deg, bsums);
  scan2_k<<<1, 256, 0, stream>>>(bsums);
  scan3_k<<<SCAN_B, 256, 0, stream>>>(deg, bsums, row_ptr, deg);
  scatter_k<<<(NE + 255) / 256, 256, 0, stream>>>(dsts, srcs, deg, eid, src_s);
  pack_ea_k<<<(NE * 2 + 255) / 256, 256, 0, stream>>>(ea, eid, eab);
  tobf2_k<<<(NN * FIN + 255) / 256, 256, 0, stream>>>(x, xbh, xbl);

  const unsigned short* hin_h = xbh;
  const unsigned short* hin_l = xbl;
  for (int L = 0; L < 4; L++){
    int D = (L == 0) ? FIN : EMB;
    const float *qw,*qb,*kw,*kb,*vw,*vb,*eww,*skw,*skb,*bww,*tw,*tb,*bnw,*bnb;
    if (L == 0){
      qw=c1_qw; qb=c1_qb; kw=c1_kw; kb=c1_kb; vw=c1_vw; vb=c1_vb;
      eww=c1_ew; skw=c1_skw; skb=c1_skb; bww=c1_bw; tw=c1_tw; tb=c1_tb;
      bnw=c1_bnw; bnb=c1_bnb;
    } else {
      int i = L - 1;
      qw = L_qw + (size_t)i * HCC * EMB;  qb = L_qb + (size_t)i * HCC;
      kw = L_kw + (size_t)i * HCC * EMB;  kb = L_kb + (size_t)i * HCC;
      vw = L_vw + (size_t)i * HCC * EMB;  vb = L_vb + (size_t)i * HCC;
      eww= L_ew + (size_t)i * HCC * EDIM;
      skw= L_skw+ (size_t)i * HCC * EMB;  skb= L_skb+ (size_t)i * HCC;
      bww= L_bw + (size_t)i * 3 * HCC;
      tw = L_tw + (size_t)i * EMB * HCC;  tb = L_tb + (size_t)i * EMB;
      bnw= L_bnw+ (size_t)i * EMB;        bnb= L_bnb+ (size_t)i * EMB;
    }
    float* bn_acc = bn_acc4 + L * 128;
    int pl = (L > 0) ? L - 1 : 0;
    float* gsum = gsum3 + (size_t)pl * NG * 64;
    unsigned* gmax = gmax3 + (size_t)pl * NG * 64;
    pack_all_k<<<256, 256, 0, stream>>>(qw, kw, vw, skw, qb, kb, vb, skb, tw, eww,
                                        ss, (L > 0) ? 1 : 0,
                                        Wh, Wl, bp, twph, twpl, bdh, bdl, D);
    dim3 gg((NN + 63) / 64, 4);
    if (D == 128) gemm6_k<128><<<gg, 256, 0, stream>>>(hin_h, hin_l, Wh, Wl, bp, eww, qb16, qe, kvb, skb_);
    else          gemm6_k<64><<<gg, 256, 0, stream>>>(hin_h, hin_l, Wh, Wl, bp, eww, qb16, qe, kvb, skb_);
    edge_k<<<(NN * 64 + 255) / 256, 256, 0, stream>>>(qb16, kvb, eab, qe, row_ptr, src_s, attn, tbuf, dbuf);
    combine3_k<<<(NN + 63) / 64, 256, 0, stream>>>(attn, skb_, bww, twph, twpl, tb, bdh, bdl,
                                                   tbuf, dbuf, hbh, hbl, h2, bn_acc, (L > 0) ? 1 : 0);
    bn_final_k<<<1, 64, 0, stream>>>(bn_acc, bnw, bnb, ss);
    if (L > 0) pool_scan_k<<<256, 256, 0, stream>>>(h2, ss, batch, gsum, gmax);
    hin_h = hbh; hin_l = hbl;
  }
  pool_final_all_k<<<(NG * 64 + 255) / 256, 256, 0, stream>>>(gsum3, gmax3, counts, (float*)d_out);
}

// Round 17
// 775.184 us; speedup vs baseline: 1.8170x; 1.0409x over previous
//
#include <hip/hip_runtime.h>

#define NN 50000
#define NE 800000
#define FIN 128
#define EDIM 16
#define EMB 64
#define NH 2
#define NLAYERS 3
#define NG 64
#define HCC 128
#define INV_SQRT_D 0.125f
#define EPS_BN 1e-5f
#define SCAN_B 196   // ceil(NN/256)
#define SCALE_L2E 0.18033688f   // 0.125 * log2(e)
#define NRT (NN / 16)            // 3125 row tiles

typedef __attribute__((ext_vector_type(8))) short bf16x8;
typedef __attribute__((ext_vector_type(4))) float f32x4;

__device__ __forceinline__ unsigned encf(float f){
  unsigned u = __float_as_uint(f);
  return (u & 0x80000000u) ? ~u : (u | 0x80000000u);
}
__device__ __forceinline__ float decf(unsigned e){
  unsigned u = (e & 0x80000000u) ? (e ^ 0x80000000u) : ~e;
  return __uint_as_float(u);
}
__device__ __forceinline__ unsigned f2bf(float x){   // RNE bf16, returned in low 16
  unsigned u = __float_as_uint(x);
  return (u + 0x7fffu + ((u >> 16) & 1u)) >> 16;
}
// split fp32 -> hi + lo bf16 (a ~= hi + lo, |lo| <= 2^-9 |a|)
__device__ __forceinline__ void f2bf_split(float x, unsigned short* hi, unsigned short* lo){
  unsigned h = f2bf(x);
  float hf = __uint_as_float(h << 16);
  *hi = (unsigned short)h;
  *lo = (unsigned short)f2bf(x - hf);
}
// fragment-major index: element (tile16, kk, lane, j) -> flat offset (in halves)
__device__ __forceinline__ size_t fragidx(int tile, int NK, int kk, int lane, int j){
  return (((size_t)tile * NK + kk) * 64 + lane) * 8 + j;
}

__global__ void hist_k(const int* __restrict__ dst, int* __restrict__ deg){
  int i = blockIdx.x * 256 + threadIdx.x;
  if (i < NE) atomicAdd(&deg[dst[i]], 1);
}

__global__ void bounds_k(const int* __restrict__ batch, int* __restrict__ starts){
  int i = blockIdx.x * 256 + threadIdx.x;
  if (i >= NN) return;
  int g = batch[i];
  int gp = (i == 0) ? -1 : batch[i - 1];
  for (int gg = gp + 1; gg <= g; gg++) starts[gg] = i;
  if (i == NN - 1){
    for (int gg = g + 1; gg <= NG; gg++) starts[gg] = NN;
  }
}

__global__ void scan1_k(const int* __restrict__ deg, int* __restrict__ bsums){
  __shared__ int lds[256];
  int b = blockIdx.x, t = threadIdx.x;
  int idx = b * 256 + t;
  lds[t] = (idx < NN) ? deg[idx] : 0;
  __syncthreads();
  for (int off = 128; off >= 1; off >>= 1){
    if (t < off) lds[t] += lds[t + off];
    __syncthreads();
  }
  if (t == 0) bsums[b] = lds[0];
}

__global__ void scan2_k(int* __restrict__ bsums){
  __shared__ int lds[256];
  int t = threadIdx.x;
  int v = (t < SCAN_B) ? bsums[t] : 0;
  int x = v;
  lds[t] = x;
  __syncthreads();
  for (int off = 1; off < 256; off <<= 1){
    int y = (t >= off) ? lds[t - off] : 0;
    __syncthreads();
    x += y;
    lds[t] = x;
    __syncthreads();
  }
  if (t < SCAN_B) bsums[t] = x - v;   // exclusive
}

// scan3 also initializes the scatter cursor.
__global__ void scan3_k(const int* __restrict__ degin, const int* __restrict__ bsums,
                        int* __restrict__ row_ptr, int* __restrict__ cur){
  __shared__ int lds[256];
  int b = blockIdx.x, t = threadIdx.x;
  int idx = b * 256 + t;
  int v = (idx < NN) ? degin[idx] : 0;
  int x = v;
  lds[t] = x;
  __syncthreads();
  for (int off = 1; off < 256; off <<= 1){
    int y = (t >= off) ? lds[t - off] : 0;
    __syncthreads();
    x += y;
    lds[t] = x;
    __syncthreads();
  }
  int val = bsums[b] + x - v;
  if (idx <= NN) row_ptr[idx] = val;
  if (idx < NN) cur[idx] = val;
}

__global__ void scatter_k(const int* __restrict__ dst, const int* __restrict__ src,
                          int* __restrict__ cur, int* __restrict__ eid,
                          int* __restrict__ src_s){
  int i = blockIdx.x * 256 + threadIdx.x;
  if (i < NE){
    int p = atomicAdd(&cur[dst[i]], 1);
    eid[p] = i;
    src_s[p] = src[i];
  }
}

// edge_attr -> bf16, reordered into CSR position order.
__global__ void pack_ea_k(const float* __restrict__ ea, const int* __restrict__ eid,
                          unsigned* __restrict__ eab){
  int i = blockIdx.x * 256 + threadIdx.x;
  if (i >= NE * 2) return;
  int p = i >> 1, half = i & 1;
  int e = eid[p];
  const float* s = ea + (size_t)e * 16 + half * 8;
  float4 a = *(const float4*)(s);
  float4 b = *(const float4*)(s + 4);
  uint4 o;
  o.x = f2bf(a.x) | (f2bf(a.y) << 16);
  o.y = f2bf(a.z) | (f2bf(a.w) << 16);
  o.z = f2bf(b.x) | (f2bf(b.y) << 16);
  o.w = f2bf(b.z) | (f2bf(b.w) << 16);
  ((uint4*)eab)[(size_t)p * 2 + half] = o;
}

// x (fp32, NN x 128) -> split bf16 in MFMA-fragment-major layout (NK=4)
__global__ void tobf2_k(const float* __restrict__ in, unsigned short* __restrict__ hi,
                        unsigned short* __restrict__ lo){
  int i = blockIdx.x * 256 + threadIdx.x;
  if (i >= NN * 128) return;
  int n = i >> 7, c = i & 127;
  int rt = n >> 4, rr = n & 15;
  int kk = c >> 5, kg = (c & 31) >> 3, j = c & 7;
  size_t idx = fragidx(rt, 4, kk, kg * 16 + rr, j);
  f2bf_split(in[i], &hi[idx], &lo[idx]);
}

// ALL per-layer weight packing fused, WITH BN folding (use_ss: W'=W*sc, b'=b+W.sh).
__global__ void pack_all_k(const float* __restrict__ qw, const float* __restrict__ kw,
                           const float* __restrict__ vw, const float* __restrict__ skw,
                           const float* __restrict__ qb, const float* __restrict__ kb,
                           const float* __restrict__ vb, const float* __restrict__ skb,
                           const float* __restrict__ tw, const float* __restrict__ ew,
                           const float* __restrict__ ss, int use_ss,
                           unsigned short* __restrict__ W2h, unsigned short* __restrict__ W2l,
                           float* __restrict__ bp,
                           unsigned short* __restrict__ twh, unsigned short* __restrict__ twl,
                           unsigned short* __restrict__ bdh, unsigned short* __restrict__ bdl,
                           int D){
  int i = blockIdx.x * 256 + threadIdx.x;
  int NK = D / 32;
  if (i < 512 * D){
    int c = i / D, d = i - c * D;
    const float* w = (c < 128) ? qw : (c < 256) ? kw : (c < 384) ? vw : skw;
    float wv = w[(c & 127) * D + d];
    if (use_ss) wv *= ss[d];
    int tile = c >> 4, rr = c & 15;
    int kk = d >> 5, kg = (d & 31) >> 3, j = d & 7;
    size_t idx = fragidx(tile, NK, kk, kg * 16 + rr, j);
    f2bf_split(wv, &W2h[idx], &W2l[idx]);
  }
  if (i < 512){
    const float* b = (i < 128) ? qb : (i < 256) ? kb : (i < 384) ? vb : skb;
    const float* w = (i < 128) ? qw : (i < 256) ? kw : (i < 384) ? vw : skw;
    float bb = b[i & 127];
    if (use_ss){
      float acc = 0.f;
      const float* wr = w + (size_t)(i & 127) * 64;
      #pragma unroll 8
      for (int c = 0; c < 64; c++) acc += wr[c] * ss[64 + c];
      bb += acc;
    }
    bp[i] = bb;
  }
  if (i < 64 * 128){
    int col = i >> 7, k = i & 127;
    int ct = col >> 4, rr = col & 15;
    int kk = k >> 5, kg = (k & 31) >> 3, j = k & 7;
    size_t idx = fragidx(ct, 4, kk, kg * 16 + rr, j);
    f2bf_split(tw[i], &twh[idx], &twl[idx]);
  }
  if (i < 32 * 128){
    int k = i >> 7, c = i & 127;
    float val = ((k >> 4) == (c >> 6)) ? ew[c * 16 + (k & 15)] : 0.f;
    int ct = c >> 4, rr = c & 15;
    int kg = k >> 3, j = k & 7;
    size_t idx = ((size_t)(ct * 64 + kg * 16 + rr)) * 8 + j;
    f2bf_split(val, &bdh[idx], &bdl[idx]);
  }
}

// Fused qkvs GEMM, fragment-major; part0 additionally computes qe via LDS
// and stores q as bf16 with SCALE_L2E prefolded.
template<int D>
__global__ __launch_bounds__(256, 4) void gemm6_k(const unsigned short* __restrict__ A2h,
                                                  const unsigned short* __restrict__ A2l,
                                                  const unsigned short* __restrict__ W2h,
                                                  const unsigned short* __restrict__ W2l,
                                                  const float* __restrict__ bp,
                                                  const float* __restrict__ ew,
                                                  unsigned short* __restrict__ qb16,
                                                  float* __restrict__ qe,
                                                  unsigned* __restrict__ kvb,
                                                  float* __restrict__ sk){
  __shared__ float qs[64][128];
  __shared__ float ews[2048];
  const int NK = D / 32;
  int t = threadIdx.x;
  int w = t >> 6, lane = t & 63;
  int brow = blockIdx.x * 64 + w * 16;
  int part = blockIdx.y;
  int r = lane & 15, kg = lane >> 4;
  int rt = brow >> 4; if (rt > NRT - 1) rt = NRT - 1;
  int cb0 = (part == 0) ? 0 : (part == 1) ? 2 : (part == 2) ? 3 : 6;
  int cb1 = (part == 0) ? 1 : (part == 1) ? 4 : (part == 2) ? 5 : 7;
  f32x4 acc0[4], acc1[4];
  #pragma unroll
  for (int tt = 0; tt < 4; tt++){
    acc0[tt] = (f32x4){0.f,0.f,0.f,0.f};
    acc1[tt] = (f32x4){0.f,0.f,0.f,0.f};
  }
  const unsigned short* a2hp = A2h + ((size_t)rt * NK) * 512 + lane * 8;
  const unsigned short* a2lp = A2l + ((size_t)rt * NK) * 512 + lane * 8;
  #pragma unroll
  for (int kk = 0; kk < NK; kk++){
    bf16x8 ah = *(const bf16x8*)(a2hp + kk * 512);
    bf16x8 al = *(const bf16x8*)(a2lp + kk * 512);
    bf16x8 b0h[4], b0l[4], b1h[4], b1l[4];
    #pragma unroll
    for (int tt = 0; tt < 4; tt++){
      size_t i0 = fragidx(cb0 * 4 + tt, NK, kk, lane, 0);
      size_t i1 = fragidx(cb1 * 4 + tt, NK, kk, lane, 0);
      b0h[tt] = *(const bf16x8*)(W2h + i0);
      b0l[tt] = *(const bf16x8*)(W2l + i0);
      b1h[tt] = *(const bf16x8*)(W2h + i1);
      b1l[tt] = *(const bf16x8*)(W2l + i1);
    }
    #pragma unroll
    for (int tt = 0; tt < 4; tt++){
      acc0[tt] = __builtin_amdgcn_mfma_f32_16x16x32_bf16(ah, b0h[tt], acc0[tt], 0, 0, 0);
      acc1[tt] = __builtin_amdgcn_mfma_f32_16x16x32_bf16(ah, b1h[tt], acc1[tt], 0, 0, 0);
      acc0[tt] = __builtin_amdgcn_mfma_f32_16x16x32_bf16(al, b0h[tt], acc0[tt], 0, 0, 0);
      acc1[tt] = __builtin_amdgcn_mfma_f32_16x16x32_bf16(al, b1h[tt], acc1[tt], 0, 0, 0);
      acc0[tt] = __builtin_amdgcn_mfma_f32_16x16x32_bf16(ah, b0l[tt], acc0[tt], 0, 0, 0);
      acc1[tt] = __builtin_amdgcn_mfma_f32_16x16x32_bf16(ah, b1l[tt], acc1[tt], 0, 0, 0);
    }
  }
  int rowbase = brow + kg * 4;
  if (part == 0){
    for (int i = t; i < 2048; i += 256) ews[i] = ew[i];
    #pragma unroll
    for (int tt = 0; tt < 4; tt++){
      int ch0 = tt * 16 + r, ch1 = 64 + tt * 16 + r;
      float b0 = bp[ch0], b1 = bp[ch1];
      #pragma unroll
      for (int j = 0; j < 4; j++){
        int row = rowbase + j;
        float v0 = acc0[tt][j] + b0;
        float v1 = acc1[tt][j] + b1;
        qs[w * 16 + kg * 4 + j][ch0] = v0;
        qs[w * 16 + kg * 4 + j][ch1] = v1;
        if (row < NN){
          qb16[(size_t)row * 128 + ch0] = (unsigned short)f2bf(v0 * SCALE_L2E);
          qb16[(size_t)row * 128 + ch1] = (unsigned short)f2bf(v1 * SCALE_L2E);
        }
      }
    }
    __syncthreads();
    #pragma unroll
    for (int i = 0; i < 8; i++){
      int idx = t + 256 * i;           // 0..2047
      int nl = idx >> 5, hd = idx & 31;
      int h = hd >> 4, d = hd & 15;
      float s = 0.f;
      #pragma unroll 8
      for (int c = 0; c < 64; c++)
        s += qs[nl][h * 64 + c] * ews[(h * 64 + c) * 16 + d];
      int n = blockIdx.x * 64 + nl;
      if (n < NN) qe[(size_t)n * 32 + hd] = s * SCALE_L2E;
    }
  } else if (part == 3){
    #pragma unroll
    for (int tt = 0; tt < 4; tt++){
      int ch0 = tt * 16 + r, ch1 = 64 + tt * 16 + r;
      float b0 = bp[384 + ch0], b1 = bp[384 + ch1];
      #pragma unroll
      for (int j = 0; j < 4; j++){
        int row = rowbase + j;
        if (row < NN){
          sk[(size_t)row * 128 + ch0] = acc0[tt][j] + b0;
          sk[(size_t)row * 128 + ch1] = acc1[tt][j] + b1;
        }
      }
    }
  } else {
    int chbase = (part - 1) * 64;
    #pragma unroll
    for (int tt = 0; tt < 4; tt++){
      int ch = chbase + tt * 16 + r;
      float bk = bp[cb0 * 64 + tt * 16 + r];
      float bv = bp[cb1 * 64 + tt * 16 + r];
      #pragma unroll
      for (int j = 0; j < 4; j++){
        int row = rowbase + j;
        if (row < NN){
          float kk4 = acc0[tt][j] + bk;
          float vv = acc1[tt][j] + bv;
          kvb[(size_t)row * 128 + ch] = f2bf(kk4) | (f2bf(vv) << 16);
        }
      }
    }
  }
}

// One wave per NODE, both heads; q read as prescaled bf16.
#define EDGE_STEP(EOFF, MASKED)                                               \
  {                                                                           \
    int e = (EOFF);                                                           \
    int s = __shfl(sv, e);                                                    \
    const unsigned* kp = kvb + (size_t)s * 128 + chb;                         \
    uint4 kv0 = *(const uint4*)(kp);                                          \
    uint4 kv1 = *(const uint4*)(kp + 4);                                      \
    size_t g = (size_t)(beg + cb + e);                                        \
    if (MASKED && g >= NE) g = NE - 1;                                        \
    unsigned eau = eab_u[g * 8 + l8];                                         \
    float ea0 = __uint_as_float(eau << 16);                                   \
    float ea1 = __uint_as_float(eau & 0xffff0000u);                           \
    float k0 = __uint_as_float(kv0.x << 16), v0 = __uint_as_float(kv0.x & 0xffff0000u); \
    float k1 = __uint_as_float(kv0.y << 16), v1 = __uint_as_float(kv0.y & 0xffff0000u); \
    float k2 = __uint_as_float(kv0.z << 16), v2 = __uint_as_float(kv0.z & 0xffff0000u); \
    float k3 = __uint_as_float(kv0.w << 16), v3 = __uint_as_float(kv0.w & 0xffff0000u); \
    float k4 = __uint_as_float(kv1.x << 16), v4 = __uint_as_float(kv1.x & 0xffff0000u); \
    float k5 = __uint_as_float(kv1.y << 16), v5 = __uint_as_float(kv1.y & 0xffff0000u); \
    float k6 = __uint_as_float(kv1.z << 16), v6 = __uint_as_float(kv1.z & 0xffff0000u); \
    float k7 = __uint_as_float(kv1.w << 16), v7 = __uint_as_float(kv1.w & 0xffff0000u); \
    float p = fmaf(q[0], k0, fmaf(q[1], k1, fmaf(q[2], k2, fmaf(q[3], k3,     \
              fmaf(q[4], k4, fmaf(q[5], k5, fmaf(q[6], k6, fmaf(q[7], k7,     \
              fmaf(qe2.x, ea0, qe2.y * ea1)))))))));                          \
    p += __shfl_xor(p, 1); p += __shfl_xor(p, 2); p += __shfl_xor(p, 4);      \
    float w = exp2f(p);                                                       \
    if (MASKED && e >= m) w = 0.f;                                            \
    a0 = fmaf(v0, w, a0); a1 = fmaf(v1, w, a1);                               \
    a2 = fmaf(v2, w, a2); a3 = fmaf(v3, w, a3);                               \
    a4 = fmaf(v4, w, a4); a5 = fmaf(v5, w, a5);                               \
    a6 = fmaf(v6, w, a6); a7 = fmaf(v7, w, a7);                               \
    den += w; t0 = fmaf(ea0, w, t0); t1 = fmaf(ea1, w, t1);                   \
  }

__global__ __launch_bounds__(256) void edge_k(const unsigned short* __restrict__ qb16,
    const unsigned* __restrict__ kvb, const unsigned* __restrict__ eab_u,
    const float* __restrict__ qe, const int* __restrict__ row_ptr,
    const int* __restrict__ src_s, float* __restrict__ accp,
    float* __restrict__ tbuf, float* __restrict__ dbuf){
  int n = (blockIdx.x * 256 + threadIdx.x) >> 6;
  if (n >= NN) return;
  int lane = threadIdx.x & 63;
  int grp = lane >> 4;
  int l8 = lane & 7;
  int h = (lane >> 3) & 1;
  int chb = h * 64 + l8 * 8;
  float q[8];
  {
    uint4 qv = *(const uint4*)(qb16 + (size_t)n * 128 + chb);
    q[0] = __uint_as_float(qv.x << 16); q[1] = __uint_as_float(qv.x & 0xffff0000u);
    q[2] = __uint_as_float(qv.y << 16); q[3] = __uint_as_float(qv.y & 0xffff0000u);
    q[4] = __uint_as_float(qv.z << 16); q[5] = __uint_as_float(qv.z & 0xffff0000u);
    q[6] = __uint_as_float(qv.w << 16); q[7] = __uint_as_float(qv.w & 0xffff0000u);
  }
  float2 qe2 = *(const float2*)(qe + (size_t)n * 32 + h * 16 + 2 * l8);
  int beg = row_ptr[n], end = row_ptr[n + 1];
  int nb = end - beg;
  float a0=0.f,a1=0.f,a2=0.f,a3=0.f,a4=0.f,a5=0.f,a6=0.f,a7=0.f;
  float den = 0.f, t0 = 0.f, t1 = 0.f;
  for (int cb = 0; cb < nb; cb += 64){
    int sv = (cb + lane < nb) ? src_s[beg + cb + lane] : 0;
    int m = min(64, nb - cb);
    int u = 0;
    for (; u + 8 <= m; u += 8){
      EDGE_STEP(u + grp, false)
      EDGE_STEP(u + 4 + grp, false)
    }
    int rem = m - u;
    if (rem > 0){
      EDGE_STEP(u + grp, true)
      if (rem > 4){
        EDGE_STEP(u + 4 + grp, true)
      }
    }
  }
  a0 += __shfl_xor(a0, 16); a0 += __shfl_xor(a0, 32);
  a1 += __shfl_xor(a1, 16); a1 += __shfl_xor(a1, 32);
  a2 += __shfl_xor(a2, 16); a2 += __shfl_xor(a2, 32);
  a3 += __shfl_xor(a3, 16); a3 += __shfl_xor(a3, 32);
  a4 += __shfl_xor(a4, 16); a4 += __shfl_xor(a4, 32);
  a5 += __shfl_xor(a5, 16); a5 += __shfl_xor(a5, 32);
  a6 += __shfl_xor(a6, 16); a6 += __shfl_xor(a6, 32);
  a7 += __shfl_xor(a7, 16); a7 += __shfl_xor(a7, 32);
  den += __shfl_xor(den, 16); den += __shfl_xor(den, 32);
  t0 += __shfl_xor(t0, 16); t0 += __shfl_xor(t0, 32);
  t1 += __shfl_xor(t1, 16); t1 += __shfl_xor(t1, 32);
  if (lane < 16){
    float4 o0 = {a0, a1, a2, a3};
    float4 o1 = {a4, a5, a6, a7};
    *(float4*)(accp + (size_t)n * 128 + chb) = o0;
    *(float4*)(accp + (size_t)n * 128 + chb + 4) = o1;
    *(float2*)(tbuf + (size_t)n * 32 + h * 16 + 2 * l8) = make_float2(t0, t1);
    if (l8 == 0) dbuf[(size_t)n * 2 + h] = den;
  }
}

// MFMA combine v4: emits next-layer GEMM fragments + fused RAW pooling stats
// (BN applied later in pool_final since sc>0: max/mean are affine-compatible).
__global__ __launch_bounds__(256) void combine4_k(const float* __restrict__ accp,
    const float* __restrict__ sk, const float* __restrict__ bw,
    const unsigned short* __restrict__ twh, const unsigned short* __restrict__ twl,
    const float* __restrict__ tb, const unsigned short* __restrict__ bdh,
    const unsigned short* __restrict__ bdl, const float* __restrict__ tbuf,
    const float* __restrict__ dbuf, const int* __restrict__ batch,
    unsigned short* __restrict__ hbh, unsigned short* __restrict__ hbl,
    float* __restrict__ bn_acc, float* __restrict__ gsum,
    unsigned* __restrict__ gmax, int do_pool){
  __shared__ float ext[64][132];
  __shared__ bf16x8 afh[4][4][64];
  __shared__ bf16x8 afl[4][4][64];
  __shared__ float bws[384];
  __shared__ float bsum[64], bsq[64];
  __shared__ float psum_l[4][64];
  __shared__ unsigned pmax_l[4][64];
  int t = threadIdx.x;
  int w = t >> 6, lane = t & 63;
  int blk = (int)blockIdx.x;
  int base0 = blk * 64; if (base0 > NN - 1) base0 = NN - 1;
  int base63 = blk * 64 + 63; if (base63 > NN - 1) base63 = NN - 1;
  for (int i = t; i < 384; i += 256) bws[i] = bw[i];
  if (t < 64){ bsum[t] = 0.f; bsq[t] = 0.f; }
  if (do_pool){
    #pragma unroll
    for (int s = 0; s < 4; s++){
      if (t < 64){ psum_l[s][t] = 0.f; pmax_l[s][t] = 0u; }
    }
  }
  {
    int row = lane & 15, kg = lane >> 4;
    int nrow = blk * 64 + w * 16 + row;
    if (nrow >= NN) nrow = NN - 1;
    float4 tva = *(const float4*)(tbuf + (size_t)nrow * 32 + kg * 8);
    float4 tvb = *(const float4*)(tbuf + (size_t)nrow * 32 + kg * 8 + 4);
    float tv[8] = {tva.x, tva.y, tva.z, tva.w, tvb.x, tvb.y, tvb.z, tvb.w};
    bf16x8 th, tlw;
    #pragma unroll
    for (int j = 0; j < 8; j++){
      unsigned hb = f2bf(tv[j]);
      th[j] = (short)hb;
      tlw[j] = (short)f2bf(tv[j] - __uint_as_float(hb << 16));
    }
    #pragma unroll
    for (int ct = 0; ct < 8; ct++){
      f32x4 ae = (f32x4){0.f,0.f,0.f,0.f};
      size_t idx = ((size_t)(ct * 64 + lane)) * 8;
      bf16x8 bh = *(const bf16x8*)(bdh + idx);
      bf16x8 bl = *(const bf16x8*)(bdl + idx);
      ae = __builtin_amdgcn_mfma_f32_16x16x32_bf16(th, bh, ae, 0, 0, 0);
      ae = __builtin_amdgcn_mfma_f32_16x16x32_bf16(tlw, bh, ae, 0, 0, 0);
      ae = __builtin_amdgcn_mfma_f32_16x16x32_bf16(th, bl, ae, 0, 0, 0);
      #pragma unroll
      for (int j = 0; j < 4; j++)
        ext[w * 16 + kg * 4 + j][ct * 16 + row] = ae[j];
    }
  }
  int nl = t >> 2, q = t & 3;
  int n = blk * 64 + nl;
  bool valid = n < NN;
  float o[32], r[32];
  if (valid){
    const float* ap = accp + (size_t)n * 128 + q * 32;
    const float* sp = sk   + (size_t)n * 128 + q * 32;
    #pragma unroll
    for (int i = 0; i < 32; i += 4){
      float4 va = *(const float4*)(ap + i);
      float4 vr = *(const float4*)(sp + i);
      o[i] = va.x; o[i+1] = va.y; o[i+2] = va.z; o[i+3] = va.w;
      r[i] = vr.x; r[i+1] = vr.y; r[i+2] = vr.z; r[i+3] = vr.w;
    }
  } else {
    #pragma unroll
    for (int i = 0; i < 32; i++){ o[i] = 0.f; r[i] = 0.f; }
  }
  float dh = valid ? dbuf[(size_t)n * 2 + (q >> 1)] : 0.f;
  float invden = dh > 0.f ? 1.f / dh : 0.f;
  __syncthreads();
  #pragma unroll
  for (int i = 0; i < 32; i++)
    o[i] = (o[i] + ext[nl][q * 32 + i]) * invden;
  float pp = 0.f;
  #pragma unroll
  for (int i = 0; i < 32; i++){
    int c = q * 32 + i;
    pp += o[i] * bws[c] + r[i] * bws[128 + c] + (o[i] - r[i]) * bws[256 + c];
  }
  pp += __shfl_xor(pp, 1); pp += __shfl_xor(pp, 2);
  float beta = 1.f / (1.f + __expf(-pp));
  int w2 = t >> 6;
  int r0 = (t & 63) >> 2;
  #pragma unroll
  for (int kg = 0; kg < 4; kg++){
    bf16x8 hv, lv;
    #pragma unroll
    for (int j = 0; j < 8; j++){
      int i = kg * 8 + j;
      float hc = o[i] + beta * (r[i] - o[i]);
      unsigned hb = f2bf(hc);
      hv[j] = (short)hb;
      lv[j] = (short)f2bf(hc - __uint_as_float(hb << 16));
    }
    afh[w2][q][kg * 16 + r0] = hv;
    afl[w2][q][kg * 16 + r0] = lv;
  }
  __syncthreads();
  bf16x8 ah[4], al[4];
  #pragma unroll
  for (int kk = 0; kk < 4; kk++){ ah[kk] = afh[w][kk][lane]; al[kk] = afl[w][kk][lane]; }
  int brow = blk * 64 + w * 16;
  int tile = blk * 4 + w;
  int g0 = 0, bt[4], rowloc = (lane >> 4) * 4;
  if (do_pool){
    g0 = batch[base0];
    #pragma unroll
    for (int j = 0; j < 4; j++){
      int row = brow + rowloc + j;
      bt[j] = (row < NN) ? (batch[row] - g0) : -1;
      if (bt[j] > 3) bt[j] = 3;
      if (bt[j] < 0 && row < NN) bt[j] = 0;
    }
  }
  #pragma unroll
  for (int ct = 0; ct < 4; ct++){
    f32x4 acc = (f32x4){0.f,0.f,0.f,0.f};
    #pragma unroll
    for (int kk = 0; kk < 4; kk++){
      size_t idx = (((size_t)(ct * 4 + kk)) * 64 + lane) * 8;
      bf16x8 bh = *(const bf16x8*)(twh + idx);
      bf16x8 bl = *(const bf16x8*)(twl + idx);
      acc = __builtin_amdgcn_mfma_f32_16x16x32_bf16(ah[kk], bh, acc, 0, 0, 0);
      acc = __builtin_amdgcn_mfma_f32_16x16x32_bf16(al[kk], bh, acc, 0, 0, 0);
      acc = __builtin_amdgcn_mfma_f32_16x16x32_bf16(ah[kk], bl, acc, 0, 0, 0);
    }
    int col = ct * 16 + (lane & 15);
    float bias = tb[col];
    int kk2 = col >> 5, kg2 = (col & 31) >> 3, jj = col & 7;
    float ps = 0.f, pq = 0.f;
    #pragma unroll
    for (int j = 0; j < 4; j++){
      int rr = rowloc + j;
      int row = brow + rr;
      float s = acc[j] + bias;
      float v = s > 0.f ? s : 0.01f * s;
      if (tile < NRT){
        size_t fidx = fragidx(tile, 2, kk2, kg2 * 16 + rr, jj);
        unsigned hb = f2bf(v);
        hbh[fidx] = (unsigned short)hb;
        hbl[fidx] = (unsigned short)f2bf(v - __uint_as_float(hb << 16));
      }
      if (row < NN){
        ps += v; pq += v * v;
        if (do_pool){
          int s2 = bt[j];
          atomicAdd(&psum_l[s2][col], v);
          atomicMax(&pmax_l[s2][col], encf(v));
        }
      }
    }
    ps += __shfl_xor(ps, 16); ps += __shfl_xor(ps, 32);
    pq += __shfl_xor(pq, 16); pq += __shfl_xor(pq, 32);
    if (lane < 16){
      atomicAdd(&bsum[col], ps);
      atomicAdd(&bsq[col], pq);
    }
  }
  __syncthreads();
  if (t < 64){
    atomicAdd(&bn_acc[t], bsum[t]);
    atomicAdd(&bn_acc[64 + t], bsq[t]);
  }
  if (do_pool){
    int span = batch[base63] - batch[base0];
    if (span > 3) span = 3;
    int s2 = t >> 6, col = t & 63;
    if (s2 <= span){
      int g = batch[base0] + s2;
      if (g < NG){
        float sv2 = psum_l[s2][col];
        unsigned mv = pmax_l[s2][col];
        if (sv2 != 0.f) atomicAdd(&gsum[g * 64 + col], sv2);
        if (mv) atomicMax(&gmax[g * 64 + col], mv);
      }
    }
  }
}

__global__ void bn_final_k(const float* __restrict__ bn_acc, const float* __restrict__ bnw,
                           const float* __restrict__ bnb, float* __restrict__ ss){
  int j = threadIdx.x;
  if (j < 64){
    float m = bn_acc[j] / (float)NN;
    float v = bn_acc[64 + j] / (float)NN - m * m;
    float sc = bnw[j] * rsqrtf(v + EPS_BN);
    ss[j] = sc;
    ss[64 + j] = bnb[j] - m * sc;
  }
}

// final pool over 3 layers: apply each layer's BN affine to RAW stats
// (valid since sc>0: max(v*sc+sh) = sc*max(v)+sh; mean is affine).
__global__ void pool_final_all_k(const float* __restrict__ gsum3, const unsigned* __restrict__ gmax3,
                                 const int* __restrict__ starts, const float* __restrict__ ss3,
                                 float* __restrict__ gr){
  int i = blockIdx.x * 256 + threadIdx.x;
  if (i >= NG * 64) return;
  int g = i >> 6, j = i & 63;
  int c = starts[g + 1] - starts[g]; if (c < 1) c = 1;
  float msum = 0.f, ssum = 0.f;
  #pragma unroll
  for (int L = 1; L <= 3; L++){
    float sc = ss3[L * 128 + j];
    float sh = ss3[L * 128 + 64 + j];
    unsigned e = gmax3[(size_t)(L - 1) * NG * 64 + i];
    float rawmax = e ? decf(e) : 0.f;
    msum += rawmax * sc + sh;
    ssum += (gsum3[(size_t)(L - 1) * NG * 64 + i] / (float)c) * sc + sh;
  }
  gr[g * 128 + j]      += msum;
  gr[g * 128 + 64 + j] += ssum;
}

extern "C" void kernel_launch(void* const* d_in, const int* in_sizes, int n_in,
                              void* d_out, int out_size, void* d_ws, size_t ws_size,
                              hipStream_t stream){
  const float* x     = (const float*)d_in[0];
  const float* ea    = (const float*)d_in[1];
  const int*   eidx  = (const int*)d_in[2];
  const int*   batch = (const int*)d_in[3];
  const float* c1_qw = (const float*)d_in[4];
  const float* c1_qb = (const float*)d_in[5];
  const float* c1_kw = (const float*)d_in[6];
  const float* c1_kb = (const float*)d_in[7];
  const float* c1_vw = (const float*)d_in[8];
  const float* c1_vb = (const float*)d_in[9];
  const float* c1_ew = (const float*)d_in[10];
  const float* c1_skw= (const float*)d_in[11];
  const float* c1_skb= (const float*)d_in[12];
  const float* c1_bw = (const float*)d_in[13];
  const float* c1_tw = (const float*)d_in[14];
  const float* c1_tb = (const float*)d_in[15];
  const float* c1_bnw= (const float*)d_in[16];
  const float* c1_bnb= (const float*)d_in[17];
  const float* L_qw  = (const float*)d_in[18];
  const float* L_qb  = (const float*)d_in[19];
  const float* L_kw  = (const float*)d_in[20];
  const float* L_kb  = (const float*)d_in[21];
  const float* L_vw  = (const float*)d_in[22];
  const float* L_vb  = (const float*)d_in[23];
  const float* L_ew  = (const float*)d_in[24];
  const float* L_skw = (const float*)d_in[25];
  const float* L_skb = (const float*)d_in[26];
  const float* L_bw  = (const float*)d_in[27];
  const float* L_tw  = (const float*)d_in[28];
  const float* L_tb  = (const float*)d_in[29];
  const float* L_bnw = (const float*)d_in[30];
  const float* L_bnb = (const float*)d_in[31];
  const int* srcs = eidx;
  const int* dsts = eidx + NE;

  char* p = (char*)d_ws;
  auto carve = [&](size_t bytes) -> void* {
    void* r = (void*)p;
    p += (bytes + 255) & ~(size_t)255;
    return r;
  };
  unsigned short* Wh = (unsigned short*)carve(512 * 128 * sizeof(unsigned short));
  unsigned short* Wl = (unsigned short*)carve(512 * 128 * sizeof(unsigned short));
  float*    bp     = (float*)carve(512 * sizeof(float));
  unsigned short* twph = (unsigned short*)carve(64 * 128 * sizeof(unsigned short));
  unsigned short* twpl = (unsigned short*)carve(64 * 128 * sizeof(unsigned short));
  unsigned short* bdh = (unsigned short*)carve(32 * 128 * sizeof(unsigned short));
  unsigned short* bdl = (unsigned short*)carve(32 * 128 * sizeof(unsigned short));
  unsigned short* qb16 = (unsigned short*)carve((size_t)NN * 128 * sizeof(unsigned short));
  float*    skb_   = (float*)carve((size_t)NN * 128 * sizeof(float));
  unsigned* kvb    = (unsigned*)carve((size_t)NN * 128 * sizeof(unsigned));
  unsigned* eab    = (unsigned*)carve((size_t)NE * 8 * sizeof(unsigned));
  float*    qe     = (float*)carve((size_t)NN * 32 * sizeof(float));
  float*    attn   = (float*)carve((size_t)NN * 128 * sizeof(float));
  float*    tbuf   = (float*)carve((size_t)NN * 32 * sizeof(float));
  float*    dbuf   = (float*)carve((size_t)NN * 2 * sizeof(float));
  unsigned short* xbh = (unsigned short*)carve((size_t)NN * FIN * sizeof(unsigned short));
  unsigned short* xbl = (unsigned short*)carve((size_t)NN * FIN * sizeof(unsigned short));
  unsigned short* hbh = (unsigned short*)carve((size_t)NN * 64 * sizeof(unsigned short));
  unsigned short* hbl = (unsigned short*)carve((size_t)NN * 64 * sizeof(unsigned short));
  // contiguous zero block: bn_acc[4][128] + gsum[3][NG*64] + gmax[3][NG*64]
  float*    bn_acc4 = (float*)carve(4 * 128 * sizeof(float));
  float*    gsum3  = (float*)carve(3 * (size_t)NG * 64 * sizeof(float));
  unsigned* gmax3  = (unsigned*)carve(3 * (size_t)NG * 64 * sizeof(unsigned));
  float*    ss3    = (float*)carve(4 * 128 * sizeof(float));
  int*      deg    = (int*)carve(NN * sizeof(int));
  int*      row_ptr= (int*)carve((NN + 1) * sizeof(int));
  int*      eid    = (int*)carve((size_t)NE * sizeof(int));
  int*      src_s  = (int*)carve((size_t)NE * sizeof(int));
  int*      starts = (int*)carve((NG + 1) * sizeof(int));
  int*      bsums  = (int*)carve(256 * sizeof(int));

  size_t zero_bytes = ((4 * 128 * sizeof(float) + 255) & ~(size_t)255)
                    + ((3 * (size_t)NG * 64 * sizeof(float) + 255) & ~(size_t)255)
                    + ((3 * (size_t)NG * 64 * sizeof(unsigned) + 255) & ~(size_t)255);
  hipMemsetAsync(d_out, 0, (size_t)out_size * sizeof(float), stream);
  hipMemsetAsync(deg, 0, NN * sizeof(int), stream);
  hipMemsetAsync(bn_acc4, 0, zero_bytes, stream);
  hist_k<<<(NE + 255) / 256, 256, 0, stream>>>(dsts, deg);
  bounds_k<<<(NN + 255) / 256, 256, 0, stream>>>(batch, starts);
  scan1_k<<<SCAN_B, 256, 0, stream>>>(deg, bsums);
  scan2_k<<<1, 256, 0, stream>>>(bsums);
  scan3_k<<<SCAN_B, 256, 0, stream>>>(deg, bsums, row_ptr, deg);
  scatter_k<<<(NE + 255) / 256, 256, 0, stream>>>(dsts, srcs, deg, eid, src_s);
  pack_ea_k<<<(NE * 2 + 255) / 256, 256, 0, stream>>>(ea, eid, eab);
  tobf2_k<<<(NN * FIN + 255) / 256, 256, 0, stream>>>(x, xbh, xbl);

  const unsigned short* hin_h = xbh;
  const unsigned short* hin_l = xbl;
  for (int L = 0; L < 4; L++){
    int D = (L == 0) ? FIN : EMB;
    const float *qw,*qb,*kw,*kb,*vw,*vb,*eww,*skw,*skb,*bww,*tw,*tb,*bnw,*bnb;
    if (L == 0){
      qw=c1_qw; qb=c1_qb; kw=c1_kw; kb=c1_kb; vw=c1_vw; vb=c1_vb;
      eww=c1_ew; skw=c1_skw; skb=c1_skb; bww=c1_bw; tw=c1_tw; tb=c1_tb;
      bnw=c1_bnw; bnb=c1_bnb;
    } else {
      int i = L - 1;
      qw = L_qw + (size_t)i * HCC * EMB;  qb = L_qb + (size_t)i * HCC;
      kw = L_kw + (size_t)i * HCC * EMB;  kb = L_kb + (size_t)i * HCC;
      vw = L_vw + (size_t)i * HCC * EMB;  vb = L_vb + (size_t)i * HCC;
      eww= L_ew + (size_t)i * HCC * EDIM;
      skw= L_skw+ (size_t)i * HCC * EMB;  skb= L_skb+ (size_t)i * HCC;
      bww= L_bw + (size_t)i * 3 * HCC;
      tw = L_tw + (size_t)i * EMB * HCC;  tb = L_tb + (size_t)i * EMB;
      bnw= L_bnw+ (size_t)i * EMB;        bnb= L_bnb+ (size_t)i * EMB;
    }
    float* bn_acc = bn_acc4 + L * 128;
    int pl = (L > 0) ? L - 1 : 0;
    float* gsum = gsum3 + (size_t)pl * NG * 64;
    unsigned* gmax = gmax3 + (size_t)pl * NG * 64;
    pack_all_k<<<256, 256, 0, stream>>>(qw, kw, vw, skw, qb, kb, vb, skb, tw, eww,
                                        ss3 + (L > 0 ? (L - 1) * 128 : 0), (L > 0) ? 1 : 0,
                                        Wh, Wl, bp, twph, twpl, bdh, bdl, D);
    dim3 gg((NN + 63) / 64, 4);
    if (D == 128) gemm6_k<128><<<gg, 256, 0, stream>>>(hin_h, hin_l, Wh, Wl, bp, eww, qb16, qe, kvb, skb_);
    else          gemm6_k<64><<<gg, 256, 0, stream>>>(hin_h, hin_l, Wh, Wl, bp, eww, qb16, qe, kvb, skb_);
    edge_k<<<(NN * 64 + 255) / 256, 256, 0, stream>>>(qb16, kvb, eab, qe, row_ptr, src_s, attn, tbuf, dbuf);
    combine4_k<<<(NN + 63) / 64, 256, 0, stream>>>(attn, skb_, bww, twph, twpl, tb, bdh, bdl,
                                                   tbuf, dbuf, batch, hbh, hbl, bn_acc,
                                                   gsum, gmax, (L > 0) ? 1 : 0);
    bn_final_k<<<1, 64, 0, stream>>>(bn_acc, bnw, bnb, ss3 + L * 128);
    hin_h = hbh; hin_l = hbl;
  }
  pool_final_all_k<<<(NG * 64 + 255) / 256, 256, 0, stream>>>(gsum3, gmax3, starts, ss3, (float*)d_out);
}